// Round 6
// baseline (1313.455 us; speedup 1.0000x reference)
//
#include <hip/hip_runtime.h>

#define Hd 256
#define NNODE 10000
#define NE1 131072
#define NE2 65536

typedef __attribute__((ext_vector_type(8))) short bf16x8;
typedef __attribute__((ext_vector_type(4))) float f32x4;

#define MFMA16(a, b, c) __builtin_amdgcn_mfma_f32_16x16x32_bf16((a), (b), (c), 0, 0, 0)

__device__ __forceinline__ float b2f(ushort u) { return __uint_as_float(((unsigned)u) << 16); }
__device__ __forceinline__ ushort f2b(float f) {
  unsigned u = __float_as_uint(f);
  return (ushort)((u + 0x7fffu + ((u >> 16) & 1u)) >> 16);
}

// ---------------- small kernels ----------------

__global__ void time_mlp_k(const float* __restrict__ tval,
                           const float* __restrict__ W0, const float* __restrict__ b0,
                           const float* __restrict__ W1, const float* __restrict__ b1,
                           const float* __restrict__ W2, const float* __restrict__ b2,
                           float* __restrict__ tenc) {
  __shared__ float h0[Hd], h1[Hd];
  int b = blockIdx.x, j = threadIdx.x;
  float t = tval[b];
  h0[j] = fmaxf(t * W0[j] + b0[j], 0.f);
  __syncthreads();
  float a = b1[j];
  for (int k = 0; k < Hd; ++k) a += h0[k] * W1[k * Hd + j];
  h1[j] = fmaxf(a, 0.f);
  __syncthreads();
  float c = b2[j];
  for (int k = 0; k < Hd; ++k) c += h1[k] * W2[k * Hd + j];
  tenc[b * Hd + j] = c;
}

__global__ void build_x0_k(const int* __restrict__ batch, const float* __restrict__ tenc,
                           ushort* __restrict__ x0) {
  int idx = blockIdx.x * 256 + threadIdx.x;
  int n = idx >> 9;
  x0[idx] = f2b(tenc[batch[n] * Hd + (idx & 255)]);
}

// zero CSR counters + zero-bias + concat per-layer GAT biases (1024-wide)
__global__ void init_small_k(int* __restrict__ cnt1, int* __restrict__ cur1,
                             int* __restrict__ cnt2, int* __restrict__ cur2,
                             float* __restrict__ zerob, float* __restrict__ biascat,
                             const float* __restrict__ gg_bl, const float* __restrict__ gg_br,
                             const float* __restrict__ gf_bl, const float* __restrict__ gf_br) {
  int i = blockIdx.x * 256 + threadIdx.x;
  if (i < NNODE) { cnt1[i] = 0; cur1[i] = 0; cnt2[i] = 0; cur2[i] = 0; return; }
  i -= NNODE;
  if (i < 512) { zerob[i] = 0.f; return; }
  i -= 512;
  if (i < 6144) {
    int layer = i >> 10, c = i & 1023;
    float v;
    if (c < 256)      v = gg_bl[layer * 256 + c];
    else if (c < 512) v = gg_br[layer * 256 + c - 256];
    else if (c < 768) v = gf_bl[layer * 256 + c - 512];
    else              v = gf_br[layer * 256 + c - 768];
    biascat[layer * 1024 + c] = v;
  }
}

// ---------------- merged weight transposes ----------------
struct TT { const float* src; ushort* dst; int K; int n_off; int ld; int start; };
struct TransArgs { TT t[24]; };

__global__ void trans_all_k(TransArgs a) {
  int b = blockIdx.x;
  int ti = 0;
  while (ti + 1 < 24 && a.t[ti + 1].start <= b) ++ti;
  TT tk = a.t[ti];
  int lb = b - tk.start;
  int gx = tk.K >> 5;
  int k0 = (lb % gx) * 32, n0 = (lb / gx) * 32;
  __shared__ float t[32][33];
  int tx = threadIdx.x & 31, ty = threadIdx.x >> 5;
#pragma unroll
  for (int p = 0; p < 4; ++p)
    t[ty + 8 * p][tx] = tk.src[(size_t)(k0 + ty + 8 * p) * 256 + n0 + tx];
  __syncthreads();
#pragma unroll
  for (int p = 0; p < 4; ++p)
    tk.dst[(size_t)(tk.n_off + n0 + ty + 8 * p) * tk.ld + k0 + tx] = f2b(t[tx][ty + 8 * p]);
}

// ---------------- CSR build (by dst) ----------------

__global__ void deg_all_k(const int* __restrict__ dst1, int* __restrict__ cnt1,
                          const int* __restrict__ dst2, int* __restrict__ cnt2) {
  int e = blockIdx.x * 256 + threadIdx.x;
  if (e < NE1) atomicAdd(cnt1 + dst1[e], 1);
  else if (e - NE1 < NE2) atomicAdd(cnt2 + dst2[e - NE1], 1);
}

__global__ void scan_k(const int* __restrict__ cnt1, int* __restrict__ rs1,
                       const int* __restrict__ cnt2, int* __restrict__ rs2) {
  const int g = blockIdx.x;
  const int* cnt = g ? cnt2 : cnt1;
  int* rowstart = g ? rs2 : rs1;
  const int E = g ? NE2 : NE1;
  __shared__ int part[626];
  int t = threadIdx.x;
  if (t < 625) {
    int s = 0;
#pragma unroll
    for (int i = 0; i < 16; ++i) s += cnt[t * 16 + i];
    part[t] = s;
  }
  __syncthreads();
  if (t == 0) {
    int run = 0;
    for (int i = 0; i < 625; ++i) { int v = part[i]; part[i] = run; run += v; }
  }
  __syncthreads();
  if (t < 625) {
    int off = part[t];
#pragma unroll
    for (int i = 0; i < 16; ++i) { rowstart[t * 16 + i] = off; off += cnt[t * 16 + i]; }
  }
  if (t == 0) rowstart[NNODE] = E;
}

__global__ void fill_all_k(const int* __restrict__ dst1, const int* __restrict__ rs1,
                           int* __restrict__ cur1, int* __restrict__ eid1,
                           const int* __restrict__ dst2, const int* __restrict__ rs2,
                           int* __restrict__ cur2, int* __restrict__ eid2) {
  int e = blockIdx.x * 256 + threadIdx.x;
  if (e < NE1) {
    int d = dst1[e];
    eid1[rs1[d] + atomicAdd(cur1 + d, 1)] = e;
  } else if (e - NE1 < NE2) {
    int e2 = e - NE1;
    int d = dst2[e2];
    eid2[rs2[d] + atomicAdd(cur2 + d, 1)] = e2;
  }
}

// ---------------- fused softmax + aggregate (one wave per node) ----------------
__global__ __launch_bounds__(256) void aggregate_k(
    const float* __restrict__ logits, const ushort* __restrict__ xl,
    const int* __restrict__ src, const int* __restrict__ rowstart,
    const int* __restrict__ eid, const float* __restrict__ bias,
    ushort* __restrict__ xnext, int colbase) {
  const int tid = threadIdx.x;
  const int wave = tid >> 6, lane = tid & 63;
  const int nid = blockIdx.x * 4 + wave;
  if (nid >= NNODE) return;
  const int s0 = rowstart[nid], s1 = rowstart[nid + 1];
  float mx = -__int_as_float(0x7f800000);
  for (int i = s0 + lane; i < s1; i += 64) mx = fmaxf(mx, logits[eid[i]]);
#pragma unroll
  for (int d = 1; d < 64; d <<= 1) mx = fmaxf(mx, __shfl_xor(mx, d));
  float den = 0.f;
  for (int i = s0 + lane; i < s1; i += 64) den += __expf(logits[eid[i]] - mx);
#pragma unroll
  for (int d = 1; d < 64; d <<= 1) den += __shfl_xor(den, d);
  float acc0 = 0.f, acc1 = 0.f, acc2 = 0.f, acc3 = 0.f;
  for (int i = s0; i < s1; ++i) {
    int e = eid[i];
    float w = __expf(logits[e] - mx);
    int s = src[e];
    ushort4 v = *(const ushort4*)(xl + (size_t)s * 1024 + lane * 4);
    acc0 += w * b2f(v.x); acc1 += w * b2f(v.y);
    acc2 += w * b2f(v.z); acc3 += w * b2f(v.w);
  }
  float inv = 1.f / (den + 1e-16f);
  int c = lane * 4;
  ushort4 o;
  o.x = f2b(acc0 * inv + bias[c + 0]);
  o.y = f2b(acc1 * inv + bias[c + 1]);
  o.z = f2b(acc2 * inv + bias[c + 2]);
  o.w = f2b(acc3 * inv + bias[c + 3]);
  *(ushort4*)(xnext + (size_t)nid * 512 + colbase + c) = o;
}

// ---------------- generic MFMA GEMM: zero LDS, A & B direct ----------------
// C[M, 256*gridDim.y] = op(A[M,K](bf16) @ W + bias), W as WT[n][k] bf16 (L2-resident).
template <bool RELU, bool OBF16>
__global__ __launch_bounds__(256, 4) void mgemm_k(
    const ushort* __restrict__ A, int lda, const ushort* __restrict__ WT, int K,
    const float* __restrict__ bias, void* __restrict__ C, int ldc, int M) {
  const int tid = threadIdx.x;
  const int wave = tid >> 6, lane = tid & 63;
  const int quad = lane >> 4, l15 = lane & 15;
  const int m0 = blockIdx.x * 64;
  const int ncol0 = blockIdx.y * 256;
  const ushort* WTb = WT + (size_t)ncol0 * K;
  int arow[4];
#pragma unroll
  for (int mi = 0; mi < 4; ++mi) {
    int r = m0 + mi * 16 + l15;
    arow[mi] = r < M ? r : M - 1;
  }
  f32x4 acc[4][4];
#pragma unroll
  for (int i = 0; i < 4; ++i)
#pragma unroll
    for (int j = 0; j < 4; ++j) acc[i][j] = (f32x4){0.f, 0.f, 0.f, 0.f};
  for (int k0 = 0; k0 < K; k0 += 32) {
    bf16x8 bfr[4];
#pragma unroll
    for (int ni = 0; ni < 4; ++ni)
      bfr[ni] = *(const bf16x8*)(WTb + (size_t)(wave * 64 + ni * 16 + l15) * K + k0 + quad * 8);
#pragma unroll
    for (int mi = 0; mi < 4; ++mi) {
      bf16x8 af = *(const bf16x8*)(A + (size_t)arow[mi] * lda + k0 + quad * 8);
#pragma unroll
      for (int ni = 0; ni < 4; ++ni) acc[mi][ni] = MFMA16(af, bfr[ni], acc[mi][ni]);
    }
  }
#pragma unroll
  for (int mi = 0; mi < 4; ++mi)
#pragma unroll
    for (int ni = 0; ni < 4; ++ni) {
      int c = ncol0 + wave * 64 + ni * 16 + l15;
      float bv = bias[c];
#pragma unroll
      for (int r = 0; r < 4; ++r) {
        int m = m0 + mi * 16 + quad * 4 + r;
        if (m < M) {
          float v = acc[mi][ni][r] + bv;
          if (RELU) v = fmaxf(v, 0.f);
          if (OBF16) ((ushort*)C)[(size_t)m * ldc + c] = f2b(v);
          else       ((float*)C)[(size_t)m * ldc + c] = v;
        }
      }
    }
}

// ---------------- fused edge-encoder MLP (64 edges / block) ----------------
__global__ __launch_bounds__(256, 4) void enc_fused_k(
    const float* __restrict__ attr, const float* __restrict__ W0,
    const float* __restrict__ b0, const ushort* __restrict__ W1T,
    const float* __restrict__ b1, const ushort* __restrict__ W2T,
    const float* __restrict__ b2, ushort* __restrict__ eout) {
  __shared__ ushort h[64][264];
  __shared__ float w0s[256], b0s[256];
  const int tid = threadIdx.x;
  const int wave = tid >> 6, lane = tid & 63;
  const int quad = lane >> 4, l15 = lane & 15;
  const int m0 = blockIdx.x * 64;
  const int arow = tid >> 2;
  w0s[tid] = W0[tid];
  b0s[tid] = b0[tid];
  float a0 = attr[m0 + arow];
  __syncthreads();
  {
    int c0 = (tid & 3) * 64;
#pragma unroll
    for (int j = 0; j < 64; j += 4) {
      int c = c0 + j;
      ushort4 o;
      o.x = f2b(fmaxf(a0 * w0s[c + 0] + b0s[c + 0], 0.f));
      o.y = f2b(fmaxf(a0 * w0s[c + 1] + b0s[c + 1], 0.f));
      o.z = f2b(fmaxf(a0 * w0s[c + 2] + b0s[c + 2], 0.f));
      o.w = f2b(fmaxf(a0 * w0s[c + 3] + b0s[c + 3], 0.f));
      *(ushort4*)&h[arow][c] = o;
    }
  }
  __syncthreads();
  // phase A: h1 = relu(h @ W1 + b1)
  f32x4 acc[4][4];
#pragma unroll
  for (int i = 0; i < 4; ++i)
#pragma unroll
    for (int j = 0; j < 4; ++j) acc[i][j] = (f32x4){0.f, 0.f, 0.f, 0.f};
  for (int k0 = 0; k0 < 256; k0 += 32) {
    bf16x8 bfr[4];
#pragma unroll
    for (int ni = 0; ni < 4; ++ni)
      bfr[ni] = *(const bf16x8*)(W1T + (size_t)(wave * 64 + ni * 16 + l15) * 256 + k0 + quad * 8);
#pragma unroll
    for (int mi = 0; mi < 4; ++mi) {
      bf16x8 af = *(const bf16x8*)&h[mi * 16 + l15][k0 + quad * 8];
#pragma unroll
      for (int ni = 0; ni < 4; ++ni) acc[mi][ni] = MFMA16(af, bfr[ni], acc[mi][ni]);
    }
  }
  __syncthreads();
#pragma unroll
  for (int mi = 0; mi < 4; ++mi)
#pragma unroll
    for (int ni = 0; ni < 4; ++ni) {
      int c = wave * 64 + ni * 16 + l15;
      float bv = b1[c];
#pragma unroll
      for (int r = 0; r < 4; ++r)
        h[mi * 16 + quad * 4 + r][c] = f2b(fmaxf(acc[mi][ni][r] + bv, 0.f));
    }
  __syncthreads();
  // phase B: eout = h1 @ W2 + b2
  f32x4 acc2[4][4];
#pragma unroll
  for (int i = 0; i < 4; ++i)
#pragma unroll
    for (int j = 0; j < 4; ++j) acc2[i][j] = (f32x4){0.f, 0.f, 0.f, 0.f};
  for (int k0 = 0; k0 < 256; k0 += 32) {
    bf16x8 bfr[4];
#pragma unroll
    for (int ni = 0; ni < 4; ++ni)
      bfr[ni] = *(const bf16x8*)(W2T + (size_t)(wave * 64 + ni * 16 + l15) * 256 + k0 + quad * 8);
#pragma unroll
    for (int mi = 0; mi < 4; ++mi) {
      bf16x8 af = *(const bf16x8*)&h[mi * 16 + l15][k0 + quad * 8];
#pragma unroll
      for (int ni = 0; ni < 4; ++ni) acc2[mi][ni] = MFMA16(af, bfr[ni], acc2[mi][ni]);
    }
  }
#pragma unroll
  for (int mi = 0; mi < 4; ++mi)
#pragma unroll
    for (int ni = 0; ni < 4; ++ni) {
      int c = wave * 64 + ni * 16 + l15;
      float bv = b2[c];
#pragma unroll
      for (int r = 0; r < 4; ++r) {
        int m = m0 + mi * 16 + quad * 4 + r;
        eout[(size_t)m * 256 + c] = f2b(acc2[mi][ni][r] + bv);
      }
    }
}

// ---------------- fused MFMA attention logits (barrier-free K-loop) ----------------
__global__ __launch_bounds__(256, 3) void attn_mfma_k(
    const ushort* __restrict__ eenc, const ushort* __restrict__ weT,
    const float* __restrict__ att, const ushort* __restrict__ xlr,
    const int* __restrict__ src, const int* __restrict__ dst,
    float* __restrict__ logits) {
  __shared__ ushort xs[64][264];
  __shared__ float red[4][64];
  __shared__ float att_s[256];
  const int tid = threadIdx.x;
  const int wave = tid >> 6, lane = tid & 63;
  const int quad = lane >> 4, l15 = lane & 15;
  const int m0 = blockIdx.x * 64;
  const int arow = tid >> 2;
  att_s[tid] = att[tid];
  {
    int s = src[m0 + arow], d = dst[m0 + arow];
    int c0 = (tid & 3) * 64;
    const ushort* pl = xlr + (size_t)s * 1024;
    const ushort* pr = xlr + (size_t)d * 1024 + 256;
#pragma unroll
    for (int j = 0; j < 16; ++j) {
      int c = c0 + 4 * j;
      ushort4 a = *(const ushort4*)(pl + c);
      ushort4 b = *(const ushort4*)(pr + c);
      ushort4 o;
      o.x = f2b(b2f(a.x) + b2f(b.x)); o.y = f2b(b2f(a.y) + b2f(b.y));
      o.z = f2b(b2f(a.z) + b2f(b.z)); o.w = f2b(b2f(a.w) + b2f(b.w));
      *(ushort4*)&xs[arow][c] = o;
    }
  }
  f32x4 acc[4][4];
#pragma unroll
  for (int i = 0; i < 4; ++i)
#pragma unroll
    for (int j = 0; j < 4; ++j) acc[i][j] = (f32x4){0.f, 0.f, 0.f, 0.f};
  for (int k0 = 0; k0 < 256; k0 += 32) {
    bf16x8 bfr[4];
#pragma unroll
    for (int ni = 0; ni < 4; ++ni)
      bfr[ni] = *(const bf16x8*)(weT + (size_t)(wave * 64 + ni * 16 + l15) * 256 + k0 + quad * 8);
#pragma unroll
    for (int mi = 0; mi < 4; ++mi) {
      bf16x8 af = *(const bf16x8*)(eenc + (size_t)(m0 + mi * 16 + l15) * 256 + k0 + quad * 8);
#pragma unroll
      for (int ni = 0; ni < 4; ++ni) acc[mi][ni] = MFMA16(af, bfr[ni], acc[mi][ni]);
    }
  }
  __syncthreads();  // xs fully staged (covers pre-loop writes)
  float part[4][4];
#pragma unroll
  for (int mi = 0; mi < 4; ++mi)
#pragma unroll
    for (int r = 0; r < 4; ++r) part[mi][r] = 0.f;
#pragma unroll
  for (int mi = 0; mi < 4; ++mi)
#pragma unroll
    for (int ni = 0; ni < 4; ++ni) {
      int c = wave * 64 + ni * 16 + l15;
      float av = att_s[c];
#pragma unroll
      for (int r = 0; r < 4; ++r) {
        int row = mi * 16 + quad * 4 + r;
        float v = acc[mi][ni][r] + b2f(xs[row][c]);
        v = v > 0.f ? v : 0.2f * v;
        part[mi][r] += v * av;
      }
    }
#pragma unroll
  for (int d = 1; d < 16; d <<= 1)
#pragma unroll
    for (int mi = 0; mi < 4; ++mi)
#pragma unroll
      for (int r = 0; r < 4; ++r) part[mi][r] += __shfl_xor(part[mi][r], d);
  if (l15 == 0)
#pragma unroll
    for (int mi = 0; mi < 4; ++mi)
#pragma unroll
      for (int r = 0; r < 4; ++r) red[wave][mi * 16 + quad * 4 + r] = part[mi][r];
  __syncthreads();
  if (tid < 64)
    logits[m0 + tid] = red[0][tid] + red[1][tid] + red[2][tid] + red[3][tid];
}

// ---------------- decomposed MFMA decoder (barrier-free K-loops) ----------------
__global__ __launch_bounds__(256, 3) void dec2_k(
    const ushort* __restrict__ e1, const ushort* __restrict__ W0cT,
    const float* __restrict__ Z, const float* __restrict__ b0,
    const ushort* __restrict__ W1T, const float* __restrict__ b1,
    const float* __restrict__ W2, const float* __restrict__ b2,
    const int* __restrict__ src, const int* __restrict__ dst,
    float* __restrict__ out) {
  __shared__ ushort h0[64][264];
  __shared__ float red[4][64];
  const int tid = threadIdx.x;
  const int wave = tid >> 6, lane = tid & 63;
  const int quad = lane >> 4, l15 = lane & 15;
  const int m0 = blockIdx.x * 64;
  const int arow = tid >> 2;
  {  // pre-stage h0 = bf16(Za[src] + Zb[dst])
    int gs = src[m0 + arow], gd = dst[m0 + arow];
    int c0 = (tid & 3) * 64;
    const float* za = Z + (size_t)gs * 512;
    const float* zb = Z + (size_t)gd * 512 + 256;
#pragma unroll
    for (int j = 0; j < 16; ++j) {
      int c = c0 + 4 * j;
      float4 a = *(const float4*)(za + c);
      float4 b = *(const float4*)(zb + c);
      ushort4 o;
      o.x = f2b(a.x + b.x); o.y = f2b(a.y + b.y);
      o.z = f2b(a.z + b.z); o.w = f2b(a.w + b.w);
      *(ushort4*)&h0[arow][c] = o;
    }
  }
  // phase 1: acc = e1 @ W0c (A direct from e1, B direct from L2)
  f32x4 acc[4][4];
#pragma unroll
  for (int i = 0; i < 4; ++i)
#pragma unroll
    for (int j = 0; j < 4; ++j) acc[i][j] = (f32x4){0.f, 0.f, 0.f, 0.f};
  for (int k0 = 0; k0 < 256; k0 += 32) {
    bf16x8 bfr[4];
#pragma unroll
    for (int ni = 0; ni < 4; ++ni)
      bfr[ni] = *(const bf16x8*)(W0cT + (size_t)(wave * 64 + ni * 16 + l15) * 256 + k0 + quad * 8);
#pragma unroll
    for (int mi = 0; mi < 4; ++mi) {
      bf16x8 af = *(const bf16x8*)(e1 + (size_t)(m0 + mi * 16 + l15) * 256 + k0 + quad * 8);
#pragma unroll
      for (int ni = 0; ni < 4; ++ni) acc[mi][ni] = MFMA16(af, bfr[ni], acc[mi][ni]);
    }
  }
  __syncthreads();  // h0 staging complete before epilogue read-modify-write
#pragma unroll
  for (int mi = 0; mi < 4; ++mi)
#pragma unroll
    for (int ni = 0; ni < 4; ++ni) {
      int c = wave * 64 + ni * 16 + l15;
      float bv = b0[c];
#pragma unroll
      for (int r = 0; r < 4; ++r) {
        int row = mi * 16 + quad * 4 + r;
        h0[row][c] = f2b(fmaxf(acc[mi][ni][r] + b2f(h0[row][c]) + bv, 0.f));
      }
    }
  __syncthreads();
  // phase 2: h1 = relu(h0 @ W1 + b1); out = h1 . W2 + b2
  f32x4 acc2[4][4];
#pragma unroll
  for (int i = 0; i < 4; ++i)
#pragma unroll
    for (int j = 0; j < 4; ++j) acc2[i][j] = (f32x4){0.f, 0.f, 0.f, 0.f};
  for (int k0 = 0; k0 < 256; k0 += 32) {
    bf16x8 bfr[4];
#pragma unroll
    for (int ni = 0; ni < 4; ++ni)
      bfr[ni] = *(const bf16x8*)(W1T + (size_t)(wave * 64 + ni * 16 + l15) * 256 + k0 + quad * 8);
#pragma unroll
    for (int mi = 0; mi < 4; ++mi) {
      bf16x8 af = *(const bf16x8*)&h0[mi * 16 + l15][k0 + quad * 8];
#pragma unroll
      for (int ni = 0; ni < 4; ++ni) acc2[mi][ni] = MFMA16(af, bfr[ni], acc2[mi][ni]);
    }
  }
  float part[4][4];
#pragma unroll
  for (int mi = 0; mi < 4; ++mi)
#pragma unroll
    for (int r = 0; r < 4; ++r) part[mi][r] = 0.f;
#pragma unroll
  for (int mi = 0; mi < 4; ++mi)
#pragma unroll
    for (int ni = 0; ni < 4; ++ni) {
      int c = wave * 64 + ni * 16 + l15;
      float bv = b1[c], wv = W2[c];
#pragma unroll
      for (int r = 0; r < 4; ++r) {
        float v = fmaxf(acc2[mi][ni][r] + bv, 0.f);
        part[mi][r] += v * wv;
      }
    }
#pragma unroll
  for (int d = 1; d < 16; d <<= 1)
#pragma unroll
    for (int mi = 0; mi < 4; ++mi)
#pragma unroll
      for (int r = 0; r < 4; ++r) part[mi][r] += __shfl_xor(part[mi][r], d);
  if (l15 == 0)
#pragma unroll
    for (int mi = 0; mi < 4; ++mi)
#pragma unroll
      for (int r = 0; r < 4; ++r) red[wave][mi * 16 + quad * 4 + r] = part[mi][r];
  __syncthreads();
  if (tid < 64) {
    float s = red[0][tid] + red[1][tid] + red[2][tid] + red[3][tid];
    out[m0 + tid] = s + b2[0];
  }
}

// ---------------- host ----------------

extern "C" void kernel_launch(void* const* d_in, const int* in_sizes, int n_in,
                              void* d_out, int out_size, void* d_ws, size_t ws_size,
                              hipStream_t stream) {
  const int*   eidx1  = (const int*)d_in[0];
  const float* eattr1 = (const float*)d_in[1];
  const int*   eidx2  = (const int*)d_in[2];
  const float* eattr2 = (const float*)d_in[3];
  const int*   batch  = (const int*)d_in[4];
  const float* tval   = (const float*)d_in[5];
  const float* te_W0 = (const float*)d_in[6];
  const float* te_b0 = (const float*)d_in[7];
  const float* te_W1 = (const float*)d_in[8];
  const float* te_b1 = (const float*)d_in[9];
  const float* te_W2 = (const float*)d_in[10];
  const float* te_b2 = (const float*)d_in[11];
  const float* ee_W0 = (const float*)d_in[12];
  const float* ee_b0 = (const float*)d_in[13];
  const float* ee_W1 = (const float*)d_in[14];
  const float* ee_b1 = (const float*)d_in[15];
  const float* ee_W2 = (const float*)d_in[16];
  const float* ee_b2 = (const float*)d_in[17];
  const float* dec_W0 = (const float*)d_in[18];
  const float* dec_b0 = (const float*)d_in[19];
  const float* dec_W1 = (const float*)d_in[20];
  const float* dec_b1 = (const float*)d_in[21];
  const float* dec_W2 = (const float*)d_in[22];
  const float* dec_b2 = (const float*)d_in[23];
  const float* gg_Wl  = (const float*)d_in[24];
  const float* gg_bl  = (const float*)d_in[25];
  const float* gg_Wr  = (const float*)d_in[26];
  const float* gg_br  = (const float*)d_in[27];
  const float* gg_We  = (const float*)d_in[28];
  const float* gg_att = (const float*)d_in[29];
  const float* gg_bias= (const float*)d_in[30];
  const float* gf_Wl  = (const float*)d_in[31];
  const float* gf_bl  = (const float*)d_in[32];
  const float* gf_Wr  = (const float*)d_in[33];
  const float* gf_br  = (const float*)d_in[34];
  const float* gf_We  = (const float*)d_in[35];
  const float* gf_att = (const float*)d_in[36];
  const float* gf_bias= (const float*)d_in[37];
  (void)in_sizes; (void)n_in; (void)out_size; (void)ws_size;

  const int* src1 = eidx1;
  const int* dst1 = eidx1 + NE1;
  const int* src2 = eidx2;
  const int* dst2 = eidx2 + NE2;

  char* base = (char*)d_ws;
  size_t off = 0;
  auto alloc = [&](size_t bytes) {
    void* p = base + off;
    off += (bytes + 255) & ~(size_t)255;
    return p;
  };
  ushort* x_a    = (ushort*)alloc((size_t)NNODE * 512 * 2);
  ushort* x_b    = (ushort*)alloc((size_t)NNODE * 512 * 2);
  ushort* xlr    = (ushort*)alloc((size_t)NNODE * 1024 * 2);
  float*  Z      = (float*)alloc((size_t)NNODE * 512 * 4);
  ushort* e1     = (ushort*)alloc((size_t)NE1 * Hd * 2);
  ushort* e2     = (ushort*)alloc((size_t)NE2 * Hd * 2);
  float*  logits = (float*)alloc((size_t)NE1 * 4);
  float*  tenc   = (float*)alloc((size_t)16 * Hd * 4);
  ushort* eeW1T  = (ushort*)alloc((size_t)256 * 256 * 2);
  ushort* eeW2T  = (ushort*)alloc((size_t)256 * 256 * 2);
  ushort* decZT  = (ushort*)alloc((size_t)512 * 512 * 2);
  ushort* decW0cT= (ushort*)alloc((size_t)256 * 256 * 2);
  ushort* decW1T = (ushort*)alloc((size_t)256 * 256 * 2);
  ushort* wlrT   = (ushort*)alloc((size_t)6 * 512 * 512 * 2);  // [2*i+g]
  ushort* weT    = (ushort*)alloc((size_t)6 * 256 * 256 * 2);  // [2*i+g]
  float*  biascat= (float*)alloc((size_t)6 * 1024 * 4);
  float*  zerob  = (float*)alloc((size_t)512 * 4);
  int* cnt1      = (int*)alloc((size_t)NNODE * 4);
  int* cur1      = (int*)alloc((size_t)NNODE * 4);
  int* rs1       = (int*)alloc((size_t)(NNODE + 1) * 4);
  int* eid1      = (int*)alloc((size_t)NE1 * 4);
  int* cnt2      = (int*)alloc((size_t)NNODE * 4);
  int* cur2      = (int*)alloc((size_t)NNODE * 4);
  int* rs2       = (int*)alloc((size_t)(NNODE + 1) * 4);
  int* eid2      = (int*)alloc((size_t)NE2 * 4);

  float* out = (float*)d_out;

  // ---- merged setup ----
  init_small_k<<<(NNODE + 512 + 6144 + 255) / 256, 256, 0, stream>>>(
      cnt1, cur1, cnt2, cur2, zerob, biascat, gg_bl, gg_br, gf_bl, gf_br);

  TransArgs ta;
  int nt = 0, cum = 0;
  auto add = [&](const float* s, ushort* d, int K, int noff, int ld) {
    ta.t[nt].src = s; ta.t[nt].dst = d; ta.t[nt].K = K;
    ta.t[nt].n_off = noff; ta.t[nt].ld = ld; ta.t[nt].start = cum;
    cum += (K / 32) * 8; ++nt;
  };
  add(ee_W1, eeW1T, 256, 0, 256);
  add(ee_W2, eeW2T, 256, 0, 256);
  add(dec_W1, decW1T, 256, 0, 256);
  add(dec_W0, decZT, 512, 0, 512);
  add(dec_W0 + 512 * 256, decZT, 512, 256, 512);
  add(dec_W0 + 1024 * 256, decW0cT, 256, 0, 256);
  for (int i = 0; i < 3; ++i) {
    add(gg_Wl + (size_t)i * 512 * 256, wlrT + (size_t)(2 * i) * 512 * 512, 512, 0, 512);
    add(gg_Wr + (size_t)i * 512 * 256, wlrT + (size_t)(2 * i) * 512 * 512, 512, 256, 512);
    add(gf_Wl + (size_t)i * 512 * 256, wlrT + (size_t)(2 * i + 1) * 512 * 512, 512, 0, 512);
    add(gf_Wr + (size_t)i * 512 * 256, wlrT + (size_t)(2 * i + 1) * 512 * 512, 512, 256, 512);
    add(gg_We + (size_t)i * 65536, weT + (size_t)(2 * i) * 65536, 256, 0, 256);
    add(gf_We + (size_t)i * 65536, weT + (size_t)(2 * i + 1) * 65536, 256, 0, 256);
  }
  trans_all_k<<<cum, 256, 0, stream>>>(ta);

  // ---- CSR build ----
  deg_all_k<<<(NE1 + NE2) / 256, 256, 0, stream>>>(dst1, cnt1, dst2, cnt2);
  scan_k<<<2, 640, 0, stream>>>(cnt1, rs1, cnt2, rs2);
  fill_all_k<<<(NE1 + NE2) / 256, 256, 0, stream>>>(dst1, rs1, cur1, eid1, dst2, rs2, cur2, eid2);

  // ---- fused edge encoder ----
  enc_fused_k<<<NE1 / 64, 256, 0, stream>>>(eattr1, ee_W0, ee_b0, eeW1T, ee_b1, eeW2T, ee_b2, e1);
  enc_fused_k<<<NE2 / 64, 256, 0, stream>>>(eattr2, ee_W0, ee_b0, eeW1T, ee_b1, eeW2T, ee_b2, e2);

  // ---- time encoding -> x0 (bf16) ----
  time_mlp_k<<<16, 256, 0, stream>>>(tval, te_W0, te_b0, te_W1, te_b1, te_W2, te_b2, tenc);
  build_x0_k<<<(NNODE * 512) / 256, 256, 0, stream>>>(batch, tenc, x_a);

  ushort* x_cur = x_a;
  ushort* x_nxt = x_b;
  const int ngrid = (NNODE + 63) / 64;
  const int agrid = (NNODE + 3) / 4;
  for (int i = 0; i < 3; ++i) {
    mgemm_k<false, true><<<dim3(ngrid, 4), 256, 0, stream>>>(
        x_cur, 512, wlrT + (size_t)(2 * i) * 512 * 512, 512, biascat + (size_t)i * 1024, xlr, 1024, NNODE);
    attn_mfma_k<<<NE1 / 64, 256, 0, stream>>>(e1, weT + (size_t)(2 * i) * 65536, gg_att + i * Hd,
                                              xlr, src1, dst1, logits);
    aggregate_k<<<agrid, 256, 0, stream>>>(logits, xlr, src1, rs1, eid1, gg_bias + i * Hd, x_nxt, 0);
    attn_mfma_k<<<NE2 / 64, 256, 0, stream>>>(e2, weT + (size_t)(2 * i + 1) * 65536, gf_att + i * Hd,
                                              xlr + 512, src2, dst2, logits);
    aggregate_k<<<agrid, 256, 0, stream>>>(logits, xlr + 512, src2, rs2, eid2, gf_bias + i * Hd, x_nxt, 256);
    ushort* t = x_cur; x_cur = x_nxt; x_nxt = t;
  }

  // ---- decoder ----
  mgemm_k<false, false><<<dim3(ngrid, 2), 256, 0, stream>>>(
      x_cur, 512, decZT, 512, zerob, Z, 512, NNODE);
  dec2_k<<<NE1 / 64, 256, 0, stream>>>(e1, decW0cT, Z, dec_b0, decW1T, dec_b1,
                                       dec_W2, dec_b2, src1, dst1, out);
}

// Round 7
// 1096.460 us; speedup vs baseline: 1.1979x; 1.1979x over previous
//
#include <hip/hip_runtime.h>

#define Hd 256
#define NNODE 10000
#define NE1 131072
#define NE2 65536

typedef __attribute__((ext_vector_type(8))) short bf16x8;
typedef __attribute__((ext_vector_type(4))) float f32x4;

#define MFMA16(a, b, c) __builtin_amdgcn_mfma_f32_16x16x32_bf16((a), (b), (c), 0, 0, 0)

__device__ __forceinline__ float b2f(ushort u) { return __uint_as_float(((unsigned)u) << 16); }
__device__ __forceinline__ ushort f2b(float f) {
  unsigned u = __float_as_uint(f);
  return (ushort)((u + 0x7fffu + ((u >> 16) & 1u)) >> 16);
}

// ---------------- small kernels ----------------

__global__ void time_mlp_k(const float* __restrict__ tval,
                           const float* __restrict__ W0, const float* __restrict__ b0,
                           const float* __restrict__ W1, const float* __restrict__ b1,
                           const float* __restrict__ W2, const float* __restrict__ b2,
                           float* __restrict__ tenc) {
  __shared__ float h0[Hd], h1[Hd];
  int b = blockIdx.x, j = threadIdx.x;
  float t = tval[b];
  h0[j] = fmaxf(t * W0[j] + b0[j], 0.f);
  __syncthreads();
  float a = b1[j];
  for (int k = 0; k < Hd; ++k) a += h0[k] * W1[k * Hd + j];
  h1[j] = fmaxf(a, 0.f);
  __syncthreads();
  float c = b2[j];
  for (int k = 0; k < Hd; ++k) c += h1[k] * W2[k * Hd + j];
  tenc[b * Hd + j] = c;
}

__global__ void build_x0_k(const int* __restrict__ batch, const float* __restrict__ tenc,
                           ushort* __restrict__ x0) {
  int idx = blockIdx.x * 256 + threadIdx.x;
  int n = idx >> 9;
  x0[idx] = f2b(tenc[batch[n] * Hd + (idx & 255)]);
}

__global__ void init_small_k(int* __restrict__ cnt1, int* __restrict__ cur1,
                             int* __restrict__ cnt2, int* __restrict__ cur2,
                             float* __restrict__ zerob, float* __restrict__ biascat,
                             const float* __restrict__ gg_bl, const float* __restrict__ gg_br,
                             const float* __restrict__ gf_bl, const float* __restrict__ gf_br) {
  int i = blockIdx.x * 256 + threadIdx.x;
  if (i < NNODE) { cnt1[i] = 0; cur1[i] = 0; cnt2[i] = 0; cur2[i] = 0; return; }
  i -= NNODE;
  if (i < 512) { zerob[i] = 0.f; return; }
  i -= 512;
  if (i < 6144) {
    int layer = i >> 10, c = i & 1023;
    float v;
    if (c < 256)      v = gg_bl[layer * 256 + c];
    else if (c < 512) v = gg_br[layer * 256 + c - 256];
    else if (c < 768) v = gf_bl[layer * 256 + c - 512];
    else              v = gf_br[layer * 256 + c - 768];
    biascat[layer * 1024 + c] = v;
  }
}

// ---------------- merged weight transposes ----------------
struct TT { const float* src; ushort* dst; int K; int n_off; int ld; int start; };
struct TransArgs { TT t[24]; };

__global__ void trans_all_k(TransArgs a) {
  int b = blockIdx.x;
  int ti = 0;
  while (ti + 1 < 24 && a.t[ti + 1].start <= b) ++ti;
  TT tk = a.t[ti];
  int lb = b - tk.start;
  int gx = tk.K >> 5;
  int k0 = (lb % gx) * 32, n0 = (lb / gx) * 32;
  __shared__ float t[32][33];
  int tx = threadIdx.x & 31, ty = threadIdx.x >> 5;
#pragma unroll
  for (int p = 0; p < 4; ++p)
    t[ty + 8 * p][tx] = tk.src[(size_t)(k0 + ty + 8 * p) * 256 + n0 + tx];
  __syncthreads();
#pragma unroll
  for (int p = 0; p < 4; ++p)
    tk.dst[(size_t)(tk.n_off + n0 + ty + 8 * p) * tk.ld + k0 + tx] = f2b(t[tx][ty + 8 * p]);
}

// ---------------- CSR build (by dst) ----------------

__global__ void deg_all_k(const int* __restrict__ dst1, int* __restrict__ cnt1,
                          const int* __restrict__ dst2, int* __restrict__ cnt2) {
  int e = blockIdx.x * 256 + threadIdx.x;
  if (e < NE1) atomicAdd(cnt1 + dst1[e], 1);
  else if (e - NE1 < NE2) atomicAdd(cnt2 + dst2[e - NE1], 1);
}

__global__ void scan_k(const int* __restrict__ cnt1, int* __restrict__ rs1,
                       const int* __restrict__ cnt2, int* __restrict__ rs2) {
  const int g = blockIdx.x;
  const int* cnt = g ? cnt2 : cnt1;
  int* rowstart = g ? rs2 : rs1;
  const int E = g ? NE2 : NE1;
  __shared__ int part[626];
  int t = threadIdx.x;
  if (t < 625) {
    int s = 0;
#pragma unroll
    for (int i = 0; i < 16; ++i) s += cnt[t * 16 + i];
    part[t] = s;
  }
  __syncthreads();
  if (t == 0) {
    int run = 0;
    for (int i = 0; i < 625; ++i) { int v = part[i]; part[i] = run; run += v; }
  }
  __syncthreads();
  if (t < 625) {
    int off = part[t];
#pragma unroll
    for (int i = 0; i < 16; ++i) { rowstart[t * 16 + i] = off; off += cnt[t * 16 + i]; }
  }
  if (t == 0) rowstart[NNODE] = E;
}

__global__ void fill_all_k(const int* __restrict__ dst1, const int* __restrict__ rs1,
                           int* __restrict__ cur1, int* __restrict__ eid1,
                           const int* __restrict__ dst2, const int* __restrict__ rs2,
                           int* __restrict__ cur2, int* __restrict__ eid2) {
  int e = blockIdx.x * 256 + threadIdx.x;
  if (e < NE1) {
    int d = dst1[e];
    eid1[rs1[d] + atomicAdd(cur1 + d, 1)] = e;
  } else if (e - NE1 < NE2) {
    int e2 = e - NE1;
    int d = dst2[e2];
    eid2[rs2[d] + atomicAdd(cur2 + d, 1)] = e2;
  }
}

// ---------------- 128-row-tile MFMA GEMM: A direct, B LDS-staged ----------------
// C[M, 256*gridDim.y] = A[M,K](bf16) @ WT^T + bias.  W as WT[n][k] bf16.
template <bool OBF16>
__global__ __launch_bounds__(256, 2) void mgemm128_k(
    const ushort* __restrict__ A, int lda, const ushort* __restrict__ WT, int K,
    const float* __restrict__ bias, void* __restrict__ C, int ldc, int M) {
  __shared__ ushort Bs[256][40];
  const int tid = threadIdx.x;
  const int wave = tid >> 6, lane = tid & 63;
  const int quad = lane >> 4, l15 = lane & 15;
  const int m0 = blockIdx.x * 128;
  const int ncol0 = blockIdx.y * 256;
  const ushort* WTb = WT + (size_t)ncol0 * K;
  const int brow = tid >> 2, bkc = (tid & 3) << 3;
  int arow[8];
#pragma unroll
  for (int mi = 0; mi < 8; ++mi) {
    int r = m0 + mi * 16 + l15;
    arow[mi] = r < M ? r : M - 1;
  }
  f32x4 acc[8][4];
#pragma unroll
  for (int i = 0; i < 8; ++i)
#pragma unroll
    for (int j = 0; j < 4; ++j) acc[i][j] = (f32x4){0.f, 0.f, 0.f, 0.f};
  for (int k0 = 0; k0 < K; k0 += 32) {
#pragma unroll
    for (int r = 0; r < 4; ++r) {
      int row = brow + r * 64;
      *(uint4*)&Bs[row][bkc] = *(const uint4*)(WTb + (size_t)row * K + k0 + bkc);
    }
    __syncthreads();
    bf16x8 bfr[4];
#pragma unroll
    for (int ni = 0; ni < 4; ++ni)
      bfr[ni] = *(const bf16x8*)&Bs[wave * 64 + ni * 16 + l15][quad * 8];
#pragma unroll
    for (int mi = 0; mi < 8; ++mi) {
      bf16x8 af = *(const bf16x8*)(A + (size_t)arow[mi] * lda + k0 + quad * 8);
#pragma unroll
      for (int ni = 0; ni < 4; ++ni) acc[mi][ni] = MFMA16(af, bfr[ni], acc[mi][ni]);
    }
    __syncthreads();
  }
#pragma unroll
  for (int mi = 0; mi < 8; ++mi)
#pragma unroll
    for (int ni = 0; ni < 4; ++ni) {
      int c = ncol0 + wave * 64 + ni * 16 + l15;
      float bv = bias[c];
#pragma unroll
      for (int r = 0; r < 4; ++r) {
        int m = m0 + mi * 16 + quad * 4 + r;
        if (m < M) {
          float v = acc[mi][ni][r] + bv;
          if (OBF16) ((ushort*)C)[(size_t)m * ldc + c] = f2b(v);
          else       ((float*)C)[(size_t)m * ldc + c] = v;
        }
      }
    }
}

// ---------------- fused edge-encoder MLP (both graphs, 64 edges/block) ----------------
__global__ __launch_bounds__(256, 2) void enc_fused_k(
    const float* __restrict__ attr1, ushort* __restrict__ e1,
    const float* __restrict__ attr2, ushort* __restrict__ e2,
    const float* __restrict__ W0, const float* __restrict__ b0,
    const ushort* __restrict__ W1T, const float* __restrict__ b1,
    const ushort* __restrict__ W2T, const float* __restrict__ b2) {
  __shared__ ushort h[64][264];
  __shared__ ushort Bs[256][40];
  __shared__ float w0s[256], b0s[256];
  const int tid = threadIdx.x;
  const int wave = tid >> 6, lane = tid & 63;
  const int quad = lane >> 4, l15 = lane & 15;
  const float* attr;
  ushort* eout;
  int m0;
  if (blockIdx.x < NE1 / 64) { attr = attr1; eout = e1; m0 = blockIdx.x * 64; }
  else { attr = attr2; eout = e2; m0 = (blockIdx.x - NE1 / 64) * 64; }
  const int arow = tid >> 2, akc = (tid & 3) << 3;
  w0s[tid] = W0[tid];
  b0s[tid] = b0[tid];
  float a0 = attr[m0 + arow];
  __syncthreads();
  {
    int c0 = (tid & 3) * 64;
#pragma unroll
    for (int j = 0; j < 64; j += 4) {
      int c = c0 + j;
      ushort4 o;
      o.x = f2b(fmaxf(a0 * w0s[c + 0] + b0s[c + 0], 0.f));
      o.y = f2b(fmaxf(a0 * w0s[c + 1] + b0s[c + 1], 0.f));
      o.z = f2b(fmaxf(a0 * w0s[c + 2] + b0s[c + 2], 0.f));
      o.w = f2b(fmaxf(a0 * w0s[c + 3] + b0s[c + 3], 0.f));
      *(ushort4*)&h[arow][c] = o;
    }
  }
  __syncthreads();
  // phase A: h1 = relu(h @ W1 + b1)
  f32x4 acc[4][4];
#pragma unroll
  for (int i = 0; i < 4; ++i)
#pragma unroll
    for (int j = 0; j < 4; ++j) acc[i][j] = (f32x4){0.f, 0.f, 0.f, 0.f};
  for (int k0 = 0; k0 < 256; k0 += 32) {
#pragma unroll
    for (int r = 0; r < 4; ++r) {
      int row = arow + r * 64;
      *(uint4*)&Bs[row][akc] = *(const uint4*)(W1T + (size_t)row * 256 + k0 + akc);
    }
    __syncthreads();
    bf16x8 bfr[4];
#pragma unroll
    for (int ni = 0; ni < 4; ++ni)
      bfr[ni] = *(const bf16x8*)&Bs[wave * 64 + ni * 16 + l15][quad * 8];
#pragma unroll
    for (int mi = 0; mi < 4; ++mi) {
      bf16x8 af = *(const bf16x8*)&h[mi * 16 + l15][k0 + quad * 8];
#pragma unroll
      for (int ni = 0; ni < 4; ++ni) acc[mi][ni] = MFMA16(af, bfr[ni], acc[mi][ni]);
    }
    __syncthreads();
  }
#pragma unroll
  for (int mi = 0; mi < 4; ++mi)
#pragma unroll
    for (int ni = 0; ni < 4; ++ni) {
      int c = wave * 64 + ni * 16 + l15;
      float bv = b1[c];
#pragma unroll
      for (int r = 0; r < 4; ++r)
        h[mi * 16 + quad * 4 + r][c] = f2b(fmaxf(acc[mi][ni][r] + bv, 0.f));
    }
  __syncthreads();
  // phase B: eout = h1 @ W2 + b2
  f32x4 acc2[4][4];
#pragma unroll
  for (int i = 0; i < 4; ++i)
#pragma unroll
    for (int j = 0; j < 4; ++j) acc2[i][j] = (f32x4){0.f, 0.f, 0.f, 0.f};
  for (int k0 = 0; k0 < 256; k0 += 32) {
#pragma unroll
    for (int r = 0; r < 4; ++r) {
      int row = arow + r * 64;
      *(uint4*)&Bs[row][akc] = *(const uint4*)(W2T + (size_t)row * 256 + k0 + akc);
    }
    __syncthreads();
    bf16x8 bfr[4];
#pragma unroll
    for (int ni = 0; ni < 4; ++ni)
      bfr[ni] = *(const bf16x8*)&Bs[wave * 64 + ni * 16 + l15][quad * 8];
#pragma unroll
    for (int mi = 0; mi < 4; ++mi) {
      bf16x8 af = *(const bf16x8*)&h[mi * 16 + l15][k0 + quad * 8];
#pragma unroll
      for (int ni = 0; ni < 4; ++ni) acc2[mi][ni] = MFMA16(af, bfr[ni], acc2[mi][ni]);
    }
    __syncthreads();
  }
#pragma unroll
  for (int mi = 0; mi < 4; ++mi)
#pragma unroll
    for (int ni = 0; ni < 4; ++ni) {
      int c = wave * 64 + ni * 16 + l15;
      float bv = b2[c];
#pragma unroll
      for (int r = 0; r < 4; ++r) {
        int m = m0 + mi * 16 + quad * 4 + r;
        eout[(size_t)m * 256 + c] = f2b(acc2[mi][ni][r] + bv);
      }
    }
}

// ---------------- fused online-softmax attention aggregate (one wave/node) ----------------
// logit_e = att . leakyrelu(xl[src] + xr[nid] + ew[e]);  out = softmax-weighted sum of xl.
__global__ __launch_bounds__(256) void agg2_k(
    const ushort* __restrict__ ew, const ushort* __restrict__ xlr, int goff,
    const int* __restrict__ src, const int* __restrict__ rowstart,
    const int* __restrict__ eid, const float* __restrict__ att,
    const float* __restrict__ bias, ushort* __restrict__ xnext, int colbase) {
  __shared__ float att_s[256], bias_s[256];
  const int tid = threadIdx.x;
  att_s[tid] = att[tid];
  bias_s[tid] = bias[tid];
  __syncthreads();
  const int wave = tid >> 6, lane = tid & 63;
  const int nid = blockIdx.x * 4 + wave;
  if (nid >= NNODE) return;
  const int c = lane * 4;
  const ushort* xr = xlr + (size_t)nid * 1024 + goff + 256;
  float xr0 = b2f(xr[c]), xr1 = b2f(xr[c + 1]), xr2 = b2f(xr[c + 2]), xr3 = b2f(xr[c + 3]);
  float a0 = att_s[c], a1 = att_s[c + 1], a2 = att_s[c + 2], a3 = att_s[c + 3];
  const int s0 = rowstart[nid], s1 = rowstart[nid + 1];
  float m = -__int_as_float(0x7f800000);
  float den = 0.f, ac0 = 0.f, ac1 = 0.f, ac2 = 0.f, ac3 = 0.f;
  for (int i = s0; i < s1; ++i) {
    int e = eid[i], s = src[e];
    ushort4 xv = *(const ushort4*)(xlr + (size_t)s * 1024 + goff + c);
    ushort4 ev = *(const ushort4*)(ew + (size_t)e * 256 + c);
    float x0 = b2f(xv.x), x1 = b2f(xv.y), x2 = b2f(xv.z), x3 = b2f(xv.w);
    float z0 = x0 + xr0 + b2f(ev.x);
    float z1 = x1 + xr1 + b2f(ev.y);
    float z2 = x2 + xr2 + b2f(ev.z);
    float z3 = x3 + xr3 + b2f(ev.w);
    z0 = z0 > 0.f ? z0 : 0.2f * z0;
    z1 = z1 > 0.f ? z1 : 0.2f * z1;
    z2 = z2 > 0.f ? z2 : 0.2f * z2;
    z3 = z3 > 0.f ? z3 : 0.2f * z3;
    float p = z0 * a0 + z1 * a1 + z2 * a2 + z3 * a3;
#pragma unroll
    for (int d = 1; d < 64; d <<= 1) p += __shfl_xor(p, d);
    float mn = fmaxf(m, p);
    float sc = __expf(m - mn);
    float w = __expf(p - mn);
    den = den * sc + w;
    ac0 = ac0 * sc + w * x0;
    ac1 = ac1 * sc + w * x1;
    ac2 = ac2 * sc + w * x2;
    ac3 = ac3 * sc + w * x3;
    m = mn;
  }
  float inv = 1.f / (den + 1e-16f);
  ushort4 o;
  o.x = f2b(ac0 * inv + bias_s[c + 0]);
  o.y = f2b(ac1 * inv + bias_s[c + 1]);
  o.z = f2b(ac2 * inv + bias_s[c + 2]);
  o.w = f2b(ac3 * inv + bias_s[c + 3]);
  *(ushort4*)(xnext + (size_t)nid * 512 + colbase + c) = o;
}

// ---------------- decomposed MFMA decoder (A direct, B LDS-staged) ----------------
__global__ __launch_bounds__(256, 2) void dec2_k(
    const ushort* __restrict__ e1, const ushort* __restrict__ W0cT,
    const float* __restrict__ Z, const float* __restrict__ b0,
    const ushort* __restrict__ W1T, const float* __restrict__ b1,
    const float* __restrict__ W2, const float* __restrict__ b2,
    const int* __restrict__ src, const int* __restrict__ dst,
    float* __restrict__ out) {
  __shared__ ushort Bs[256][40];
  __shared__ ushort h0[64][264];
  __shared__ float red[4][64];
  const int tid = threadIdx.x;
  const int wave = tid >> 6, lane = tid & 63;
  const int quad = lane >> 4, l15 = lane & 15;
  const int m0 = blockIdx.x * 64;
  const int arow = tid >> 2, akc = (tid & 3) << 3;
  {  // pre-stage h0 = bf16(Za[src] + Zb[dst])
    int gs = src[m0 + arow], gd = dst[m0 + arow];
    int c0 = (tid & 3) * 64;
    const float* za = Z + (size_t)gs * 512;
    const float* zb = Z + (size_t)gd * 512 + 256;
#pragma unroll
    for (int j = 0; j < 16; ++j) {
      int c = c0 + 4 * j;
      float4 a = *(const float4*)(za + c);
      float4 b = *(const float4*)(zb + c);
      ushort4 o;
      o.x = f2b(a.x + b.x); o.y = f2b(a.y + b.y);
      o.z = f2b(a.z + b.z); o.w = f2b(a.w + b.w);
      *(ushort4*)&h0[arow][c] = o;
    }
  }
  // phase 1: acc = e1 @ W0c  (A direct — e1 rows contiguous; B staged)
  f32x4 acc[4][4];
#pragma unroll
  for (int i = 0; i < 4; ++i)
#pragma unroll
    for (int j = 0; j < 4; ++j) acc[i][j] = (f32x4){0.f, 0.f, 0.f, 0.f};
  for (int k0 = 0; k0 < 256; k0 += 32) {
#pragma unroll
    for (int r = 0; r < 4; ++r) {
      int row = arow + r * 64;
      *(uint4*)&Bs[row][akc] = *(const uint4*)(W0cT + (size_t)row * 256 + k0 + akc);
    }
    __syncthreads();
    bf16x8 bfr[4];
#pragma unroll
    for (int ni = 0; ni < 4; ++ni)
      bfr[ni] = *(const bf16x8*)&Bs[wave * 64 + ni * 16 + l15][quad * 8];
#pragma unroll
    for (int mi = 0; mi < 4; ++mi) {
      bf16x8 af = *(const bf16x8*)(e1 + (size_t)(m0 + mi * 16 + l15) * 256 + k0 + quad * 8);
#pragma unroll
      for (int ni = 0; ni < 4; ++ni) acc[mi][ni] = MFMA16(af, bfr[ni], acc[mi][ni]);
    }
    __syncthreads();
  }
#pragma unroll
  for (int mi = 0; mi < 4; ++mi)
#pragma unroll
    for (int ni = 0; ni < 4; ++ni) {
      int c = wave * 64 + ni * 16 + l15;
      float bv = b0[c];
#pragma unroll
      for (int r = 0; r < 4; ++r) {
        int row = mi * 16 + quad * 4 + r;
        h0[row][c] = f2b(fmaxf(acc[mi][ni][r] + b2f(h0[row][c]) + bv, 0.f));
      }
    }
  __syncthreads();
  // phase 2: h1 = relu(h0 @ W1 + b1); out = h1 . W2 + b2
  f32x4 acc2[4][4];
#pragma unroll
  for (int i = 0; i < 4; ++i)
#pragma unroll
    for (int j = 0; j < 4; ++j) acc2[i][j] = (f32x4){0.f, 0.f, 0.f, 0.f};
  for (int k0 = 0; k0 < 256; k0 += 32) {
#pragma unroll
    for (int r = 0; r < 4; ++r) {
      int row = arow + r * 64;
      *(uint4*)&Bs[row][akc] = *(const uint4*)(W1T + (size_t)row * 256 + k0 + akc);
    }
    __syncthreads();
    bf16x8 bfr[4];
#pragma unroll
    for (int ni = 0; ni < 4; ++ni)
      bfr[ni] = *(const bf16x8*)&Bs[wave * 64 + ni * 16 + l15][quad * 8];
#pragma unroll
    for (int mi = 0; mi < 4; ++mi) {
      bf16x8 af = *(const bf16x8*)&h0[mi * 16 + l15][k0 + quad * 8];
#pragma unroll
      for (int ni = 0; ni < 4; ++ni) acc2[mi][ni] = MFMA16(af, bfr[ni], acc2[mi][ni]);
    }
    __syncthreads();
  }
  float part[4][4];
#pragma unroll
  for (int mi = 0; mi < 4; ++mi)
#pragma unroll
    for (int r = 0; r < 4; ++r) part[mi][r] = 0.f;
#pragma unroll
  for (int mi = 0; mi < 4; ++mi)
#pragma unroll
    for (int ni = 0; ni < 4; ++ni) {
      int c = wave * 64 + ni * 16 + l15;
      float bv = b1[c], wv = W2[c];
#pragma unroll
      for (int r = 0; r < 4; ++r) {
        float v = fmaxf(acc2[mi][ni][r] + bv, 0.f);
        part[mi][r] += v * wv;
      }
    }
#pragma unroll
  for (int d = 1; d < 16; d <<= 1)
#pragma unroll
    for (int mi = 0; mi < 4; ++mi)
#pragma unroll
      for (int r = 0; r < 4; ++r) part[mi][r] += __shfl_xor(part[mi][r], d);
  if (l15 == 0)
#pragma unroll
    for (int mi = 0; mi < 4; ++mi)
#pragma unroll
      for (int r = 0; r < 4; ++r) red[wave][mi * 16 + quad * 4 + r] = part[mi][r];
  __syncthreads();
  if (tid < 64) {
    float s = red[0][tid] + red[1][tid] + red[2][tid] + red[3][tid];
    out[m0 + tid] = s + b2[0];
  }
}

// ---------------- host ----------------

extern "C" void kernel_launch(void* const* d_in, const int* in_sizes, int n_in,
                              void* d_out, int out_size, void* d_ws, size_t ws_size,
                              hipStream_t stream) {
  const int*   eidx1  = (const int*)d_in[0];
  const float* eattr1 = (const float*)d_in[1];
  const int*   eidx2  = (const int*)d_in[2];
  const float* eattr2 = (const float*)d_in[3];
  const int*   batch  = (const int*)d_in[4];
  const float* tval   = (const float*)d_in[5];
  const float* te_W0 = (const float*)d_in[6];
  const float* te_b0 = (const float*)d_in[7];
  const float* te_W1 = (const float*)d_in[8];
  const float* te_b1 = (const float*)d_in[9];
  const float* te_W2 = (const float*)d_in[10];
  const float* te_b2 = (const float*)d_in[11];
  const float* ee_W0 = (const float*)d_in[12];
  const float* ee_b0 = (const float*)d_in[13];
  const float* ee_W1 = (const float*)d_in[14];
  const float* ee_b1 = (const float*)d_in[15];
  const float* ee_W2 = (const float*)d_in[16];
  const float* ee_b2 = (const float*)d_in[17];
  const float* dec_W0 = (const float*)d_in[18];
  const float* dec_b0 = (const float*)d_in[19];
  const float* dec_W1 = (const float*)d_in[20];
  const float* dec_b1 = (const float*)d_in[21];
  const float* dec_W2 = (const float*)d_in[22];
  const float* dec_b2 = (const float*)d_in[23];
  const float* gg_Wl  = (const float*)d_in[24];
  const float* gg_bl  = (const float*)d_in[25];
  const float* gg_Wr  = (const float*)d_in[26];
  const float* gg_br  = (const float*)d_in[27];
  const float* gg_We  = (const float*)d_in[28];
  const float* gg_att = (const float*)d_in[29];
  const float* gg_bias= (const float*)d_in[30];
  const float* gf_Wl  = (const float*)d_in[31];
  const float* gf_bl  = (const float*)d_in[32];
  const float* gf_Wr  = (const float*)d_in[33];
  const float* gf_br  = (const float*)d_in[34];
  const float* gf_We  = (const float*)d_in[35];
  const float* gf_att = (const float*)d_in[36];
  const float* gf_bias= (const float*)d_in[37];
  (void)in_sizes; (void)n_in; (void)out_size; (void)ws_size;

  const int* src1 = eidx1;
  const int* dst1 = eidx1 + NE1;
  const int* src2 = eidx2;
  const int* dst2 = eidx2 + NE2;

  char* base = (char*)d_ws;
  size_t off = 0;
  auto alloc = [&](size_t bytes) {
    void* p = base + off;
    off += (bytes + 255) & ~(size_t)255;
    return p;
  };
  ushort* x_a    = (ushort*)alloc((size_t)NNODE * 512 * 2);
  ushort* x_b    = (ushort*)alloc((size_t)NNODE * 512 * 2);
  ushort* xlr    = (ushort*)alloc((size_t)NNODE * 1024 * 2);
  float*  Z      = (float*)alloc((size_t)NNODE * 512 * 4);
  ushort* e1     = (ushort*)alloc((size_t)NE1 * Hd * 2);
  ushort* e2     = (ushort*)alloc((size_t)NE2 * Hd * 2);
  ushort* ew     = (ushort*)alloc((size_t)NE1 * Hd * 2);   // shared by g1/g2 sequentially
  float*  tenc   = (float*)alloc((size_t)16 * Hd * 4);
  ushort* eeW1T  = (ushort*)alloc((size_t)256 * 256 * 2);
  ushort* eeW2T  = (ushort*)alloc((size_t)256 * 256 * 2);
  ushort* decZT  = (ushort*)alloc((size_t)512 * 512 * 2);
  ushort* decW0cT= (ushort*)alloc((size_t)256 * 256 * 2);
  ushort* decW1T = (ushort*)alloc((size_t)256 * 256 * 2);
  ushort* wlrT   = (ushort*)alloc((size_t)6 * 512 * 512 * 2);  // [2*i+g]
  ushort* weT    = (ushort*)alloc((size_t)6 * 256 * 256 * 2);  // [2*i+g]
  float*  biascat= (float*)alloc((size_t)6 * 1024 * 4);
  float*  zerob  = (float*)alloc((size_t)512 * 4);
  int* cnt1      = (int*)alloc((size_t)NNODE * 4);
  int* cur1      = (int*)alloc((size_t)NNODE * 4);
  int* rs1       = (int*)alloc((size_t)(NNODE + 1) * 4);
  int* eid1      = (int*)alloc((size_t)NE1 * 4);
  int* cnt2      = (int*)alloc((size_t)NNODE * 4);
  int* cur2      = (int*)alloc((size_t)NNODE * 4);
  int* rs2       = (int*)alloc((size_t)(NNODE + 1) * 4);
  int* eid2      = (int*)alloc((size_t)NE2 * 4);

  float* out = (float*)d_out;

  // ---- merged setup ----
  init_small_k<<<(NNODE + 512 + 6144 + 255) / 256, 256, 0, stream>>>(
      cnt1, cur1, cnt2, cur2, zerob, biascat, gg_bl, gg_br, gf_bl, gf_br);

  TransArgs ta;
  int nt = 0, cum = 0;
  auto add = [&](const float* s, ushort* d, int K, int noff, int ld) {
    ta.t[nt].src = s; ta.t[nt].dst = d; ta.t[nt].K = K;
    ta.t[nt].n_off = noff; ta.t[nt].ld = ld; ta.t[nt].start = cum;
    cum += (K / 32) * 8; ++nt;
  };
  add(ee_W1, eeW1T, 256, 0, 256);
  add(ee_W2, eeW2T, 256, 0, 256);
  add(dec_W1, decW1T, 256, 0, 256);
  add(dec_W0, decZT, 512, 0, 512);
  add(dec_W0 + 512 * 256, decZT, 512, 256, 512);
  add(dec_W0 + 1024 * 256, decW0cT, 256, 0, 256);
  for (int i = 0; i < 3; ++i) {
    add(gg_Wl + (size_t)i * 512 * 256, wlrT + (size_t)(2 * i) * 512 * 512, 512, 0, 512);
    add(gg_Wr + (size_t)i * 512 * 256, wlrT + (size_t)(2 * i) * 512 * 512, 512, 256, 512);
    add(gf_Wl + (size_t)i * 512 * 256, wlrT + (size_t)(2 * i + 1) * 512 * 512, 512, 0, 512);
    add(gf_Wr + (size_t)i * 512 * 256, wlrT + (size_t)(2 * i + 1) * 512 * 512, 512, 256, 512);
    add(gg_We + (size_t)i * 65536, weT + (size_t)(2 * i) * 65536, 256, 0, 256);
    add(gf_We + (size_t)i * 65536, weT + (size_t)(2 * i + 1) * 65536, 256, 0, 256);
  }
  trans_all_k<<<cum, 256, 0, stream>>>(ta);

  // ---- CSR build ----
  deg_all_k<<<(NE1 + NE2) / 256, 256, 0, stream>>>(dst1, cnt1, dst2, cnt2);
  scan_k<<<2, 640, 0, stream>>>(cnt1, rs1, cnt2, rs2);
  fill_all_k<<<(NE1 + NE2) / 256, 256, 0, stream>>>(dst1, rs1, cur1, eid1, dst2, rs2, cur2, eid2);

  // ---- fused edge encoder (both graphs, one launch) ----
  enc_fused_k<<<(NE1 + NE2) / 64, 256, 0, stream>>>(
      eattr1, e1, eattr2, e2, ee_W0, ee_b0, eeW1T, ee_b1, eeW2T, ee_b2);

  // ---- time encoding -> x0 (bf16) ----
  time_mlp_k<<<16, 256, 0, stream>>>(tval, te_W0, te_b0, te_W1, te_b1, te_W2, te_b2, tenc);
  build_x0_k<<<(NNODE * 512) / 256, 256, 0, stream>>>(batch, tenc, x_a);

  ushort* x_cur = x_a;
  ushort* x_nxt = x_b;
  const int ngrid128 = (NNODE + 127) / 128;
  const int agrid = (NNODE + 3) / 4;
  for (int i = 0; i < 3; ++i) {
    // xlr (both graphs): cols 0..511 g1 [xl|xr], 512..1023 g2
    mgemm128_k<true><<<dim3(ngrid128, 4), 256, 0, stream>>>(
        x_cur, 512, wlrT + (size_t)(2 * i) * 512 * 512, 512, biascat + (size_t)i * 1024, xlr, 1024, NNODE);
    // g1: ew = e1 @ We, then fused online-softmax aggregate
    mgemm128_k<true><<<dim3(NE1 / 128, 1), 256, 0, stream>>>(
        e1, 256, weT + (size_t)(2 * i) * 65536, 256, zerob, ew, 256, NE1);
    agg2_k<<<agrid, 256, 0, stream>>>(ew, xlr, 0, src1, rs1, eid1,
                                      gg_att + i * Hd, gg_bias + i * Hd, x_nxt, 0);
    // g2
    mgemm128_k<true><<<dim3(NE2 / 128, 1), 256, 0, stream>>>(
        e2, 256, weT + (size_t)(2 * i + 1) * 65536, 256, zerob, ew, 256, NE2);
    agg2_k<<<agrid, 256, 0, stream>>>(ew, xlr, 512, src2, rs2, eid2,
                                      gf_att + i * Hd, gf_bias + i * Hd, x_nxt, 256);
    ushort* t = x_cur; x_cur = x_nxt; x_nxt = t;
  }

  // ---- decoder: Z per-node, then per-edge fused MLP ----
  mgemm128_k<false><<<dim3(ngrid128, 2), 256, 0, stream>>>(
      x_cur, 512, decZT, 512, zerob, Z, 512, NNODE);
  dec2_k<<<NE1 / 64, 256, 0, stream>>>(e1, decW0cT, Z, dec_b0, decW1T, dec_b1,
                                       dec_W2, dec_b2, src1, dst1, out);
}

// Round 8
// 977.298 us; speedup vs baseline: 1.3440x; 1.1219x over previous
//
#include <hip/hip_runtime.h>

#define Hd 256
#define NNODE 10000
#define NE1 131072
#define NE2 65536

typedef __attribute__((ext_vector_type(8))) short bf16x8;
typedef __attribute__((ext_vector_type(4))) float f32x4;

#define MFMA16(a, b, c) __builtin_amdgcn_mfma_f32_16x16x32_bf16((a), (b), (c), 0, 0, 0)

__device__ __forceinline__ float b2f(ushort u) { return __uint_as_float(((unsigned)u) << 16); }
__device__ __forceinline__ ushort f2b(float f) {
  unsigned u = __float_as_uint(f);
  return (ushort)((u + 0x7fffu + ((u >> 16) & 1u)) >> 16);
}

// ---------------- small kernels ----------------

__global__ void time_mlp_k(const float* __restrict__ tval,
                           const float* __restrict__ W0, const float* __restrict__ b0,
                           const float* __restrict__ W1, const float* __restrict__ b1,
                           const float* __restrict__ W2, const float* __restrict__ b2,
                           float* __restrict__ tenc) {
  __shared__ float h0[Hd], h1[Hd];
  int b = blockIdx.x, j = threadIdx.x;
  float t = tval[b];
  h0[j] = fmaxf(t * W0[j] + b0[j], 0.f);
  __syncthreads();
  float a = b1[j];
  for (int k = 0; k < Hd; ++k) a += h0[k] * W1[k * Hd + j];
  h1[j] = fmaxf(a, 0.f);
  __syncthreads();
  float c = b2[j];
  for (int k = 0; k < Hd; ++k) c += h1[k] * W2[k * Hd + j];
  tenc[b * Hd + j] = c;
}

__global__ void build_x0_k(const int* __restrict__ batch, const float* __restrict__ tenc,
                           ushort* __restrict__ x0) {
  int idx = blockIdx.x * 256 + threadIdx.x;
  int n = idx >> 9;
  x0[idx] = f2b(tenc[batch[n] * Hd + (idx & 255)]);
}

__global__ void init_small_k(int* __restrict__ cnt1, int* __restrict__ cur1,
                             int* __restrict__ cnt2, int* __restrict__ cur2,
                             float* __restrict__ zerob, float* __restrict__ biascat,
                             const float* __restrict__ gg_bl, const float* __restrict__ gg_br,
                             const float* __restrict__ gf_bl, const float* __restrict__ gf_br) {
  int i = blockIdx.x * 256 + threadIdx.x;
  if (i < NNODE) { cnt1[i] = 0; cur1[i] = 0; cnt2[i] = 0; cur2[i] = 0; return; }
  i -= NNODE;
  if (i < 512) { zerob[i] = 0.f; return; }
  i -= 512;
  if (i < 6144) {
    int layer = i >> 10, c = i & 1023;
    float v;
    if (c < 256)      v = gg_bl[layer * 256 + c];
    else if (c < 512) v = gg_br[layer * 256 + c - 256];
    else if (c < 768) v = gf_bl[layer * 256 + c - 512];
    else              v = gf_br[layer * 256 + c - 768];
    biascat[layer * 1024 + c] = v;
  }
}

// Wf = ee_W2 @ dec_W0c  (h1 -> decoder hidden), WfT[n][k] bf16; bfold = dec_b0 + ee_b2 @ dec_W0c
__global__ void fold_k(const float* __restrict__ dec_W0, const float* __restrict__ dec_b0,
                       const float* __restrict__ eeW2, const float* __restrict__ eeb2,
                       ushort* __restrict__ WfT, float* __restrict__ bfold) {
  __shared__ float col[256];
  int n = blockIdx.x, k = threadIdx.x;
  col[k] = dec_W0[(size_t)(1024 + k) * 256 + n];
  __syncthreads();
  float acc = 0.f;
  const float* w2row = eeW2 + (size_t)k * 256;
  for (int j = 0; j < 256; ++j) acc += w2row[j] * col[j];
  WfT[(size_t)n * 256 + k] = f2b(acc);
  if (k == 0) {
    float bb = dec_b0[n];
    for (int j = 0; j < 256; ++j) bb += eeb2[j] * col[j];
    bfold[n] = bb;
  }
}

// ---------------- merged weight transposes ----------------
struct TT { const float* src; ushort* dst; int K; int n_off; int ld; int start; };
struct TransArgs { TT t[24]; };

__global__ void trans_all_k(TransArgs a) {
  int b = blockIdx.x;
  int ti = 0;
  while (ti + 1 < 24 && a.t[ti + 1].start <= b) ++ti;
  TT tk = a.t[ti];
  int lb = b - tk.start;
  int gx = tk.K >> 5;
  int k0 = (lb % gx) * 32, n0 = (lb / gx) * 32;
  __shared__ float t[32][33];
  int tx = threadIdx.x & 31, ty = threadIdx.x >> 5;
#pragma unroll
  for (int p = 0; p < 4; ++p)
    t[ty + 8 * p][tx] = tk.src[(size_t)(k0 + ty + 8 * p) * 256 + n0 + tx];
  __syncthreads();
#pragma unroll
  for (int p = 0; p < 4; ++p)
    tk.dst[(size_t)(tk.n_off + n0 + ty + 8 * p) * tk.ld + k0 + tx] = f2b(t[tx][ty + 8 * p]);
}

// ---------------- CSR build (by dst) ----------------

__global__ void deg_all_k(const int* __restrict__ dst1, int* __restrict__ cnt1,
                          const int* __restrict__ dst2, int* __restrict__ cnt2) {
  int e = blockIdx.x * 256 + threadIdx.x;
  if (e < NE1) atomicAdd(cnt1 + dst1[e], 1);
  else if (e - NE1 < NE2) atomicAdd(cnt2 + dst2[e - NE1], 1);
}

__global__ void scan_k(const int* __restrict__ cnt1, int* __restrict__ rs1,
                       const int* __restrict__ cnt2, int* __restrict__ rs2) {
  const int g = blockIdx.x;
  const int* cnt = g ? cnt2 : cnt1;
  int* rowstart = g ? rs2 : rs1;
  const int E = g ? NE2 : NE1;
  __shared__ int part[626];
  int t = threadIdx.x;
  if (t < 625) {
    int s = 0;
#pragma unroll
    for (int i = 0; i < 16; ++i) s += cnt[t * 16 + i];
    part[t] = s;
  }
  __syncthreads();
  if (t == 0) {
    int run = 0;
    for (int i = 0; i < 625; ++i) { int v = part[i]; part[i] = run; run += v; }
  }
  __syncthreads();
  if (t < 625) {
    int off = part[t];
#pragma unroll
    for (int i = 0; i < 16; ++i) { rowstart[t * 16 + i] = off; off += cnt[t * 16 + i]; }
  }
  if (t == 0) rowstart[NNODE] = E;
}

__global__ void fill_all_k(const int* __restrict__ dst1, const int* __restrict__ rs1,
                           int* __restrict__ cur1, int* __restrict__ eid1,
                           const int* __restrict__ dst2, const int* __restrict__ rs2,
                           int* __restrict__ cur2, int* __restrict__ eid2) {
  int e = blockIdx.x * 256 + threadIdx.x;
  if (e < NE1) {
    int d = dst1[e];
    eid1[rs1[d] + atomicAdd(cur1 + d, 1)] = e;
  } else if (e - NE1 < NE2) {
    int e2 = e - NE1;
    int d = dst2[e2];
    eid2[rs2[d] + atomicAdd(cur2 + d, 1)] = e2;
  }
}

// ---------------- fused softmax + aggregate (one wave per node) ----------------
__global__ __launch_bounds__(256) void aggregate_k(
    const float* __restrict__ logits, const ushort* __restrict__ xl,
    const int* __restrict__ src, const int* __restrict__ rowstart,
    const int* __restrict__ eid, const float* __restrict__ bias,
    ushort* __restrict__ xnext, int colbase) {
  const int tid = threadIdx.x;
  const int wave = tid >> 6, lane = tid & 63;
  const int nid = blockIdx.x * 4 + wave;
  if (nid >= NNODE) return;
  const int s0 = rowstart[nid], s1 = rowstart[nid + 1];
  float mx = -__int_as_float(0x7f800000);
  for (int i = s0 + lane; i < s1; i += 64) mx = fmaxf(mx, logits[eid[i]]);
#pragma unroll
  for (int d = 1; d < 64; d <<= 1) mx = fmaxf(mx, __shfl_xor(mx, d));
  float den = 0.f;
  for (int i = s0 + lane; i < s1; i += 64) den += __expf(logits[eid[i]] - mx);
#pragma unroll
  for (int d = 1; d < 64; d <<= 1) den += __shfl_xor(den, d);
  float acc0 = 0.f, acc1 = 0.f, acc2 = 0.f, acc3 = 0.f;
  for (int i = s0; i < s1; ++i) {
    int e = eid[i];
    float w = __expf(logits[e] - mx);
    int s = src[e];
    ushort4 v = *(const ushort4*)(xl + (size_t)s * 1024 + lane * 4);
    acc0 += w * b2f(v.x); acc1 += w * b2f(v.y);
    acc2 += w * b2f(v.z); acc3 += w * b2f(v.w);
  }
  float inv = 1.f / (den + 1e-16f);
  int c = lane * 4;
  ushort4 o;
  o.x = f2b(acc0 * inv + bias[c + 0]);
  o.y = f2b(acc1 * inv + bias[c + 1]);
  o.z = f2b(acc2 * inv + bias[c + 2]);
  o.w = f2b(acc3 * inv + bias[c + 3]);
  *(ushort4*)(xnext + (size_t)nid * 512 + colbase + c) = o;
}

// ---------------- generic MFMA GEMM (R4: A + B LDS-staged, 64-row tile) ----------------
template <bool RELU, bool OBF16>
__global__ __launch_bounds__(256, 2) void mgemm_k(
    const ushort* __restrict__ A, int lda, const ushort* __restrict__ WT, int K,
    const float* __restrict__ bias, void* __restrict__ C, int ldc, int M) {
  __shared__ ushort As[64][40];
  __shared__ ushort Bs[256][40];
  const int tid = threadIdx.x;
  const int wave = tid >> 6, lane = tid & 63;
  const int quad = lane >> 4, l15 = lane & 15;
  const int m0 = blockIdx.x * 64;
  const int ncol0 = blockIdx.y * 256;
  const ushort* WTb = WT + (size_t)ncol0 * K;
  const int arow = tid >> 2, akc = (tid & 3) << 3;
  int am = m0 + arow;
  if (am >= M) am = M - 1;
  f32x4 acc[4][4];
#pragma unroll
  for (int i = 0; i < 4; ++i)
#pragma unroll
    for (int j = 0; j < 4; ++j) acc[i][j] = (f32x4){0.f, 0.f, 0.f, 0.f};
  for (int k0 = 0; k0 < K; k0 += 32) {
    *(uint4*)&As[arow][akc] = *(const uint4*)(A + (size_t)am * lda + k0 + akc);
#pragma unroll
    for (int r = 0; r < 4; ++r) {
      int row = arow + r * 64;
      *(uint4*)&Bs[row][akc] = *(const uint4*)(WTb + (size_t)row * K + k0 + akc);
    }
    __syncthreads();
    bf16x8 bfr[4];
#pragma unroll
    for (int ni = 0; ni < 4; ++ni)
      bfr[ni] = *(const bf16x8*)&Bs[wave * 64 + ni * 16 + l15][quad * 8];
#pragma unroll
    for (int mi = 0; mi < 4; ++mi) {
      bf16x8 af = *(const bf16x8*)&As[mi * 16 + l15][quad * 8];
#pragma unroll
      for (int ni = 0; ni < 4; ++ni) acc[mi][ni] = MFMA16(af, bfr[ni], acc[mi][ni]);
    }
    __syncthreads();
  }
#pragma unroll
  for (int mi = 0; mi < 4; ++mi)
#pragma unroll
    for (int ni = 0; ni < 4; ++ni) {
      int c = ncol0 + wave * 64 + ni * 16 + l15;
      float bv = bias[c];
#pragma unroll
      for (int r = 0; r < 4; ++r) {
        int m = m0 + mi * 16 + quad * 4 + r;
        if (m < M) {
          float v = acc[mi][ni][r] + bv;
          if (RELU) v = fmaxf(v, 0.f);
          if (OBF16) ((ushort*)C)[(size_t)m * ldc + c] = f2b(v);
          else       ((float*)C)[(size_t)m * ldc + c] = v;
        }
      }
    }
}

// ---------------- fused edge-encoder MLP, both graphs; g1 also emits ZE ----------------
__global__ __launch_bounds__(256, 2) void enc_fused_k(
    const float* __restrict__ attr1, ushort* __restrict__ e1, ushort* __restrict__ ZE,
    const float* __restrict__ attr2, ushort* __restrict__ e2,
    const float* __restrict__ W0, const float* __restrict__ b0,
    const ushort* __restrict__ W1T, const float* __restrict__ b1,
    const ushort* __restrict__ W2T, const float* __restrict__ b2,
    const ushort* __restrict__ WfT, const float* __restrict__ bfold) {
  __shared__ ushort h[64][264];
  __shared__ ushort Bs[256][40];
  __shared__ float w0s[256], b0s[256];
  const int tid = threadIdx.x;
  const int wave = tid >> 6, lane = tid & 63;
  const int quad = lane >> 4, l15 = lane & 15;
  const bool g1 = blockIdx.x < NE1 / 64;
  const float* attr = g1 ? attr1 : attr2;
  ushort* eout = g1 ? e1 : e2;
  const int m0 = (g1 ? blockIdx.x : blockIdx.x - NE1 / 64) * 64;
  const int arow = tid >> 2, akc = (tid & 3) << 3;
  w0s[tid] = W0[tid];
  b0s[tid] = b0[tid];
  float a0 = attr[m0 + arow];
  __syncthreads();
  {
    int c0 = (tid & 3) * 64;
#pragma unroll
    for (int j = 0; j < 64; j += 4) {
      int c = c0 + j;
      ushort4 o;
      o.x = f2b(fmaxf(a0 * w0s[c + 0] + b0s[c + 0], 0.f));
      o.y = f2b(fmaxf(a0 * w0s[c + 1] + b0s[c + 1], 0.f));
      o.z = f2b(fmaxf(a0 * w0s[c + 2] + b0s[c + 2], 0.f));
      o.w = f2b(fmaxf(a0 * w0s[c + 3] + b0s[c + 3], 0.f));
      *(ushort4*)&h[arow][c] = o;
    }
  }
  __syncthreads();
  // phase A: h1 = relu(h0 @ W1 + b1)
  f32x4 acc[4][4];
#pragma unroll
  for (int i = 0; i < 4; ++i)
#pragma unroll
    for (int j = 0; j < 4; ++j) acc[i][j] = (f32x4){0.f, 0.f, 0.f, 0.f};
  for (int k0 = 0; k0 < 256; k0 += 32) {
#pragma unroll
    for (int r = 0; r < 4; ++r) {
      int row = arow + r * 64;
      *(uint4*)&Bs[row][akc] = *(const uint4*)(W1T + (size_t)row * 256 + k0 + akc);
    }
    __syncthreads();
    bf16x8 bfr[4];
#pragma unroll
    for (int ni = 0; ni < 4; ++ni)
      bfr[ni] = *(const bf16x8*)&Bs[wave * 64 + ni * 16 + l15][quad * 8];
#pragma unroll
    for (int mi = 0; mi < 4; ++mi) {
      bf16x8 af = *(const bf16x8*)&h[mi * 16 + l15][k0 + quad * 8];
#pragma unroll
      for (int ni = 0; ni < 4; ++ni) acc[mi][ni] = MFMA16(af, bfr[ni], acc[mi][ni]);
    }
    __syncthreads();
  }
#pragma unroll
  for (int mi = 0; mi < 4; ++mi)
#pragma unroll
    for (int ni = 0; ni < 4; ++ni) {
      int c = wave * 64 + ni * 16 + l15;
      float bv = b1[c];
#pragma unroll
      for (int r = 0; r < 4; ++r)
        h[mi * 16 + quad * 4 + r][c] = f2b(fmaxf(acc[mi][ni][r] + bv, 0.f));
    }
  __syncthreads();
  // phase B: eout = h1 @ W2 + b2
  f32x4 acc2[4][4];
#pragma unroll
  for (int i = 0; i < 4; ++i)
#pragma unroll
    for (int j = 0; j < 4; ++j) acc2[i][j] = (f32x4){0.f, 0.f, 0.f, 0.f};
  for (int k0 = 0; k0 < 256; k0 += 32) {
#pragma unroll
    for (int r = 0; r < 4; ++r) {
      int row = arow + r * 64;
      *(uint4*)&Bs[row][akc] = *(const uint4*)(W2T + (size_t)row * 256 + k0 + akc);
    }
    __syncthreads();
    bf16x8 bfr[4];
#pragma unroll
    for (int ni = 0; ni < 4; ++ni)
      bfr[ni] = *(const bf16x8*)&Bs[wave * 64 + ni * 16 + l15][quad * 8];
#pragma unroll
    for (int mi = 0; mi < 4; ++mi) {
      bf16x8 af = *(const bf16x8*)&h[mi * 16 + l15][k0 + quad * 8];
#pragma unroll
      for (int ni = 0; ni < 4; ++ni) acc2[mi][ni] = MFMA16(af, bfr[ni], acc2[mi][ni]);
    }
    __syncthreads();
  }
#pragma unroll
  for (int mi = 0; mi < 4; ++mi)
#pragma unroll
    for (int ni = 0; ni < 4; ++ni) {
      int c = wave * 64 + ni * 16 + l15;
      float bv = b2[c];
#pragma unroll
      for (int r = 0; r < 4; ++r) {
        int m = m0 + mi * 16 + quad * 4 + r;
        eout[(size_t)m * 256 + c] = f2b(acc2[mi][ni][r] + bv);
      }
    }
  if (!g1) return;
  // phase C (g1 only): ZE = h1 @ Wf + bfold
  f32x4 acc3[4][4];
#pragma unroll
  for (int i = 0; i < 4; ++i)
#pragma unroll
    for (int j = 0; j < 4; ++j) acc3[i][j] = (f32x4){0.f, 0.f, 0.f, 0.f};
  for (int k0 = 0; k0 < 256; k0 += 32) {
    __syncthreads();
#pragma unroll
    for (int r = 0; r < 4; ++r) {
      int row = arow + r * 64;
      *(uint4*)&Bs[row][akc] = *(const uint4*)(WfT + (size_t)row * 256 + k0 + akc);
    }
    __syncthreads();
    bf16x8 bfr[4];
#pragma unroll
    for (int ni = 0; ni < 4; ++ni)
      bfr[ni] = *(const bf16x8*)&Bs[wave * 64 + ni * 16 + l15][quad * 8];
#pragma unroll
    for (int mi = 0; mi < 4; ++mi) {
      bf16x8 af = *(const bf16x8*)&h[mi * 16 + l15][k0 + quad * 8];
#pragma unroll
      for (int ni = 0; ni < 4; ++ni) acc3[mi][ni] = MFMA16(af, bfr[ni], acc3[mi][ni]);
    }
  }
#pragma unroll
  for (int mi = 0; mi < 4; ++mi)
#pragma unroll
    for (int ni = 0; ni < 4; ++ni) {
      int c = wave * 64 + ni * 16 + l15;
      float bv = bfold[c];
#pragma unroll
      for (int r = 0; r < 4; ++r) {
        int m = m0 + mi * 16 + quad * 4 + r;
        ZE[(size_t)m * 256 + c] = f2b(acc3[mi][ni][r] + bv);
      }
    }
}

// ---------------- fused MFMA attention logits (R4 structure) ----------------
__global__ __launch_bounds__(256, 2) void attn_mfma_k(
    const ushort* __restrict__ eenc, const ushort* __restrict__ weT,
    const float* __restrict__ att, const ushort* __restrict__ xlr,
    const int* __restrict__ src, const int* __restrict__ dst,
    float* __restrict__ logits) {
  __shared__ ushort As[64][40];
  __shared__ ushort Bs[256][40];
  __shared__ ushort xs[64][264];
  __shared__ float red[4][64];
  __shared__ float att_s[256];
  const int tid = threadIdx.x;
  const int wave = tid >> 6, lane = tid & 63;
  const int quad = lane >> 4, l15 = lane & 15;
  const int m0 = blockIdx.x * 64;
  const int arow = tid >> 2, akc = (tid & 3) << 3;
  att_s[tid] = att[tid];
  {
    int s = src[m0 + arow], d = dst[m0 + arow];
    int c0 = (tid & 3) * 64;
    const ushort* pl = xlr + (size_t)s * 1024;
    const ushort* pr = xlr + (size_t)d * 1024 + 256;
#pragma unroll
    for (int j = 0; j < 16; ++j) {
      int c = c0 + 4 * j;
      ushort4 a = *(const ushort4*)(pl + c);
      ushort4 b = *(const ushort4*)(pr + c);
      ushort4 o;
      o.x = f2b(b2f(a.x) + b2f(b.x)); o.y = f2b(b2f(a.y) + b2f(b.y));
      o.z = f2b(b2f(a.z) + b2f(b.z)); o.w = f2b(b2f(a.w) + b2f(b.w));
      *(ushort4*)&xs[arow][c] = o;
    }
  }
  f32x4 acc[4][4];
#pragma unroll
  for (int i = 0; i < 4; ++i)
#pragma unroll
    for (int j = 0; j < 4; ++j) acc[i][j] = (f32x4){0.f, 0.f, 0.f, 0.f};
  for (int k0 = 0; k0 < 256; k0 += 32) {
    *(uint4*)&As[arow][akc] = *(const uint4*)(eenc + (size_t)(m0 + arow) * 256 + k0 + akc);
#pragma unroll
    for (int r = 0; r < 4; ++r) {
      int row = arow + r * 64;
      *(uint4*)&Bs[row][akc] = *(const uint4*)(weT + (size_t)row * 256 + k0 + akc);
    }
    __syncthreads();
    bf16x8 bfr[4];
#pragma unroll
    for (int ni = 0; ni < 4; ++ni)
      bfr[ni] = *(const bf16x8*)&Bs[wave * 64 + ni * 16 + l15][quad * 8];
#pragma unroll
    for (int mi = 0; mi < 4; ++mi) {
      bf16x8 af = *(const bf16x8*)&As[mi * 16 + l15][quad * 8];
#pragma unroll
      for (int ni = 0; ni < 4; ++ni) acc[mi][ni] = MFMA16(af, bfr[ni], acc[mi][ni]);
    }
    __syncthreads();
  }
  float part[4][4];
#pragma unroll
  for (int mi = 0; mi < 4; ++mi)
#pragma unroll
    for (int r = 0; r < 4; ++r) part[mi][r] = 0.f;
#pragma unroll
  for (int mi = 0; mi < 4; ++mi)
#pragma unroll
    for (int ni = 0; ni < 4; ++ni) {
      int c = wave * 64 + ni * 16 + l15;
      float av = att_s[c];
#pragma unroll
      for (int r = 0; r < 4; ++r) {
        int row = mi * 16 + quad * 4 + r;
        float v = acc[mi][ni][r] + b2f(xs[row][c]);
        v = v > 0.f ? v : 0.2f * v;
        part[mi][r] += v * av;
      }
    }
#pragma unroll
  for (int d = 1; d < 16; d <<= 1)
#pragma unroll
    for (int mi = 0; mi < 4; ++mi)
#pragma unroll
      for (int r = 0; r < 4; ++r) part[mi][r] += __shfl_xor(part[mi][r], d);
  if (l15 == 0)
#pragma unroll
    for (int mi = 0; mi < 4; ++mi)
#pragma unroll
      for (int r = 0; r < 4; ++r) red[wave][mi * 16 + quad * 4 + r] = part[mi][r];
  __syncthreads();
  if (tid < 64)
    logits[m0 + tid] = red[0][tid] + red[1][tid] + red[2][tid] + red[3][tid];
}

// ---------------- decoder: h0 staged from ZE-fold, one MFMA phase + dot ----------------
__global__ __launch_bounds__(256, 2) void dec3_k(
    const ushort* __restrict__ ZE, const float* __restrict__ Z,
    const ushort* __restrict__ W1T, const float* __restrict__ b1,
    const float* __restrict__ W2, const float* __restrict__ b2,
    const int* __restrict__ src, const int* __restrict__ dst,
    float* __restrict__ out) {
  __shared__ ushort Bs[256][40];
  __shared__ ushort h0[64][264];
  __shared__ float red[4][64];
  const int tid = threadIdx.x;
  const int wave = tid >> 6, lane = tid & 63;
  const int quad = lane >> 4, l15 = lane & 15;
  const int m0 = blockIdx.x * 64;
  const int arow = tid >> 2, akc = (tid & 3) << 3;
  {  // h0 = relu(Za[src] + Zb[dst] + ZE[e])   (bias already folded into ZE)
    int gs = src[m0 + arow], gd = dst[m0 + arow];
    int c0 = (tid & 3) * 64;
    const float* za = Z + (size_t)gs * 512;
    const float* zb = Z + (size_t)gd * 512 + 256;
    const ushort* ze = ZE + (size_t)(m0 + arow) * 256;
#pragma unroll
    for (int j = 0; j < 16; ++j) {
      int c = c0 + 4 * j;
      float4 a = *(const float4*)(za + c);
      float4 b = *(const float4*)(zb + c);
      ushort4 e = *(const ushort4*)(ze + c);
      ushort4 o;
      o.x = f2b(fmaxf(a.x + b.x + b2f(e.x), 0.f));
      o.y = f2b(fmaxf(a.y + b.y + b2f(e.y), 0.f));
      o.z = f2b(fmaxf(a.z + b.z + b2f(e.z), 0.f));
      o.w = f2b(fmaxf(a.w + b.w + b2f(e.w), 0.f));
      *(ushort4*)&h0[arow][c] = o;
    }
  }
  __syncthreads();
  // h1 = relu(h0 @ W1 + b1); out = h1 . W2 + b2
  f32x4 acc2[4][4];
#pragma unroll
  for (int i = 0; i < 4; ++i)
#pragma unroll
    for (int j = 0; j < 4; ++j) acc2[i][j] = (f32x4){0.f, 0.f, 0.f, 0.f};
  for (int k0 = 0; k0 < 256; k0 += 32) {
#pragma unroll
    for (int r = 0; r < 4; ++r) {
      int row = arow + r * 64;
      *(uint4*)&Bs[row][akc] = *(const uint4*)(W1T + (size_t)row * 256 + k0 + akc);
    }
    __syncthreads();
    bf16x8 bfr[4];
#pragma unroll
    for (int ni = 0; ni < 4; ++ni)
      bfr[ni] = *(const bf16x8*)&Bs[wave * 64 + ni * 16 + l15][quad * 8];
#pragma unroll
    for (int mi = 0; mi < 4; ++mi) {
      bf16x8 af = *(const bf16x8*)&h0[mi * 16 + l15][k0 + quad * 8];
#pragma unroll
      for (int ni = 0; ni < 4; ++ni) acc2[mi][ni] = MFMA16(af, bfr[ni], acc2[mi][ni]);
    }
    __syncthreads();
  }
  float part[4][4];
#pragma unroll
  for (int mi = 0; mi < 4; ++mi)
#pragma unroll
    for (int r = 0; r < 4; ++r) part[mi][r] = 0.f;
#pragma unroll
  for (int mi = 0; mi < 4; ++mi)
#pragma unroll
    for (int ni = 0; ni < 4; ++ni) {
      int c = wave * 64 + ni * 16 + l15;
      float bv = b1[c], wv = W2[c];
#pragma unroll
      for (int r = 0; r < 4; ++r) {
        float v = fmaxf(acc2[mi][ni][r] + bv, 0.f);
        part[mi][r] += v * wv;
      }
    }
#pragma unroll
  for (int d = 1; d < 16; d <<= 1)
#pragma unroll
    for (int mi = 0; mi < 4; ++mi)
#pragma unroll
      for (int r = 0; r < 4; ++r) part[mi][r] += __shfl_xor(part[mi][r], d);
  if (l15 == 0)
#pragma unroll
    for (int mi = 0; mi < 4; ++mi)
#pragma unroll
      for (int r = 0; r < 4; ++r) red[wave][mi * 16 + quad * 4 + r] = part[mi][r];
  __syncthreads();
  if (tid < 64) {
    float s = red[0][tid] + red[1][tid] + red[2][tid] + red[3][tid];
    out[m0 + tid] = s + b2[0];
  }
}

// ---------------- host ----------------

extern "C" void kernel_launch(void* const* d_in, const int* in_sizes, int n_in,
                              void* d_out, int out_size, void* d_ws, size_t ws_size,
                              hipStream_t stream) {
  const int*   eidx1  = (const int*)d_in[0];
  const float* eattr1 = (const float*)d_in[1];
  const int*   eidx2  = (const int*)d_in[2];
  const float* eattr2 = (const float*)d_in[3];
  const int*   batch  = (const int*)d_in[4];
  const float* tval   = (const float*)d_in[5];
  const float* te_W0 = (const float*)d_in[6];
  const float* te_b0 = (const float*)d_in[7];
  const float* te_W1 = (const float*)d_in[8];
  const float* te_b1 = (const float*)d_in[9];
  const float* te_W2 = (const float*)d_in[10];
  const float* te_b2 = (const float*)d_in[11];
  const float* ee_W0 = (const float*)d_in[12];
  const float* ee_b0 = (const float*)d_in[13];
  const float* ee_W1 = (const float*)d_in[14];
  const float* ee_b1 = (const float*)d_in[15];
  const float* ee_W2 = (const float*)d_in[16];
  const float* ee_b2 = (const float*)d_in[17];
  const float* dec_W0 = (const float*)d_in[18];
  const float* dec_b0 = (const float*)d_in[19];
  const float* dec_W1 = (const float*)d_in[20];
  const float* dec_b1 = (const float*)d_in[21];
  const float* dec_W2 = (const float*)d_in[22];
  const float* dec_b2 = (const float*)d_in[23];
  const float* gg_Wl  = (const float*)d_in[24];
  const float* gg_bl  = (const float*)d_in[25];
  const float* gg_Wr  = (const float*)d_in[26];
  const float* gg_br  = (const float*)d_in[27];
  const float* gg_We  = (const float*)d_in[28];
  const float* gg_att = (const float*)d_in[29];
  const float* gg_bias= (const float*)d_in[30];
  const float* gf_Wl  = (const float*)d_in[31];
  const float* gf_bl  = (const float*)d_in[32];
  const float* gf_Wr  = (const float*)d_in[33];
  const float* gf_br  = (const float*)d_in[34];
  const float* gf_We  = (const float*)d_in[35];
  const float* gf_att = (const float*)d_in[36];
  const float* gf_bias= (const float*)d_in[37];
  (void)in_sizes; (void)n_in; (void)out_size; (void)ws_size;

  const int* src1 = eidx1;
  const int* dst1 = eidx1 + NE1;
  const int* src2 = eidx2;
  const int* dst2 = eidx2 + NE2;

  char* base = (char*)d_ws;
  size_t off = 0;
  auto alloc = [&](size_t bytes) {
    void* p = base + off;
    off += (bytes + 255) & ~(size_t)255;
    return p;
  };
  ushort* x_a    = (ushort*)alloc((size_t)NNODE * 512 * 2);
  ushort* x_b    = (ushort*)alloc((size_t)NNODE * 512 * 2);
  ushort* xlr    = (ushort*)alloc((size_t)NNODE * 1024 * 2);
  float*  Z      = (float*)alloc((size_t)NNODE * 512 * 4);
  ushort* e1     = (ushort*)alloc((size_t)NE1 * Hd * 2);
  ushort* e2     = (ushort*)alloc((size_t)NE2 * Hd * 2);
  ushort* ZE     = (ushort*)alloc((size_t)NE1 * Hd * 2);
  float*  logits = (float*)alloc((size_t)NE1 * 4);
  float*  tenc   = (float*)alloc((size_t)16 * Hd * 4);
  ushort* eeW1T  = (ushort*)alloc((size_t)256 * 256 * 2);
  ushort* eeW2T  = (ushort*)alloc((size_t)256 * 256 * 2);
  ushort* decZT  = (ushort*)alloc((size_t)512 * 512 * 2);
  ushort* decW1T = (ushort*)alloc((size_t)256 * 256 * 2);
  ushort* WfT    = (ushort*)alloc((size_t)256 * 256 * 2);
  float*  bfold  = (float*)alloc((size_t)256 * 4);
  ushort* wlrT   = (ushort*)alloc((size_t)6 * 512 * 512 * 2);  // [2*i+g]
  ushort* weT    = (ushort*)alloc((size_t)6 * 256 * 256 * 2);  // [2*i+g]
  float*  biascat= (float*)alloc((size_t)6 * 1024 * 4);
  float*  zerob  = (float*)alloc((size_t)512 * 4);
  int* cnt1      = (int*)alloc((size_t)NNODE * 4);
  int* cur1      = (int*)alloc((size_t)NNODE * 4);
  int* rs1       = (int*)alloc((size_t)(NNODE + 1) * 4);
  int* eid1      = (int*)alloc((size_t)NE1 * 4);
  int* cnt2      = (int*)alloc((size_t)NNODE * 4);
  int* cur2      = (int*)alloc((size_t)NNODE * 4);
  int* rs2       = (int*)alloc((size_t)(NNODE + 1) * 4);
  int* eid2      = (int*)alloc((size_t)NE2 * 4);

  float* out = (float*)d_out;

  // ---- merged setup ----
  init_small_k<<<(NNODE + 512 + 6144 + 255) / 256, 256, 0, stream>>>(
      cnt1, cur1, cnt2, cur2, zerob, biascat, gg_bl, gg_br, gf_bl, gf_br);
  fold_k<<<256, 256, 0, stream>>>(dec_W0, dec_b0, ee_W2, ee_b2, WfT, bfold);

  TransArgs ta;
  int nt = 0, cum = 0;
  auto add = [&](const float* s, ushort* d, int K, int noff, int ld) {
    ta.t[nt].src = s; ta.t[nt].dst = d; ta.t[nt].K = K;
    ta.t[nt].n_off = noff; ta.t[nt].ld = ld; ta.t[nt].start = cum;
    cum += (K / 32) * 8; ++nt;
  };
  add(ee_W1, eeW1T, 256, 0, 256);
  add(ee_W2, eeW2T, 256, 0, 256);
  add(dec_W1, decW1T, 256, 0, 256);
  add(dec_W0, decZT, 512, 0, 512);
  add(dec_W0 + 512 * 256, decZT, 512, 256, 512);
  for (int i = 0; i < 3; ++i) {
    add(gg_Wl + (size_t)i * 512 * 256, wlrT + (size_t)(2 * i) * 512 * 512, 512, 0, 512);
    add(gg_Wr + (size_t)i * 512 * 256, wlrT + (size_t)(2 * i) * 512 * 512, 512, 256, 512);
    add(gf_Wl + (size_t)i * 512 * 256, wlrT + (size_t)(2 * i + 1) * 512 * 512, 512, 0, 512);
    add(gf_Wr + (size_t)i * 512 * 256, wlrT + (size_t)(2 * i + 1) * 512 * 512, 512, 256, 512);
    add(gg_We + (size_t)i * 65536, weT + (size_t)(2 * i) * 65536, 256, 0, 256);
    add(gf_We + (size_t)i * 65536, weT + (size_t)(2 * i + 1) * 65536, 256, 0, 256);
  }
  for (int i = nt; i < 24; ++i) ta.t[i].start = 0x7fffffff;
  trans_all_k<<<cum, 256, 0, stream>>>(ta);

  // ---- CSR build ----
  deg_all_k<<<(NE1 + NE2) / 256, 256, 0, stream>>>(dst1, cnt1, dst2, cnt2);
  scan_k<<<2, 640, 0, stream>>>(cnt1, rs1, cnt2, rs2);
  fill_all_k<<<(NE1 + NE2) / 256, 256, 0, stream>>>(dst1, rs1, cur1, eid1, dst2, rs2, cur2, eid2);

  // ---- fused edge encoder (both graphs; g1 blocks also emit ZE) ----
  enc_fused_k<<<(NE1 + NE2) / 64, 256, 0, stream>>>(
      eattr1, e1, ZE, eattr2, e2, ee_W0, ee_b0, eeW1T, ee_b1, eeW2T, ee_b2, WfT, bfold);

  // ---- time encoding -> x0 (bf16) ----
  time_mlp_k<<<16, 256, 0, stream>>>(tval, te_W0, te_b0, te_W1, te_b1, te_W2, te_b2, tenc);
  build_x0_k<<<(NNODE * 512) / 256, 256, 0, stream>>>(batch, tenc, x_a);

  ushort* x_cur = x_a;
  ushort* x_nxt = x_b;
  const int ngrid = (NNODE + 63) / 64;
  const int agrid = (NNODE + 3) / 4;
  for (int i = 0; i < 3; ++i) {
    mgemm_k<false, true><<<dim3(ngrid, 4), 256, 0, stream>>>(
        x_cur, 512, wlrT + (size_t)(2 * i) * 512 * 512, 512, biascat + (size_t)i * 1024, xlr, 1024, NNODE);
    attn_mfma_k<<<NE1 / 64, 256, 0, stream>>>(e1, weT + (size_t)(2 * i) * 65536, gg_att + i * Hd,
                                              xlr, src1, dst1, logits);
    aggregate_k<<<agrid, 256, 0, stream>>>(logits, xlr, src1, rs1, eid1, gg_bias + i * Hd, x_nxt, 0);
    attn_mfma_k<<<NE2 / 64, 256, 0, stream>>>(e2, weT + (size_t)(2 * i + 1) * 65536, gf_att + i * Hd,
                                              xlr + 512, src2, dst2, logits);
    aggregate_k<<<agrid, 256, 0, stream>>>(logits, xlr + 512, src2, rs2, eid2, gf_bias + i * Hd, x_nxt, 256);
    ushort* t = x_cur; x_cur = x_nxt; x_nxt = t;
  }

  // ---- decoder: Z per-node, then per-edge fused MLP (ZE-folded) ----
  mgemm_k<false, false><<<dim3(ngrid, 2), 256, 0, stream>>>(
      x_cur, 512, decZT, 512, zerob, Z, 512, NNODE);
  dec3_k<<<NE1 / 64, 256, 0, stream>>>(ZE, Z, decW1T, dec_b1, dec_W2, dec_b2, src1, dst1, out);
}

// Round 9
// 931.526 us; speedup vs baseline: 1.4100x; 1.0491x over previous
//
#include <hip/hip_runtime.h>

#define Hd 256
#define NNODE 10000
#define NE1 131072
#define NE2 65536
#define AGRID 2500   // ceil(NNODE/4)

typedef __attribute__((ext_vector_type(8))) short bf16x8;
typedef __attribute__((ext_vector_type(4))) float f32x4;

#define MFMA16(a, b, c) __builtin_amdgcn_mfma_f32_16x16x32_bf16((a), (b), (c), 0, 0, 0)

__device__ __forceinline__ float b2f(ushort u) { return __uint_as_float(((unsigned)u) << 16); }
__device__ __forceinline__ ushort f2b(float f) {
  unsigned u = __float_as_uint(f);
  return (ushort)((u + 0x7fffu + ((u >> 16) & 1u)) >> 16);
}

// ---------------- small kernels ----------------

__global__ void time_mlp_k(const float* __restrict__ tval,
                           const float* __restrict__ W0, const float* __restrict__ b0,
                           const float* __restrict__ W1, const float* __restrict__ b1,
                           const float* __restrict__ W2, const float* __restrict__ b2,
                           float* __restrict__ tenc) {
  __shared__ float h0[Hd], h1[Hd];
  int b = blockIdx.x, j = threadIdx.x;
  float t = tval[b];
  h0[j] = fmaxf(t * W0[j] + b0[j], 0.f);
  __syncthreads();
  float a = b1[j];
  for (int k = 0; k < Hd; ++k) a += h0[k] * W1[k * Hd + j];
  h1[j] = fmaxf(a, 0.f);
  __syncthreads();
  float c = b2[j];
  for (int k = 0; k < Hd; ++k) c += h1[k] * W2[k * Hd + j];
  tenc[b * Hd + j] = c;
}

__global__ void build_x0_k(const int* __restrict__ batch, const float* __restrict__ tenc,
                           ushort* __restrict__ x0) {
  int idx = blockIdx.x * 256 + threadIdx.x;
  int n = idx >> 9;
  x0[idx] = f2b(tenc[batch[n] * Hd + (idx & 255)]);
}

__global__ void init_small_k(int* __restrict__ cnt1, int* __restrict__ cur1,
                             int* __restrict__ cnt2, int* __restrict__ cur2,
                             float* __restrict__ zerob, float* __restrict__ biascat,
                             const float* __restrict__ gg_bl, const float* __restrict__ gg_br,
                             const float* __restrict__ gf_bl, const float* __restrict__ gf_br) {
  int i = blockIdx.x * 256 + threadIdx.x;
  if (i < NNODE) { cnt1[i] = 0; cur1[i] = 0; cnt2[i] = 0; cur2[i] = 0; return; }
  i -= NNODE;
  if (i < 512) { zerob[i] = 0.f; return; }
  i -= 512;
  if (i < 6144) {
    int layer = i >> 10, c = i & 1023;
    float v;
    if (c < 256)      v = gg_bl[layer * 256 + c];
    else if (c < 512) v = gg_br[layer * 256 + c - 256];
    else if (c < 768) v = gf_bl[layer * 256 + c - 512];
    else              v = gf_br[layer * 256 + c - 768];
    biascat[layer * 1024 + c] = v;
  }
}

// Wf = ee_W2 @ dec_W0c; bfold = dec_b0 + ee_b2 @ dec_W0c
__global__ void fold_k(const float* __restrict__ dec_W0, const float* __restrict__ dec_b0,
                       const float* __restrict__ eeW2, const float* __restrict__ eeb2,
                       ushort* __restrict__ WfT, float* __restrict__ bfold) {
  __shared__ float col[256];
  int n = blockIdx.x, k = threadIdx.x;
  col[k] = dec_W0[(size_t)(1024 + k) * 256 + n];
  __syncthreads();
  float acc = 0.f;
  const float* w2row = eeW2 + (size_t)k * 256;
  for (int j = 0; j < 256; ++j) acc += w2row[j] * col[j];
  WfT[(size_t)n * 256 + k] = f2b(acc);
  if (k == 0) {
    float bb = dec_b0[n];
    for (int j = 0; j < 256; ++j) bb += eeb2[j] * col[j];
    bfold[n] = bb;
  }
}

// ---------------- merged weight transposes ----------------
struct TT { const float* src; ushort* dst; int K; int n_off; int ld; int start; };
struct TransArgs { TT t[24]; };

__global__ void trans_all_k(TransArgs a) {
  int b = blockIdx.x;
  int ti = 0;
  while (ti + 1 < 24 && a.t[ti + 1].start <= b) ++ti;
  TT tk = a.t[ti];
  int lb = b - tk.start;
  int gx = tk.K >> 5;
  int k0 = (lb % gx) * 32, n0 = (lb / gx) * 32;
  __shared__ float t[32][33];
  int tx = threadIdx.x & 31, ty = threadIdx.x >> 5;
#pragma unroll
  for (int p = 0; p < 4; ++p)
    t[ty + 8 * p][tx] = tk.src[(size_t)(k0 + ty + 8 * p) * 256 + n0 + tx];
  __syncthreads();
#pragma unroll
  for (int p = 0; p < 4; ++p)
    tk.dst[(size_t)(tk.n_off + n0 + ty + 8 * p) * tk.ld + k0 + tx] = f2b(t[tx][ty + 8 * p]);
}

// ---------------- CSR build (by dst) ----------------

__global__ void deg_all_k(const int* __restrict__ dst1, int* __restrict__ cnt1,
                          const int* __restrict__ dst2, int* __restrict__ cnt2) {
  int e = blockIdx.x * 256 + threadIdx.x;
  if (e < NE1) atomicAdd(cnt1 + dst1[e], 1);
  else if (e - NE1 < NE2) atomicAdd(cnt2 + dst2[e - NE1], 1);
}

__global__ void scan_k(const int* __restrict__ cnt1, int* __restrict__ rs1,
                       const int* __restrict__ cnt2, int* __restrict__ rs2) {
  const int g = blockIdx.x;
  const int* cnt = g ? cnt2 : cnt1;
  int* rowstart = g ? rs2 : rs1;
  const int E = g ? NE2 : NE1;
  __shared__ int part[626];
  int t = threadIdx.x;
  if (t < 625) {
    int s = 0;
#pragma unroll
    for (int i = 0; i < 16; ++i) s += cnt[t * 16 + i];
    part[t] = s;
  }
  __syncthreads();
  if (t == 0) {
    int run = 0;
    for (int i = 0; i < 625; ++i) { int v = part[i]; part[i] = run; run += v; }
  }
  __syncthreads();
  if (t < 625) {
    int off = part[t];
#pragma unroll
    for (int i = 0; i < 16; ++i) { rowstart[t * 16 + i] = off; off += cnt[t * 16 + i]; }
  }
  if (t == 0) rowstart[NNODE] = E;
}

__global__ void fill_all_k(const int* __restrict__ dst1, const int* __restrict__ rs1,
                           int* __restrict__ cur1, int* __restrict__ eid1,
                           const int* __restrict__ dst2, const int* __restrict__ rs2,
                           int* __restrict__ cur2, int* __restrict__ eid2) {
  int e = blockIdx.x * 256 + threadIdx.x;
  if (e < NE1) {
    int d = dst1[e];
    eid1[rs1[d] + atomicAdd(cur1 + d, 1)] = e;
  } else if (e - NE1 < NE2) {
    int e2 = e - NE1;
    int d = dst2[e2];
    eid2[rs2[d] + atomicAdd(cur2 + d, 1)] = e2;
  }
}

// ---------------- merged softmax + aggregate, both graphs (one wave/node) ----------------
__global__ __launch_bounds__(256) void aggregate_k(
    const float* __restrict__ logits1, const float* __restrict__ logits2,
    const ushort* __restrict__ xlr,
    const int* __restrict__ src1, const int* __restrict__ src2,
    const int* __restrict__ rs1, const int* __restrict__ rs2,
    const int* __restrict__ eid1, const int* __restrict__ eid2,
    const float* __restrict__ bias1, const float* __restrict__ bias2,
    ushort* __restrict__ xnext) {
  const int tid = threadIdx.x;
  const int wave = tid >> 6, lane = tid & 63;
  const bool g1 = blockIdx.x < AGRID;
  const int nid = (g1 ? blockIdx.x : blockIdx.x - AGRID) * 4 + wave;
  if (nid >= NNODE) return;
  const float* logits = g1 ? logits1 : logits2;
  const int* src = g1 ? src1 : src2;
  const int* rowstart = g1 ? rs1 : rs2;
  const int* eid = g1 ? eid1 : eid2;
  const float* bias = g1 ? bias1 : bias2;
  const int goff = g1 ? 0 : 512;
  const int colbase = g1 ? 0 : 256;
  const int s0 = rowstart[nid], s1 = rowstart[nid + 1];
  float mx = -__int_as_float(0x7f800000);
  for (int i = s0 + lane; i < s1; i += 64) mx = fmaxf(mx, logits[eid[i]]);
#pragma unroll
  for (int d = 1; d < 64; d <<= 1) mx = fmaxf(mx, __shfl_xor(mx, d));
  float den = 0.f;
  float acc0 = 0.f, acc1 = 0.f, acc2 = 0.f, acc3 = 0.f;
  for (int i = s0; i < s1; ++i) {
    int e = eid[i];
    float w = __expf(logits[e] - mx);
    int s = src[e];
    ushort4 v = *(const ushort4*)(xlr + (size_t)s * 1024 + goff + lane * 4);
    den += w;
    acc0 += w * b2f(v.x); acc1 += w * b2f(v.y);
    acc2 += w * b2f(v.z); acc3 += w * b2f(v.w);
  }
  float inv = 1.f / (den + 1e-16f);
  int c = lane * 4;
  ushort4 o;
  o.x = f2b(acc0 * inv + bias[c + 0]);
  o.y = f2b(acc1 * inv + bias[c + 1]);
  o.z = f2b(acc2 * inv + bias[c + 2]);
  o.w = f2b(acc3 * inv + bias[c + 3]);
  *(ushort4*)(xnext + (size_t)nid * 512 + colbase + c) = o;
}

// ---------------- generic MFMA GEMM (A + B LDS-staged, 64-row tile) ----------------
template <bool RELU, bool OBF16>
__global__ __launch_bounds__(256, 2) void mgemm_k(
    const ushort* __restrict__ A, int lda, const ushort* __restrict__ WT, int K,
    const float* __restrict__ bias, void* __restrict__ C, int ldc, int M) {
  __shared__ ushort As[64][40];
  __shared__ ushort Bs[256][40];
  const int tid = threadIdx.x;
  const int wave = tid >> 6, lane = tid & 63;
  const int quad = lane >> 4, l15 = lane & 15;
  const int m0 = blockIdx.x * 64;
  const int ncol0 = blockIdx.y * 256;
  const ushort* WTb = WT + (size_t)ncol0 * K;
  const int arow = tid >> 2, akc = (tid & 3) << 3;
  int am = m0 + arow;
  if (am >= M) am = M - 1;
  f32x4 acc[4][4];
#pragma unroll
  for (int i = 0; i < 4; ++i)
#pragma unroll
    for (int j = 0; j < 4; ++j) acc[i][j] = (f32x4){0.f, 0.f, 0.f, 0.f};
  for (int k0 = 0; k0 < K; k0 += 32) {
    *(uint4*)&As[arow][akc] = *(const uint4*)(A + (size_t)am * lda + k0 + akc);
#pragma unroll
    for (int r = 0; r < 4; ++r) {
      int row = arow + r * 64;
      *(uint4*)&Bs[row][akc] = *(const uint4*)(WTb + (size_t)row * K + k0 + akc);
    }
    __syncthreads();
    bf16x8 bfr[4];
#pragma unroll
    for (int ni = 0; ni < 4; ++ni)
      bfr[ni] = *(const bf16x8*)&Bs[wave * 64 + ni * 16 + l15][quad * 8];
#pragma unroll
    for (int mi = 0; mi < 4; ++mi) {
      bf16x8 af = *(const bf16x8*)&As[mi * 16 + l15][quad * 8];
#pragma unroll
      for (int ni = 0; ni < 4; ++ni) acc[mi][ni] = MFMA16(af, bfr[ni], acc[mi][ni]);
    }
    __syncthreads();
  }
#pragma unroll
  for (int mi = 0; mi < 4; ++mi)
#pragma unroll
    for (int ni = 0; ni < 4; ++ni) {
      int c = ncol0 + wave * 64 + ni * 16 + l15;
      float bv = bias[c];
#pragma unroll
      for (int r = 0; r < 4; ++r) {
        int m = m0 + mi * 16 + quad * 4 + r;
        if (m < M) {
          float v = acc[mi][ni][r] + bv;
          if (RELU) v = fmaxf(v, 0.f);
          if (OBF16) ((ushort*)C)[(size_t)m * ldc + c] = f2b(v);
          else       ((float*)C)[(size_t)m * ldc + c] = v;
        }
      }
    }
}

// ---------------- fused edge-encoder MLP, both graphs; g1 also emits ZE ----------------
__global__ __launch_bounds__(256, 2) void enc_fused_k(
    const float* __restrict__ attr1, ushort* __restrict__ e1, ushort* __restrict__ ZE,
    const float* __restrict__ attr2, ushort* __restrict__ e2,
    const float* __restrict__ W0, const float* __restrict__ b0,
    const ushort* __restrict__ W1T, const float* __restrict__ b1,
    const ushort* __restrict__ W2T, const float* __restrict__ b2,
    const ushort* __restrict__ WfT, const float* __restrict__ bfold) {
  __shared__ ushort h[64][264];
  __shared__ ushort Bs[256][40];
  __shared__ float w0s[256], b0s[256];
  const int tid = threadIdx.x;
  const int wave = tid >> 6, lane = tid & 63;
  const int quad = lane >> 4, l15 = lane & 15;
  const bool g1 = blockIdx.x < NE1 / 64;
  const float* attr = g1 ? attr1 : attr2;
  ushort* eout = g1 ? e1 : e2;
  const int m0 = (g1 ? blockIdx.x : blockIdx.x - NE1 / 64) * 64;
  const int arow = tid >> 2, akc = (tid & 3) << 3;
  w0s[tid] = W0[tid];
  b0s[tid] = b0[tid];
  float a0 = attr[m0 + arow];
  __syncthreads();
  {
    int c0 = (tid & 3) * 64;
#pragma unroll
    for (int j = 0; j < 64; j += 4) {
      int c = c0 + j;
      ushort4 o;
      o.x = f2b(fmaxf(a0 * w0s[c + 0] + b0s[c + 0], 0.f));
      o.y = f2b(fmaxf(a0 * w0s[c + 1] + b0s[c + 1], 0.f));
      o.z = f2b(fmaxf(a0 * w0s[c + 2] + b0s[c + 2], 0.f));
      o.w = f2b(fmaxf(a0 * w0s[c + 3] + b0s[c + 3], 0.f));
      *(ushort4*)&h[arow][c] = o;
    }
  }
  __syncthreads();
  // phase A: h1 = relu(h0 @ W1 + b1)
  f32x4 acc[4][4];
#pragma unroll
  for (int i = 0; i < 4; ++i)
#pragma unroll
    for (int j = 0; j < 4; ++j) acc[i][j] = (f32x4){0.f, 0.f, 0.f, 0.f};
  for (int k0 = 0; k0 < 256; k0 += 32) {
#pragma unroll
    for (int r = 0; r < 4; ++r) {
      int row = arow + r * 64;
      *(uint4*)&Bs[row][akc] = *(const uint4*)(W1T + (size_t)row * 256 + k0 + akc);
    }
    __syncthreads();
    bf16x8 bfr[4];
#pragma unroll
    for (int ni = 0; ni < 4; ++ni)
      bfr[ni] = *(const bf16x8*)&Bs[wave * 64 + ni * 16 + l15][quad * 8];
#pragma unroll
    for (int mi = 0; mi < 4; ++mi) {
      bf16x8 af = *(const bf16x8*)&h[mi * 16 + l15][k0 + quad * 8];
#pragma unroll
      for (int ni = 0; ni < 4; ++ni) acc[mi][ni] = MFMA16(af, bfr[ni], acc[mi][ni]);
    }
    __syncthreads();
  }
#pragma unroll
  for (int mi = 0; mi < 4; ++mi)
#pragma unroll
    for (int ni = 0; ni < 4; ++ni) {
      int c = wave * 64 + ni * 16 + l15;
      float bv = b1[c];
#pragma unroll
      for (int r = 0; r < 4; ++r)
        h[mi * 16 + quad * 4 + r][c] = f2b(fmaxf(acc[mi][ni][r] + bv, 0.f));
    }
  __syncthreads();
  // phase B: eout = h1 @ W2 + b2
  f32x4 acc2[4][4];
#pragma unroll
  for (int i = 0; i < 4; ++i)
#pragma unroll
    for (int j = 0; j < 4; ++j) acc2[i][j] = (f32x4){0.f, 0.f, 0.f, 0.f};
  for (int k0 = 0; k0 < 256; k0 += 32) {
#pragma unroll
    for (int r = 0; r < 4; ++r) {
      int row = arow + r * 64;
      *(uint4*)&Bs[row][akc] = *(const uint4*)(W2T + (size_t)row * 256 + k0 + akc);
    }
    __syncthreads();
    bf16x8 bfr[4];
#pragma unroll
    for (int ni = 0; ni < 4; ++ni)
      bfr[ni] = *(const bf16x8*)&Bs[wave * 64 + ni * 16 + l15][quad * 8];
#pragma unroll
    for (int mi = 0; mi < 4; ++mi) {
      bf16x8 af = *(const bf16x8*)&h[mi * 16 + l15][k0 + quad * 8];
#pragma unroll
      for (int ni = 0; ni < 4; ++ni) acc2[mi][ni] = MFMA16(af, bfr[ni], acc2[mi][ni]);
    }
    __syncthreads();
  }
#pragma unroll
  for (int mi = 0; mi < 4; ++mi)
#pragma unroll
    for (int ni = 0; ni < 4; ++ni) {
      int c = wave * 64 + ni * 16 + l15;
      float bv = b2[c];
#pragma unroll
      for (int r = 0; r < 4; ++r) {
        int m = m0 + mi * 16 + quad * 4 + r;
        eout[(size_t)m * 256 + c] = f2b(acc2[mi][ni][r] + bv);
      }
    }
  if (!g1) return;
  // phase C (g1 only): ZE = h1 @ Wf + bfold
  f32x4 acc3[4][4];
#pragma unroll
  for (int i = 0; i < 4; ++i)
#pragma unroll
    for (int j = 0; j < 4; ++j) acc3[i][j] = (f32x4){0.f, 0.f, 0.f, 0.f};
  for (int k0 = 0; k0 < 256; k0 += 32) {
    __syncthreads();
#pragma unroll
    for (int r = 0; r < 4; ++r) {
      int row = arow + r * 64;
      *(uint4*)&Bs[row][akc] = *(const uint4*)(WfT + (size_t)row * 256 + k0 + akc);
    }
    __syncthreads();
    bf16x8 bfr[4];
#pragma unroll
    for (int ni = 0; ni < 4; ++ni)
      bfr[ni] = *(const bf16x8*)&Bs[wave * 64 + ni * 16 + l15][quad * 8];
#pragma unroll
    for (int mi = 0; mi < 4; ++mi) {
      bf16x8 af = *(const bf16x8*)&h[mi * 16 + l15][k0 + quad * 8];
#pragma unroll
      for (int ni = 0; ni < 4; ++ni) acc3[mi][ni] = MFMA16(af, bfr[ni], acc3[mi][ni]);
    }
  }
#pragma unroll
  for (int mi = 0; mi < 4; ++mi)
#pragma unroll
    for (int ni = 0; ni < 4; ++ni) {
      int c = wave * 64 + ni * 16 + l15;
      float bv = bfold[c];
#pragma unroll
      for (int r = 0; r < 4; ++r) {
        int m = m0 + mi * 16 + quad * 4 + r;
        ZE[(size_t)m * 256 + c] = f2b(acc3[mi][ni][r] + bv);
      }
    }
}

// ---------------- fused MFMA attention logits, both graphs, low-LDS ----------------
// xs is staged in two 32-row halves into the (dead after K-loop) Bs buffer.
__global__ __launch_bounds__(256, 4) void attn_mfma_k(
    const ushort* __restrict__ e1, const ushort* __restrict__ e2,
    const ushort* __restrict__ weT1, const ushort* __restrict__ weT2,
    const float* __restrict__ att1, const float* __restrict__ att2,
    const ushort* __restrict__ xlr,
    const int* __restrict__ src1, const int* __restrict__ dst1,
    const int* __restrict__ src2, const int* __restrict__ dst2,
    float* __restrict__ logits1, float* __restrict__ logits2) {
  __shared__ ushort As[64][40];
  __shared__ ushort Bs[256][40];
  __shared__ float red[4][64];
  __shared__ float att_s[256];
  __shared__ int sid[64], did[64];
  const int tid = threadIdx.x;
  const int wave = tid >> 6, lane = tid & 63;
  const int quad = lane >> 4, l15 = lane & 15;
  const bool g1 = blockIdx.x < NE1 / 64;
  const ushort* eenc = g1 ? e1 : e2;
  const ushort* weT = g1 ? weT1 : weT2;
  const float* att = g1 ? att1 : att2;
  const int* src = g1 ? src1 : src2;
  const int* dst = g1 ? dst1 : dst2;
  float* logits = g1 ? logits1 : logits2;
  const int goff = g1 ? 0 : 512;
  const int m0 = (g1 ? blockIdx.x : blockIdx.x - NE1 / 64) * 64;
  const int arow = tid >> 2, akc = (tid & 3) << 3;
  att_s[tid] = att[tid];
  if (tid < 64) { sid[tid] = src[m0 + tid]; did[tid] = dst[m0 + tid]; }
  f32x4 acc[4][4];
#pragma unroll
  for (int i = 0; i < 4; ++i)
#pragma unroll
    for (int j = 0; j < 4; ++j) acc[i][j] = (f32x4){0.f, 0.f, 0.f, 0.f};
  for (int k0 = 0; k0 < 256; k0 += 32) {
    *(uint4*)&As[arow][akc] = *(const uint4*)(eenc + (size_t)(m0 + arow) * 256 + k0 + akc);
#pragma unroll
    for (int r = 0; r < 4; ++r) {
      int row = arow + r * 64;
      *(uint4*)&Bs[row][akc] = *(const uint4*)(weT + (size_t)row * 256 + k0 + akc);
    }
    __syncthreads();
    bf16x8 bfr[4];
#pragma unroll
    for (int ni = 0; ni < 4; ++ni)
      bfr[ni] = *(const bf16x8*)&Bs[wave * 64 + ni * 16 + l15][quad * 8];
#pragma unroll
    for (int mi = 0; mi < 4; ++mi) {
      bf16x8 af = *(const bf16x8*)&As[mi * 16 + l15][quad * 8];
#pragma unroll
      for (int ni = 0; ni < 4; ++ni) acc[mi][ni] = MFMA16(af, bfr[ni], acc[mi][ni]);
    }
    __syncthreads();
  }
  // epilogue: xs = bf16(xl[src] + xr[dst]) staged into Bs region, 32 rows at a time
  ushort (*xs)[264] = (ushort (*)[264])Bs;
  float part[4][4];
#pragma unroll
  for (int mi = 0; mi < 4; ++mi)
#pragma unroll
    for (int r = 0; r < 4; ++r) part[mi][r] = 0.f;
#pragma unroll
  for (int half = 0; half < 2; ++half) {
    {
      int lr = tid >> 3;            // 0..31
      int row = half * 32 + lr;
      int c0 = (tid & 7) * 32;      // 32 cols/thread
      const ushort* pl = xlr + (size_t)sid[row] * 1024 + goff;
      const ushort* pr = xlr + (size_t)did[row] * 1024 + goff + 256;
#pragma unroll
      for (int j = 0; j < 8; ++j) {
        int c = c0 + 4 * j;
        ushort4 a = *(const ushort4*)(pl + c);
        ushort4 b = *(const ushort4*)(pr + c);
        ushort4 o;
        o.x = f2b(b2f(a.x) + b2f(b.x)); o.y = f2b(b2f(a.y) + b2f(b.y));
        o.z = f2b(b2f(a.z) + b2f(b.z)); o.w = f2b(b2f(a.w) + b2f(b.w));
        *(ushort4*)&xs[lr][c] = o;
      }
    }
    __syncthreads();
#pragma unroll
    for (int mi = half * 2; mi < half * 2 + 2; ++mi)
#pragma unroll
      for (int ni = 0; ni < 4; ++ni) {
        int c = wave * 64 + ni * 16 + l15;
        float av = att_s[c];
#pragma unroll
        for (int r = 0; r < 4; ++r) {
          int lr = mi * 16 + quad * 4 + r - half * 32;
          float v = acc[mi][ni][r] + b2f(xs[lr][c]);
          v = v > 0.f ? v : 0.2f * v;
          part[mi][r] += v * av;
        }
      }
    __syncthreads();
  }
#pragma unroll
  for (int d = 1; d < 16; d <<= 1)
#pragma unroll
    for (int mi = 0; mi < 4; ++mi)
#pragma unroll
      for (int r = 0; r < 4; ++r) part[mi][r] += __shfl_xor(part[mi][r], d);
  if (l15 == 0)
#pragma unroll
    for (int mi = 0; mi < 4; ++mi)
#pragma unroll
      for (int r = 0; r < 4; ++r) red[wave][mi * 16 + quad * 4 + r] = part[mi][r];
  __syncthreads();
  if (tid < 64)
    logits[m0 + tid] = red[0][tid] + red[1][tid] + red[2][tid] + red[3][tid];
}

// ---------------- decoder: h0 staged from ZE-fold, one MFMA phase + dot ----------------
__global__ __launch_bounds__(256, 2) void dec3_k(
    const ushort* __restrict__ ZE, const float* __restrict__ Z,
    const ushort* __restrict__ W1T, const float* __restrict__ b1,
    const float* __restrict__ W2, const float* __restrict__ b2,
    const int* __restrict__ src, const int* __restrict__ dst,
    float* __restrict__ out) {
  __shared__ ushort Bs[256][40];
  __shared__ ushort h0[64][264];
  __shared__ float red[4][64];
  const int tid = threadIdx.x;
  const int wave = tid >> 6, lane = tid & 63;
  const int quad = lane >> 4, l15 = lane & 15;
  const int m0 = blockIdx.x * 64;
  const int arow = tid >> 2, akc = (tid & 3) << 3;
  {
    int gs = src[m0 + arow], gd = dst[m0 + arow];
    int c0 = (tid & 3) * 64;
    const float* za = Z + (size_t)gs * 512;
    const float* zb = Z + (size_t)gd * 512 + 256;
    const ushort* ze = ZE + (size_t)(m0 + arow) * 256;
#pragma unroll
    for (int j = 0; j < 16; ++j) {
      int c = c0 + 4 * j;
      float4 a = *(const float4*)(za + c);
      float4 b = *(const float4*)(zb + c);
      ushort4 e = *(const ushort4*)(ze + c);
      ushort4 o;
      o.x = f2b(fmaxf(a.x + b.x + b2f(e.x), 0.f));
      o.y = f2b(fmaxf(a.y + b.y + b2f(e.y), 0.f));
      o.z = f2b(fmaxf(a.z + b.z + b2f(e.z), 0.f));
      o.w = f2b(fmaxf(a.w + b.w + b2f(e.w), 0.f));
      *(ushort4*)&h0[arow][c] = o;
    }
  }
  __syncthreads();
  f32x4 acc2[4][4];
#pragma unroll
  for (int i = 0; i < 4; ++i)
#pragma unroll
    for (int j = 0; j < 4; ++j) acc2[i][j] = (f32x4){0.f, 0.f, 0.f, 0.f};
  for (int k0 = 0; k0 < 256; k0 += 32) {
#pragma unroll
    for (int r = 0; r < 4; ++r) {
      int row = arow + r * 64;
      *(uint4*)&Bs[row][akc] = *(const uint4*)(W1T + (size_t)row * 256 + k0 + akc);
    }
    __syncthreads();
    bf16x8 bfr[4];
#pragma unroll
    for (int ni = 0; ni < 4; ++ni)
      bfr[ni] = *(const bf16x8*)&Bs[wave * 64 + ni * 16 + l15][quad * 8];
#pragma unroll
    for (int mi = 0; mi < 4; ++mi) {
      bf16x8 af = *(const bf16x8*)&h0[mi * 16 + l15][k0 + quad * 8];
#pragma unroll
      for (int ni = 0; ni < 4; ++ni) acc2[mi][ni] = MFMA16(af, bfr[ni], acc2[mi][ni]);
    }
    __syncthreads();
  }
  float part[4][4];
#pragma unroll
  for (int mi = 0; mi < 4; ++mi)
#pragma unroll
    for (int r = 0; r < 4; ++r) part[mi][r] = 0.f;
#pragma unroll
  for (int mi = 0; mi < 4; ++mi)
#pragma unroll
    for (int ni = 0; ni < 4; ++ni) {
      int c = wave * 64 + ni * 16 + l15;
      float bv = b1[c], wv = W2[c];
#pragma unroll
      for (int r = 0; r < 4; ++r) {
        float v = fmaxf(acc2[mi][ni][r] + bv, 0.f);
        part[mi][r] += v * wv;
      }
    }
#pragma unroll
  for (int d = 1; d < 16; d <<= 1)
#pragma unroll
    for (int mi = 0; mi < 4; ++mi)
#pragma unroll
      for (int r = 0; r < 4; ++r) part[mi][r] += __shfl_xor(part[mi][r], d);
  if (l15 == 0)
#pragma unroll
    for (int mi = 0; mi < 4; ++mi)
#pragma unroll
      for (int r = 0; r < 4; ++r) red[wave][mi * 16 + quad * 4 + r] = part[mi][r];
  __syncthreads();
  if (tid < 64) {
    float s = red[0][tid] + red[1][tid] + red[2][tid] + red[3][tid];
    out[m0 + tid] = s + b2[0];
  }
}

// ---------------- host ----------------

extern "C" void kernel_launch(void* const* d_in, const int* in_sizes, int n_in,
                              void* d_out, int out_size, void* d_ws, size_t ws_size,
                              hipStream_t stream) {
  const int*   eidx1  = (const int*)d_in[0];
  const float* eattr1 = (const float*)d_in[1];
  const int*   eidx2  = (const int*)d_in[2];
  const float* eattr2 = (const float*)d_in[3];
  const int*   batch  = (const int*)d_in[4];
  const float* tval   = (const float*)d_in[5];
  const float* te_W0 = (const float*)d_in[6];
  const float* te_b0 = (const float*)d_in[7];
  const float* te_W1 = (const float*)d_in[8];
  const float* te_b1 = (const float*)d_in[9];
  const float* te_W2 = (const float*)d_in[10];
  const float* te_b2 = (const float*)d_in[11];
  const float* ee_W0 = (const float*)d_in[12];
  const float* ee_b0 = (const float*)d_in[13];
  const float* ee_W1 = (const float*)d_in[14];
  const float* ee_b1 = (const float*)d_in[15];
  const float* ee_W2 = (const float*)d_in[16];
  const float* ee_b2 = (const float*)d_in[17];
  const float* dec_W0 = (const float*)d_in[18];
  const float* dec_b0 = (const float*)d_in[19];
  const float* dec_W1 = (const float*)d_in[20];
  const float* dec_b1 = (const float*)d_in[21];
  const float* dec_W2 = (const float*)d_in[22];
  const float* dec_b2 = (const float*)d_in[23];
  const float* gg_Wl  = (const float*)d_in[24];
  const float* gg_bl  = (const float*)d_in[25];
  const float* gg_Wr  = (const float*)d_in[26];
  const float* gg_br  = (const float*)d_in[27];
  const float* gg_We  = (const float*)d_in[28];
  const float* gg_att = (const float*)d_in[29];
  const float* gg_bias= (const float*)d_in[30];
  const float* gf_Wl  = (const float*)d_in[31];
  const float* gf_bl  = (const float*)d_in[32];
  const float* gf_Wr  = (const float*)d_in[33];
  const float* gf_br  = (const float*)d_in[34];
  const float* gf_We  = (const float*)d_in[35];
  const float* gf_att = (const float*)d_in[36];
  const float* gf_bias= (const float*)d_in[37];
  (void)in_sizes; (void)n_in; (void)out_size; (void)ws_size;

  const int* src1 = eidx1;
  const int* dst1 = eidx1 + NE1;
  const int* src2 = eidx2;
  const int* dst2 = eidx2 + NE2;

  char* base = (char*)d_ws;
  size_t off = 0;
  auto alloc = [&](size_t bytes) {
    void* p = base + off;
    off += (bytes + 255) & ~(size_t)255;
    return p;
  };
  ushort* x_a    = (ushort*)alloc((size_t)NNODE * 512 * 2);
  ushort* x_b    = (ushort*)alloc((size_t)NNODE * 512 * 2);
  ushort* xlr    = (ushort*)alloc((size_t)NNODE * 1024 * 2);
  float*  Z      = (float*)alloc((size_t)NNODE * 512 * 4);
  ushort* e1     = (ushort*)alloc((size_t)NE1 * Hd * 2);
  ushort* e2     = (ushort*)alloc((size_t)NE2 * Hd * 2);
  ushort* ZE     = (ushort*)alloc((size_t)NE1 * Hd * 2);
  float*  logits1= (float*)alloc((size_t)NE1 * 4);
  float*  logits2= (float*)alloc((size_t)NE2 * 4);
  float*  tenc   = (float*)alloc((size_t)16 * Hd * 4);
  ushort* eeW1T  = (ushort*)alloc((size_t)256 * 256 * 2);
  ushort* eeW2T  = (ushort*)alloc((size_t)256 * 256 * 2);
  ushort* decZT  = (ushort*)alloc((size_t)512 * 512 * 2);
  ushort* decW1T = (ushort*)alloc((size_t)256 * 256 * 2);
  ushort* WfT    = (ushort*)alloc((size_t)256 * 256 * 2);
  float*  bfold  = (float*)alloc((size_t)256 * 4);
  ushort* wlrT   = (ushort*)alloc((size_t)6 * 512 * 512 * 2);  // [2*i+g]
  ushort* weT    = (ushort*)alloc((size_t)6 * 256 * 256 * 2);  // [2*i+g]
  float*  biascat= (float*)alloc((size_t)6 * 1024 * 4);
  float*  zerob  = (float*)alloc((size_t)512 * 4);
  int* cnt1      = (int*)alloc((size_t)NNODE * 4);
  int* cur1      = (int*)alloc((size_t)NNODE * 4);
  int* rs1       = (int*)alloc((size_t)(NNODE + 1) * 4);
  int* eid1      = (int*)alloc((size_t)NE1 * 4);
  int* cnt2      = (int*)alloc((size_t)NNODE * 4);
  int* cur2      = (int*)alloc((size_t)NNODE * 4);
  int* rs2       = (int*)alloc((size_t)(NNODE + 1) * 4);
  int* eid2      = (int*)alloc((size_t)NE2 * 4);

  float* out = (float*)d_out;

  // ---- merged setup ----
  init_small_k<<<(NNODE + 512 + 6144 + 255) / 256, 256, 0, stream>>>(
      cnt1, cur1, cnt2, cur2, zerob, biascat, gg_bl, gg_br, gf_bl, gf_br);
  fold_k<<<256, 256, 0, stream>>>(dec_W0, dec_b0, ee_W2, ee_b2, WfT, bfold);

  TransArgs ta;
  int nt = 0, cum = 0;
  auto add = [&](const float* s, ushort* d, int K, int noff, int ld) {
    ta.t[nt].src = s; ta.t[nt].dst = d; ta.t[nt].K = K;
    ta.t[nt].n_off = noff; ta.t[nt].ld = ld; ta.t[nt].start = cum;
    cum += (K / 32) * 8; ++nt;
  };
  add(ee_W1, eeW1T, 256, 0, 256);
  add(ee_W2, eeW2T, 256, 0, 256);
  add(dec_W1, decW1T, 256, 0, 256);
  add(dec_W0, decZT, 512, 0, 512);
  add(dec_W0 + 512 * 256, decZT, 512, 256, 512);
  for (int i = 0; i < 3; ++i) {
    add(gg_Wl + (size_t)i * 512 * 256, wlrT + (size_t)(2 * i) * 512 * 512, 512, 0, 512);
    add(gg_Wr + (size_t)i * 512 * 256, wlrT + (size_t)(2 * i) * 512 * 512, 512, 256, 512);
    add(gf_Wl + (size_t)i * 512 * 256, wlrT + (size_t)(2 * i + 1) * 512 * 512, 512, 0, 512);
    add(gf_Wr + (size_t)i * 512 * 256, wlrT + (size_t)(2 * i + 1) * 512 * 512, 512, 256, 512);
    add(gg_We + (size_t)i * 65536, weT + (size_t)(2 * i) * 65536, 256, 0, 256);
    add(gf_We + (size_t)i * 65536, weT + (size_t)(2 * i + 1) * 65536, 256, 0, 256);
  }
  for (int i = nt; i < 24; ++i) ta.t[i].start = 0x7fffffff;
  trans_all_k<<<cum, 256, 0, stream>>>(ta);

  // ---- CSR build ----
  deg_all_k<<<(NE1 + NE2) / 256, 256, 0, stream>>>(dst1, cnt1, dst2, cnt2);
  scan_k<<<2, 640, 0, stream>>>(cnt1, rs1, cnt2, rs2);
  fill_all_k<<<(NE1 + NE2) / 256, 256, 0, stream>>>(dst1, rs1, cur1, eid1, dst2, rs2, cur2, eid2);

  // ---- fused edge encoder (both graphs; g1 blocks also emit ZE) ----
  enc_fused_k<<<(NE1 + NE2) / 64, 256, 0, stream>>>(
      eattr1, e1, ZE, eattr2, e2, ee_W0, ee_b0, eeW1T, ee_b1, eeW2T, ee_b2, WfT, bfold);

  // ---- time encoding -> x0 (bf16) ----
  time_mlp_k<<<16, 256, 0, stream>>>(tval, te_W0, te_b0, te_W1, te_b1, te_W2, te_b2, tenc);
  build_x0_k<<<(NNODE * 512) / 256, 256, 0, stream>>>(batch, tenc, x_a);

  ushort* x_cur = x_a;
  ushort* x_nxt = x_b;
  const int ngrid = (NNODE + 63) / 64;
  for (int i = 0; i < 3; ++i) {
    mgemm_k<false, true><<<dim3(ngrid, 4), 256, 0, stream>>>(
        x_cur, 512, wlrT + (size_t)(2 * i) * 512 * 512, 512, biascat + (size_t)i * 1024, xlr, 1024, NNODE);
    attn_mfma_k<<<(NE1 + NE2) / 64, 256, 0, stream>>>(
        e1, e2, weT + (size_t)(2 * i) * 65536, weT + (size_t)(2 * i + 1) * 65536,
        gg_att + i * Hd, gf_att + i * Hd, xlr, src1, dst1, src2, dst2, logits1, logits2);
    aggregate_k<<<2 * AGRID, 256, 0, stream>>>(
        logits1, logits2, xlr, src1, src2, rs1, rs2, eid1, eid2,
        gg_bias + i * Hd, gf_bias + i * Hd, x_nxt);
    ushort* t = x_cur; x_cur = x_nxt; x_nxt = t;
  }

  // ---- decoder: Z per-node, then per-edge fused MLP (ZE-folded) ----
  mgemm_k<false, false><<<dim3(ngrid, 2), 256, 0, stream>>>(
      x_cur, 512, decZT, 512, zerob, Z, 512, NNODE);
  dec3_k<<<NE1 / 64, 256, 0, stream>>>(ZE, Z, decW1T, dec_b1, dec_W2, dec_b2, src1, dst1, out);
}

// Round 10
// 770.263 us; speedup vs baseline: 1.7052x; 1.2094x over previous
//
#include <hip/hip_runtime.h>

#define Hd 256
#define NNODE 10000
#define NE1 131072
#define NE2 65536
#define AGRID 2500   // ceil(NNODE/4)
#define TROWS 4097
#define TLD 1792     // 7 * 256 packed table columns

typedef __attribute__((ext_vector_type(8))) short bf16x8;
typedef __attribute__((ext_vector_type(4))) float f32x4;

#define MFMA16(a, b, c) __builtin_amdgcn_mfma_f32_16x16x32_bf16((a), (b), (c), 0, 0, 0)

__device__ __forceinline__ float b2f(ushort u) { return __uint_as_float(((unsigned)u) << 16); }
__device__ __forceinline__ ushort f2b(float f) {
  unsigned u = __float_as_uint(f);
  return (ushort)((u + 0x7fffu + ((u >> 16) & 1u)) >> 16);
}

// ---------------- small kernels ----------------

__global__ void time_mlp_k(const float* __restrict__ tval,
                           const float* __restrict__ W0, const float* __restrict__ b0,
                           const float* __restrict__ W1, const float* __restrict__ b1,
                           const float* __restrict__ W2, const float* __restrict__ b2,
                           float* __restrict__ tenc) {
  __shared__ float h0[Hd], h1[Hd];
  int b = blockIdx.x, j = threadIdx.x;
  float t = tval[b];
  h0[j] = fmaxf(t * W0[j] + b0[j], 0.f);
  __syncthreads();
  float a = b1[j];
  for (int k = 0; k < Hd; ++k) a += h0[k] * W1[k * Hd + j];
  h1[j] = fmaxf(a, 0.f);
  __syncthreads();
  float c = b2[j];
  for (int k = 0; k < Hd; ++k) c += h1[k] * W2[k * Hd + j];
  tenc[b * Hd + j] = c;
}

__global__ void build_x0_k(const int* __restrict__ batch, const float* __restrict__ tenc,
                           ushort* __restrict__ x0) {
  int idx = blockIdx.x * 256 + threadIdx.x;
  int n = idx >> 9;
  x0[idx] = f2b(tenc[batch[n] * Hd + (idx & 255)]);
}

__global__ void init_small_k(int* __restrict__ cnt1, int* __restrict__ cur1,
                             int* __restrict__ cnt2, int* __restrict__ cur2,
                             float* __restrict__ zerob, float* __restrict__ biascat,
                             const float* __restrict__ gg_bl, const float* __restrict__ gg_br,
                             const float* __restrict__ gf_bl, const float* __restrict__ gf_br) {
  int i = blockIdx.x * 256 + threadIdx.x;
  if (i < NNODE) { cnt1[i] = 0; cur1[i] = 0; cnt2[i] = 0; cur2[i] = 0; return; }
  i -= NNODE;
  if (i < 512) { zerob[i] = 0.f; return; }
  i -= 512;
  if (i < 6144) {
    int layer = i >> 10, c = i & 1023;
    float v;
    if (c < 256)      v = gg_bl[layer * 256 + c];
    else if (c < 512) v = gg_br[layer * 256 + c - 256];
    else if (c < 768) v = gf_bl[layer * 256 + c - 512];
    else              v = gf_br[layer * 256 + c - 768];
    biascat[layer * 1024 + c] = v;
  }
}

// Packed fold: WcatT[y][n][k] = sum_j W2[k][j] * Wy[j][n]  (y<6: We[2i+g]; y=6: dec_W0c)
// bcat[y*256+n] = (y==6 ? dec_b0[n] : 0) + sum_j ee_b2[j] * Wy[j][n]
__global__ void fold2_k(const float* __restrict__ gg_We, const float* __restrict__ gf_We,
                        const float* __restrict__ dec_W0, const float* __restrict__ dec_b0,
                        const float* __restrict__ eeW2, const float* __restrict__ eeb2,
                        ushort* __restrict__ WcatT, float* __restrict__ bcat) {
  __shared__ float col[256];
  int n = blockIdx.x, y = blockIdx.y, k = threadIdx.x;
  if (y < 6) {
    int i = y >> 1, g = y & 1;
    const float* src = (g == 0 ? gg_We : gf_We) + (size_t)i * 65536;
    col[k] = src[(size_t)k * 256 + n];
  } else {
    col[k] = dec_W0[(size_t)(1024 + k) * 256 + n];
  }
  __syncthreads();
  float acc = 0.f;
  const float* w2row = eeW2 + (size_t)k * 256;
  for (int j = 0; j < 256; ++j) acc += w2row[j] * col[j];
  WcatT[((size_t)y * 256 + n) * 256 + k] = f2b(acc);
  if (k == 0) {
    float bb = (y == 6) ? dec_b0[n] : 0.f;
    for (int j = 0; j < 256; ++j) bb += eeb2[j] * col[j];
    bcat[y * 256 + n] = bb;
  }
}

// H1[i][j] = relu( relu((i/4096)*W0 + b0) @ W1 + b1 )[j]   (bf16)
__global__ void build_h1_k(const float* __restrict__ W0, const float* __restrict__ b0,
                           const float* __restrict__ W1, const float* __restrict__ b1,
                           ushort* __restrict__ H1) {
  __shared__ float h0[256];
  int i = blockIdx.x, j = threadIdx.x;
  float a = (float)i / 4096.f;
  h0[j] = fmaxf(a * W0[j] + b0[j], 0.f);
  __syncthreads();
  float acc = b1[j];
  for (int k = 0; k < 256; ++k) acc += h0[k] * W1[k * 256 + j];
  H1[(size_t)i * 256 + j] = f2b(fmaxf(acc, 0.f));
}

// ---------------- merged weight transposes ----------------
struct TT { const float* src; ushort* dst; int K; int n_off; int ld; int start; };
struct TransArgs { TT t[24]; };

__global__ void trans_all_k(TransArgs a) {
  int b = blockIdx.x;
  int ti = 0;
  while (ti + 1 < 24 && a.t[ti + 1].start <= b) ++ti;
  TT tk = a.t[ti];
  int lb = b - tk.start;
  int gx = tk.K >> 5;
  int k0 = (lb % gx) * 32, n0 = (lb / gx) * 32;
  __shared__ float t[32][33];
  int tx = threadIdx.x & 31, ty = threadIdx.x >> 5;
#pragma unroll
  for (int p = 0; p < 4; ++p)
    t[ty + 8 * p][tx] = tk.src[(size_t)(k0 + ty + 8 * p) * 256 + n0 + tx];
  __syncthreads();
#pragma unroll
  for (int p = 0; p < 4; ++p)
    tk.dst[(size_t)(tk.n_off + n0 + ty + 8 * p) * tk.ld + k0 + tx] = f2b(t[tx][ty + 8 * p]);
}

// ---------------- CSR build (by dst) ----------------

__global__ void deg_all_k(const int* __restrict__ dst1, int* __restrict__ cnt1,
                          const int* __restrict__ dst2, int* __restrict__ cnt2) {
  int e = blockIdx.x * 256 + threadIdx.x;
  if (e < NE1) atomicAdd(cnt1 + dst1[e], 1);
  else if (e - NE1 < NE2) atomicAdd(cnt2 + dst2[e - NE1], 1);
}

__global__ void scan_k(const int* __restrict__ cnt1, int* __restrict__ rs1,
                       const int* __restrict__ cnt2, int* __restrict__ rs2) {
  const int g = blockIdx.x;
  const int* cnt = g ? cnt2 : cnt1;
  int* rowstart = g ? rs2 : rs1;
  const int E = g ? NE2 : NE1;
  __shared__ int part[626];
  int t = threadIdx.x;
  if (t < 625) {
    int s = 0;
#pragma unroll
    for (int i = 0; i < 16; ++i) s += cnt[t * 16 + i];
    part[t] = s;
  }
  __syncthreads();
  if (t == 0) {
    int run = 0;
    for (int i = 0; i < 625; ++i) { int v = part[i]; part[i] = run; run += v; }
  }
  __syncthreads();
  if (t < 625) {
    int off = part[t];
#pragma unroll
    for (int i = 0; i < 16; ++i) { rowstart[t * 16 + i] = off; off += cnt[t * 16 + i]; }
  }
  if (t == 0) rowstart[NNODE] = E;
}

__global__ void fill_all_k(const int* __restrict__ dst1, const int* __restrict__ rs1,
                           int* __restrict__ cur1, int* __restrict__ eid1,
                           const int* __restrict__ dst2, const int* __restrict__ rs2,
                           int* __restrict__ cur2, int* __restrict__ eid2) {
  int e = blockIdx.x * 256 + threadIdx.x;
  if (e < NE1) {
    int d = dst1[e];
    eid1[rs1[d] + atomicAdd(cur1 + d, 1)] = e;
  } else if (e - NE1 < NE2) {
    int e2 = e - NE1;
    int d = dst2[e2];
    eid2[rs2[d] + atomicAdd(cur2 + d, 1)] = e2;
  }
}

// ---------------- per-edge logits via table lerp (one wave per edge) ----------------
// logit_e = att . leakyrelu( xl[src] + xr[dst] + lerp(T_ew, attr_e) )
__global__ __launch_bounds__(256) void logit_k(
    const float* __restrict__ attr1, const float* __restrict__ attr2,
    const ushort* __restrict__ T, int tcol1, int tcol2,
    const float* __restrict__ att1, const float* __restrict__ att2,
    const ushort* __restrict__ xlr,
    const int* __restrict__ src1, const int* __restrict__ dst1,
    const int* __restrict__ src2, const int* __restrict__ dst2,
    float* __restrict__ logits1, float* __restrict__ logits2) {
  const int tid = threadIdx.x, wave = tid >> 6, lane = tid & 63;
  const bool g1 = blockIdx.x < NE1 / 4;
  const int e = (g1 ? blockIdx.x : blockIdx.x - NE1 / 4) * 4 + wave;
  const float* attr = g1 ? attr1 : attr2;
  const float* att = g1 ? att1 : att2;
  const int* src = g1 ? src1 : src2;
  const int* dst = g1 ? dst1 : dst2;
  float* logits = g1 ? logits1 : logits2;
  const int goff = g1 ? 0 : 512;
  const ushort* Tg = T + (g1 ? tcol1 : tcol2);
  const int c = lane * 4;
  float f = attr[e] * 4096.f;
  int i0 = (int)f;
  i0 = i0 < 0 ? 0 : (i0 > 4095 ? 4095 : i0);
  float w = f - (float)i0;
  const ushort* t0 = Tg + (size_t)i0 * TLD + c;
  ushort4 lo = *(const ushort4*)t0;
  ushort4 hi = *(const ushort4*)(t0 + TLD);
  int s = src[e], d = dst[e];
  ushort4 xa = *(const ushort4*)(xlr + (size_t)s * 1024 + goff + c);
  ushort4 xb = *(const ushort4*)(xlr + (size_t)d * 1024 + goff + 256 + c);
  float4 av = *(const float4*)(att + c);
  float l0 = b2f(lo.x), l1 = b2f(lo.y), l2 = b2f(lo.z), l3 = b2f(lo.w);
  float z0 = b2f(xa.x) + b2f(xb.x) + l0 + w * (b2f(hi.x) - l0);
  float z1 = b2f(xa.y) + b2f(xb.y) + l1 + w * (b2f(hi.y) - l1);
  float z2 = b2f(xa.z) + b2f(xb.z) + l2 + w * (b2f(hi.z) - l2);
  float z3 = b2f(xa.w) + b2f(xb.w) + l3 + w * (b2f(hi.w) - l3);
  z0 = z0 > 0.f ? z0 : 0.2f * z0;
  z1 = z1 > 0.f ? z1 : 0.2f * z1;
  z2 = z2 > 0.f ? z2 : 0.2f * z2;
  z3 = z3 > 0.f ? z3 : 0.2f * z3;
  float p = z0 * av.x + z1 * av.y + z2 * av.z + z3 * av.w;
#pragma unroll
  for (int dd = 1; dd < 64; dd <<= 1) p += __shfl_xor(p, dd);
  if (lane == 0) logits[e] = p;
}

// ---------------- merged softmax + aggregate, both graphs (one wave/node) ----------------
__global__ __launch_bounds__(256) void aggregate_k(
    const float* __restrict__ logits1, const float* __restrict__ logits2,
    const ushort* __restrict__ xlr,
    const int* __restrict__ src1, const int* __restrict__ src2,
    const int* __restrict__ rs1, const int* __restrict__ rs2,
    const int* __restrict__ eid1, const int* __restrict__ eid2,
    const float* __restrict__ bias1, const float* __restrict__ bias2,
    ushort* __restrict__ xnext) {
  const int tid = threadIdx.x;
  const int wave = tid >> 6, lane = tid & 63;
  const bool g1 = blockIdx.x < AGRID;
  const int nid = (g1 ? blockIdx.x : blockIdx.x - AGRID) * 4 + wave;
  if (nid >= NNODE) return;
  const float* logits = g1 ? logits1 : logits2;
  const int* src = g1 ? src1 : src2;
  const int* rowstart = g1 ? rs1 : rs2;
  const int* eid = g1 ? eid1 : eid2;
  const float* bias = g1 ? bias1 : bias2;
  const int goff = g1 ? 0 : 512;
  const int colbase = g1 ? 0 : 256;
  const int s0 = rowstart[nid], s1 = rowstart[nid + 1];
  float mx = -__int_as_float(0x7f800000);
  for (int i = s0 + lane; i < s1; i += 64) mx = fmaxf(mx, logits[eid[i]]);
#pragma unroll
  for (int d = 1; d < 64; d <<= 1) mx = fmaxf(mx, __shfl_xor(mx, d));
  float den = 0.f;
  float acc0 = 0.f, acc1 = 0.f, acc2 = 0.f, acc3 = 0.f;
  for (int i = s0; i < s1; ++i) {
    int e = eid[i];
    float w = __expf(logits[e] - mx);
    int s = src[e];
    ushort4 v = *(const ushort4*)(xlr + (size_t)s * 1024 + goff + lane * 4);
    den += w;
    acc0 += w * b2f(v.x); acc1 += w * b2f(v.y);
    acc2 += w * b2f(v.z); acc3 += w * b2f(v.w);
  }
  float inv = 1.f / (den + 1e-16f);
  int c = lane * 4;
  ushort4 o;
  o.x = f2b(acc0 * inv + bias[c + 0]);
  o.y = f2b(acc1 * inv + bias[c + 1]);
  o.z = f2b(acc2 * inv + bias[c + 2]);
  o.w = f2b(acc3 * inv + bias[c + 3]);
  *(ushort4*)(xnext + (size_t)nid * 512 + colbase + c) = o;
}

// ---------------- generic MFMA GEMM (A + B LDS-staged, 64-row tile) ----------------
template <bool RELU, bool OBF16>
__global__ __launch_bounds__(256, 2) void mgemm_k(
    const ushort* __restrict__ A, int lda, const ushort* __restrict__ WT, int K,
    const float* __restrict__ bias, void* __restrict__ C, int ldc, int M) {
  __shared__ ushort As[64][40];
  __shared__ ushort Bs[256][40];
  const int tid = threadIdx.x;
  const int wave = tid >> 6, lane = tid & 63;
  const int quad = lane >> 4, l15 = lane & 15;
  const int m0 = blockIdx.x * 64;
  const int ncol0 = blockIdx.y * 256;
  const ushort* WTb = WT + (size_t)ncol0 * K;
  const int arow = tid >> 2, akc = (tid & 3) << 3;
  int am = m0 + arow;
  if (am >= M) am = M - 1;
  f32x4 acc[4][4];
#pragma unroll
  for (int i = 0; i < 4; ++i)
#pragma unroll
    for (int j = 0; j < 4; ++j) acc[i][j] = (f32x4){0.f, 0.f, 0.f, 0.f};
  for (int k0 = 0; k0 < K; k0 += 32) {
    *(uint4*)&As[arow][akc] = *(const uint4*)(A + (size_t)am * lda + k0 + akc);
#pragma unroll
    for (int r = 0; r < 4; ++r) {
      int row = arow + r * 64;
      *(uint4*)&Bs[row][akc] = *(const uint4*)(WTb + (size_t)row * K + k0 + akc);
    }
    __syncthreads();
    bf16x8 bfr[4];
#pragma unroll
    for (int ni = 0; ni < 4; ++ni)
      bfr[ni] = *(const bf16x8*)&Bs[wave * 64 + ni * 16 + l15][quad * 8];
#pragma unroll
    for (int mi = 0; mi < 4; ++mi) {
      bf16x8 af = *(const bf16x8*)&As[mi * 16 + l15][quad * 8];
#pragma unroll
      for (int ni = 0; ni < 4; ++ni) acc[mi][ni] = MFMA16(af, bfr[ni], acc[mi][ni]);
    }
    __syncthreads();
  }
#pragma unroll
  for (int mi = 0; mi < 4; ++mi)
#pragma unroll
    for (int ni = 0; ni < 4; ++ni) {
      int c = ncol0 + wave * 64 + ni * 16 + l15;
      float bv = bias[c];
#pragma unroll
      for (int r = 0; r < 4; ++r) {
        int m = m0 + mi * 16 + quad * 4 + r;
        if (m < M) {
          float v = acc[mi][ni][r] + bv;
          if (RELU) v = fmaxf(v, 0.f);
          if (OBF16) ((ushort*)C)[(size_t)m * ldc + c] = f2b(v);
          else       ((float*)C)[(size_t)m * ldc + c] = v;
        }
      }
    }
}

// ---------------- decoder: h0 = relu(Za[src]+Zb[dst]+lerp(T_ZE)), MFMA + dot ----------------
__global__ __launch_bounds__(256, 2) void dec3_k(
    const float* __restrict__ attr1, const ushort* __restrict__ T,
    const float* __restrict__ Z,
    const ushort* __restrict__ W1T, const float* __restrict__ b1,
    const float* __restrict__ W2, const float* __restrict__ b2,
    const int* __restrict__ src, const int* __restrict__ dst,
    float* __restrict__ out) {
  __shared__ ushort Bs[256][40];
  __shared__ ushort h0[64][264];
  __shared__ float red[4][64];
  const int tid = threadIdx.x;
  const int wave = tid >> 6, lane = tid & 63;
  const int quad = lane >> 4, l15 = lane & 15;
  const int m0 = blockIdx.x * 64;
  const int arow = tid >> 2, akc = (tid & 3) << 3;
  {
    int e = m0 + arow;
    int gs = src[e], gd = dst[e];
    float f = attr1[e] * 4096.f;
    int i0 = (int)f;
    i0 = i0 < 0 ? 0 : (i0 > 4095 ? 4095 : i0);
    float w = f - (float)i0;
    const ushort* tz0 = T + (size_t)i0 * TLD + 1536;
    const ushort* tz1 = tz0 + TLD;
    int c0 = (tid & 3) * 64;
    const float* za = Z + (size_t)gs * 512;
    const float* zb = Z + (size_t)gd * 512 + 256;
#pragma unroll
    for (int j = 0; j < 16; ++j) {
      int c = c0 + 4 * j;
      float4 a = *(const float4*)(za + c);
      float4 b = *(const float4*)(zb + c);
      ushort4 lo = *(const ushort4*)(tz0 + c);
      ushort4 hi = *(const ushort4*)(tz1 + c);
      float e0 = b2f(lo.x) + w * (b2f(hi.x) - b2f(lo.x));
      float e1 = b2f(lo.y) + w * (b2f(hi.y) - b2f(lo.y));
      float e2 = b2f(lo.z) + w * (b2f(hi.z) - b2f(lo.z));
      float e3 = b2f(lo.w) + w * (b2f(hi.w) - b2f(lo.w));
      ushort4 o;
      o.x = f2b(fmaxf(a.x + b.x + e0, 0.f));
      o.y = f2b(fmaxf(a.y + b.y + e1, 0.f));
      o.z = f2b(fmaxf(a.z + b.z + e2, 0.f));
      o.w = f2b(fmaxf(a.w + b.w + e3, 0.f));
      *(ushort4*)&h0[arow][c] = o;
    }
  }
  __syncthreads();
  f32x4 acc2[4][4];
#pragma unroll
  for (int i = 0; i < 4; ++i)
#pragma unroll
    for (int j = 0; j < 4; ++j) acc2[i][j] = (f32x4){0.f, 0.f, 0.f, 0.f};
  for (int k0 = 0; k0 < 256; k0 += 32) {
#pragma unroll
    for (int r = 0; r < 4; ++r) {
      int row = arow + r * 64;
      *(uint4*)&Bs[row][akc] = *(const uint4*)(W1T + (size_t)row * 256 + k0 + akc);
    }
    __syncthreads();
    bf16x8 bfr[4];
#pragma unroll
    for (int ni = 0; ni < 4; ++ni)
      bfr[ni] = *(const bf16x8*)&Bs[wave * 64 + ni * 16 + l15][quad * 8];
#pragma unroll
    for (int mi = 0; mi < 4; ++mi) {
      bf16x8 af = *(const bf16x8*)&h0[mi * 16 + l15][k0 + quad * 8];
#pragma unroll
      for (int ni = 0; ni < 4; ++ni) acc2[mi][ni] = MFMA16(af, bfr[ni], acc2[mi][ni]);
    }
    __syncthreads();
  }
  float part[4][4];
#pragma unroll
  for (int mi = 0; mi < 4; ++mi)
#pragma unroll
    for (int r = 0; r < 4; ++r) part[mi][r] = 0.f;
#pragma unroll
  for (int mi = 0; mi < 4; ++mi)
#pragma unroll
    for (int ni = 0; ni < 4; ++ni) {
      int c = wave * 64 + ni * 16 + l15;
      float bv = b1[c], wv = W2[c];
#pragma unroll
      for (int r = 0; r < 4; ++r) {
        float v = fmaxf(acc2[mi][ni][r] + bv, 0.f);
        part[mi][r] += v * wv;
      }
    }
#pragma unroll
  for (int d = 1; d < 16; d <<= 1)
#pragma unroll
    for (int mi = 0; mi < 4; ++mi)
#pragma unroll
      for (int r = 0; r < 4; ++r) part[mi][r] += __shfl_xor(part[mi][r], d);
  if (l15 == 0)
#pragma unroll
    for (int mi = 0; mi < 4; ++mi)
#pragma unroll
      for (int r = 0; r < 4; ++r) red[wave][mi * 16 + quad * 4 + r] = part[mi][r];
  __syncthreads();
  if (tid < 64) {
    float s = red[0][tid] + red[1][tid] + red[2][tid] + red[3][tid];
    out[m0 + tid] = s + b2[0];
  }
}

// ---------------- host ----------------

extern "C" void kernel_launch(void* const* d_in, const int* in_sizes, int n_in,
                              void* d_out, int out_size, void* d_ws, size_t ws_size,
                              hipStream_t stream) {
  const int*   eidx1  = (const int*)d_in[0];
  const float* eattr1 = (const float*)d_in[1];
  const int*   eidx2  = (const int*)d_in[2];
  const float* eattr2 = (const float*)d_in[3];
  const int*   batch  = (const int*)d_in[4];
  const float* tval   = (const float*)d_in[5];
  const float* te_W0 = (const float*)d_in[6];
  const float* te_b0 = (const float*)d_in[7];
  const float* te_W1 = (const float*)d_in[8];
  const float* te_b1 = (const float*)d_in[9];
  const float* te_W2 = (const float*)d_in[10];
  const float* te_b2 = (const float*)d_in[11];
  const float* ee_W0 = (const float*)d_in[12];
  const float* ee_b0 = (const float*)d_in[13];
  const float* ee_W1 = (const float*)d_in[14];
  const float* ee_b1 = (const float*)d_in[15];
  const float* ee_W2 = (const float*)d_in[16];
  const float* ee_b2 = (const float*)d_in[17];
  const float* dec_W0 = (const float*)d_in[18];
  const float* dec_b0 = (const float*)d_in[19];
  const float* dec_W1 = (const float*)d_in[20];
  const float* dec_b1 = (const float*)d_in[21];
  const float* dec_W2 = (const float*)d_in[22];
  const float* dec_b2 = (const float*)d_in[23];
  const float* gg_Wl  = (const float*)d_in[24];
  const float* gg_bl  = (const float*)d_in[25];
  const float* gg_Wr  = (const float*)d_in[26];
  const float* gg_br  = (const float*)d_in[27];
  const float* gg_We  = (const float*)d_in[28];
  const float* gg_att = (const float*)d_in[29];
  const float* gg_bias= (const float*)d_in[30];
  const float* gf_Wl  = (const float*)d_in[31];
  const float* gf_bl  = (const float*)d_in[32];
  const float* gf_Wr  = (const float*)d_in[33];
  const float* gf_br  = (const float*)d_in[34];
  const float* gf_We  = (const float*)d_in[35];
  const float* gf_att = (const float*)d_in[36];
  const float* gf_bias= (const float*)d_in[37];
  (void)in_sizes; (void)n_in; (void)out_size; (void)ws_size;

  const int* src1 = eidx1;
  const int* dst1 = eidx1 + NE1;
  const int* src2 = eidx2;
  const int* dst2 = eidx2 + NE2;

  char* base = (char*)d_ws;
  size_t off = 0;
  auto alloc = [&](size_t bytes) {
    void* p = base + off;
    off += (bytes + 255) & ~(size_t)255;
    return p;
  };
  ushort* x_a    = (ushort*)alloc((size_t)NNODE * 512 * 2);
  ushort* x_b    = (ushort*)alloc((size_t)NNODE * 512 * 2);
  ushort* xlr    = (ushort*)alloc((size_t)NNODE * 1024 * 2);
  float*  Z      = (float*)alloc((size_t)NNODE * 512 * 4);
  ushort* H1     = (ushort*)alloc((size_t)TROWS * 256 * 2);
  ushort* T      = (ushort*)alloc((size_t)TROWS * TLD * 2);   // 14.7 MB packed tables
  ushort* WcatT  = (ushort*)alloc((size_t)7 * 256 * 256 * 2);
  float*  bcat   = (float*)alloc((size_t)TLD * 4);
  float*  logits1= (float*)alloc((size_t)NE1 * 4);
  float*  logits2= (float*)alloc((size_t)NE2 * 4);
  float*  tenc   = (float*)alloc((size_t)16 * Hd * 4);
  ushort* decZT  = (ushort*)alloc((size_t)512 * 512 * 2);
  ushort* decW1T = (ushort*)alloc((size_t)256 * 256 * 2);
  ushort* wlrT   = (ushort*)alloc((size_t)6 * 512 * 512 * 2);  // [2*i+g]
  float*  biascat= (float*)alloc((size_t)6 * 1024 * 4);
  float*  zerob  = (float*)alloc((size_t)512 * 4);
  int* cnt1      = (int*)alloc((size_t)NNODE * 4);
  int* cur1      = (int*)alloc((size_t)NNODE * 4);
  int* rs1       = (int*)alloc((size_t)(NNODE + 1) * 4);
  int* eid1      = (int*)alloc((size_t)NE1 * 4);
  int* cnt2      = (int*)alloc((size_t)NNODE * 4);
  int* cur2      = (int*)alloc((size_t)NNODE * 4);
  int* rs2       = (int*)alloc((size_t)(NNODE + 1) * 4);
  int* eid2      = (int*)alloc((size_t)NE2 * 4);

  float* out = (float*)d_out;

  // ---- merged setup ----
  init_small_k<<<(NNODE + 512 + 6144 + 255) / 256, 256, 0, stream>>>(
      cnt1, cur1, cnt2, cur2, zerob, biascat, gg_bl, gg_br, gf_bl, gf_br);
  fold2_k<<<dim3(256, 7), 256, 0, stream>>>(gg_We, gf_We, dec_W0, dec_b0, ee_W2, ee_b2,
                                            WcatT, bcat);
  build_h1_k<<<TROWS, 256, 0, stream>>>(ee_W0, ee_b0, ee_W1, ee_b1, H1);

  TransArgs ta;
  int nt = 0, cum = 0;
  auto add = [&](const float* s, ushort* d, int K, int noff, int ld) {
    ta.t[nt].src = s; ta.t[nt].dst = d; ta.t[nt].K = K;
    ta.t[nt].n_off = noff; ta.t[nt].ld = ld; ta.t[nt].start = cum;
    cum += (K / 32) * 8; ++nt;
  };
  add(dec_W1, decW1T, 256, 0, 256);
  add(dec_W0, decZT, 512, 0, 512);
  add(dec_W0 + 512 * 256, decZT, 512, 256, 512);
  for (int i = 0; i < 3; ++i) {
    add(gg_Wl + (size_t)i * 512 * 256, wlrT + (size_t)(2 * i) * 512 * 512, 512, 0, 512);
    add(gg_Wr + (size_t)i * 512 * 256, wlrT + (size_t)(2 * i) * 512 * 512, 512, 256, 512);
    add(gf_Wl + (size_t)i * 512 * 256, wlrT + (size_t)(2 * i + 1) * 512 * 512, 512, 0, 512);
    add(gf_Wr + (size_t)i * 512 * 256, wlrT + (size_t)(2 * i + 1) * 512 * 512, 512, 256, 512);
  }
  for (int i = nt; i < 24; ++i) ta.t[i].start = 0x7fffffff;
  trans_all_k<<<cum, 256, 0, stream>>>(ta);

  // ---- table: T[4097][1792] = H1 @ WcatT^T + bcat (bf16) ----
  mgemm_k<false, true><<<dim3((TROWS + 63) / 64, 7), 256, 0, stream>>>(
      H1, 256, WcatT, 256, bcat, T, TLD, TROWS);

  // ---- CSR build ----
  deg_all_k<<<(NE1 + NE2) / 256, 256, 0, stream>>>(dst1, cnt1, dst2, cnt2);
  scan_k<<<2, 640, 0, stream>>>(cnt1, rs1, cnt2, rs2);
  fill_all_k<<<(NE1 + NE2) / 256, 256, 0, stream>>>(dst1, rs1, cur1, eid1, dst2, rs2, cur2, eid2);

  // ---- time encoding -> x0 (bf16) ----
  time_mlp_k<<<16, 256, 0, stream>>>(tval, te_W0, te_b0, te_W1, te_b1, te_W2, te_b2, tenc);
  build_x0_k<<<(NNODE * 512) / 256, 256, 0, stream>>>(batch, tenc, x_a);

  ushort* x_cur = x_a;
  ushort* x_nxt = x_b;
  const int ngrid = (NNODE + 63) / 64;
  for (int i = 0; i < 3; ++i) {
    mgemm_k<false, true><<<dim3(ngrid, 4), 256, 0, stream>>>(
        x_cur, 512, wlrT + (size_t)(2 * i) * 512 * 512, 512, biascat + (size_t)i * 1024, xlr, 1024, NNODE);
    logit_k<<<(NE1 + NE2) / 4, 256, 0, stream>>>(
        eattr1, eattr2, T, (2 * i) * 256, (2 * i + 1) * 256,
        gg_att + i * Hd, gf_att + i * Hd, xlr,
        src1, dst1, src2, dst2, logits1, logits2);
    aggregate_k<<<2 * AGRID, 256, 0, stream>>>(
        logits1, logits2, xlr, src1, src2, rs1, rs2, eid1, eid2,
        gg_bias + i * Hd, gf_bias + i * Hd, x_nxt);
    ushort* t = x_cur; x_cur = x_nxt; x_nxt = t;
  }

  // ---- decoder: Z per-node, then per-edge fused MLP (table ZE) ----
  mgemm_k<false, false><<<dim3(ngrid, 2), 256, 0, stream>>>(
      x_cur, 512, decZT, 512, zerob, Z, 512, NNODE);
  dec3_k<<<NE1 / 64, 256, 0, stream>>>(eattr1, T, Z, decW1T, dec_b1, dec_W2, dec_b2,
                                       src1, dst1, out);
}

// Round 11
// 661.421 us; speedup vs baseline: 1.9858x; 1.1646x over previous
//
#include <hip/hip_runtime.h>

#define Hd 256
#define NNODE 10000
#define NE1 131072
#define NE2 65536
#define AGRID 2500   // ceil(NNODE/4)
#define TROWS 4097
#define TLD 1792     // 7 * 256 packed table columns

typedef __attribute__((ext_vector_type(8))) short bf16x8;
typedef __attribute__((ext_vector_type(4))) float f32x4;

#define MFMA16(a, b, c) __builtin_amdgcn_mfma_f32_16x16x32_bf16((a), (b), (c), 0, 0, 0)

__device__ __forceinline__ float b2f(ushort u) { return __uint_as_float(((unsigned)u) << 16); }
__device__ __forceinline__ ushort f2b(float f) {
  unsigned u = __float_as_uint(f);
  return (ushort)((u + 0x7fffu + ((u >> 16) & 1u)) >> 16);
}

// ---------------- small kernels ----------------

__global__ void time_mlp_k(const float* __restrict__ tval,
                           const float* __restrict__ W0, const float* __restrict__ b0,
                           const float* __restrict__ W1, const float* __restrict__ b1,
                           const float* __restrict__ W2, const float* __restrict__ b2,
                           float* __restrict__ tenc) {
  __shared__ float h0[Hd], h1[Hd];
  int b = blockIdx.x, j = threadIdx.x;
  float t = tval[b];
  h0[j] = fmaxf(t * W0[j] + b0[j], 0.f);
  __syncthreads();
  float a = b1[j];
  for (int k = 0; k < Hd; ++k) a += h0[k] * W1[k * Hd + j];
  h1[j] = fmaxf(a, 0.f);
  __syncthreads();
  float c = b2[j];
  for (int k = 0; k < Hd; ++k) c += h1[k] * W2[k * Hd + j];
  tenc[b * Hd + j] = c;
}

__global__ void build_x0_k(const int* __restrict__ batch, const float* __restrict__ tenc,
                           ushort* __restrict__ x0) {
  int idx = blockIdx.x * 256 + threadIdx.x;
  int n = idx >> 9;
  x0[idx] = f2b(tenc[batch[n] * Hd + (idx & 255)]);
}

__global__ void init_small_k(int* __restrict__ cnt1, int* __restrict__ cur1,
                             int* __restrict__ cnt2, int* __restrict__ cur2,
                             float* __restrict__ zerob, float* __restrict__ biascat,
                             const float* __restrict__ gg_bl, const float* __restrict__ gg_br,
                             const float* __restrict__ gf_bl, const float* __restrict__ gf_br) {
  int i = blockIdx.x * 256 + threadIdx.x;
  if (i < NNODE) { cnt1[i] = 0; cur1[i] = 0; cnt2[i] = 0; cur2[i] = 0; return; }
  i -= NNODE;
  if (i < 512) { zerob[i] = 0.f; return; }
  i -= 512;
  if (i < 6144) {
    int layer = i >> 10, c = i & 1023;
    float v;
    if (c < 256)      v = gg_bl[layer * 256 + c];
    else if (c < 512) v = gg_br[layer * 256 + c - 256];
    else if (c < 768) v = gf_bl[layer * 256 + c - 512];
    else              v = gf_br[layer * 256 + c - 768];
    biascat[layer * 1024 + c] = v;
  }
}

// Packed fold: WcatT[y][n][k] = sum_j W2[k][j] * Wy[j][n]  (y<6: We[2i+g]; y=6: dec_W0c)
__global__ void fold2_k(const float* __restrict__ gg_We, const float* __restrict__ gf_We,
                        const float* __restrict__ dec_W0, const float* __restrict__ dec_b0,
                        const float* __restrict__ eeW2, const float* __restrict__ eeb2,
                        ushort* __restrict__ WcatT, float* __restrict__ bcat) {
  __shared__ float col[256];
  int n = blockIdx.x, y = blockIdx.y, k = threadIdx.x;
  if (y < 6) {
    int i = y >> 1, g = y & 1;
    const float* src = (g == 0 ? gg_We : gf_We) + (size_t)i * 65536;
    col[k] = src[(size_t)k * 256 + n];
  } else {
    col[k] = dec_W0[(size_t)(1024 + k) * 256 + n];
  }
  __syncthreads();
  float acc = 0.f;
  const float* w2row = eeW2 + (size_t)k * 256;
  for (int j = 0; j < 256; ++j) acc += w2row[j] * col[j];
  WcatT[((size_t)y * 256 + n) * 256 + k] = f2b(acc);
  if (k == 0) {
    float bb = (y == 6) ? dec_b0[n] : 0.f;
    for (int j = 0; j < 256; ++j) bb += eeb2[j] * col[j];
    bcat[y * 256 + n] = bb;
  }
}

// H1[i][j] = relu( relu((i/4096)*W0 + b0) @ W1 + b1 )[j]   (bf16)
__global__ void build_h1_k(const float* __restrict__ W0, const float* __restrict__ b0,
                           const float* __restrict__ W1, const float* __restrict__ b1,
                           ushort* __restrict__ H1) {
  __shared__ float h0[256];
  int i = blockIdx.x, j = threadIdx.x;
  float a = (float)i / 4096.f;
  h0[j] = fmaxf(a * W0[j] + b0[j], 0.f);
  __syncthreads();
  float acc = b1[j];
  for (int k = 0; k < 256; ++k) acc += h0[k] * W1[k * 256 + j];
  H1[(size_t)i * 256 + j] = f2b(fmaxf(acc, 0.f));
}

// ---------------- merged weight transposes ----------------
struct TT { const float* src; ushort* dst; int K; int n_off; int ld; int start; };
struct TransArgs { TT t[24]; };

__global__ void trans_all_k(TransArgs a) {
  int b = blockIdx.x;
  int ti = 0;
  while (ti + 1 < 24 && a.t[ti + 1].start <= b) ++ti;
  TT tk = a.t[ti];
  int lb = b - tk.start;
  int gx = tk.K >> 5;
  int k0 = (lb % gx) * 32, n0 = (lb / gx) * 32;
  __shared__ float t[32][33];
  int tx = threadIdx.x & 31, ty = threadIdx.x >> 5;
#pragma unroll
  for (int p = 0; p < 4; ++p)
    t[ty + 8 * p][tx] = tk.src[(size_t)(k0 + ty + 8 * p) * 256 + n0 + tx];
  __syncthreads();
#pragma unroll
  for (int p = 0; p < 4; ++p)
    tk.dst[(size_t)(tk.n_off + n0 + ty + 8 * p) * tk.ld + k0 + tx] = f2b(t[tx][ty + 8 * p]);
}

// ---------------- CSR build (by dst) ----------------

__global__ void deg_all_k(const int* __restrict__ dst1, int* __restrict__ cnt1,
                          const int* __restrict__ dst2, int* __restrict__ cnt2) {
  int e = blockIdx.x * 256 + threadIdx.x;
  if (e < NE1) atomicAdd(cnt1 + dst1[e], 1);
  else if (e - NE1 < NE2) atomicAdd(cnt2 + dst2[e - NE1], 1);
}

__global__ void scan_k(const int* __restrict__ cnt1, int* __restrict__ rs1,
                       const int* __restrict__ cnt2, int* __restrict__ rs2) {
  const int g = blockIdx.x;
  const int* cnt = g ? cnt2 : cnt1;
  int* rowstart = g ? rs2 : rs1;
  const int E = g ? NE2 : NE1;
  __shared__ int part[626];
  int t = threadIdx.x;
  if (t < 625) {
    int s = 0;
#pragma unroll
    for (int i = 0; i < 16; ++i) s += cnt[t * 16 + i];
    part[t] = s;
  }
  __syncthreads();
  if (t == 0) {
    int run = 0;
    for (int i = 0; i < 625; ++i) { int v = part[i]; part[i] = run; run += v; }
  }
  __syncthreads();
  if (t < 625) {
    int off = part[t];
#pragma unroll
    for (int i = 0; i < 16; ++i) { rowstart[t * 16 + i] = off; off += cnt[t * 16 + i]; }
  }
  if (t == 0) rowstart[NNODE] = E;
}

__global__ void fill_all_k(const int* __restrict__ dst1, const int* __restrict__ rs1,
                           int* __restrict__ cur1, int* __restrict__ eid1,
                           const int* __restrict__ dst2, const int* __restrict__ rs2,
                           int* __restrict__ cur2, int* __restrict__ eid2) {
  int e = blockIdx.x * 256 + threadIdx.x;
  if (e < NE1) {
    int d = dst1[e];
    eid1[rs1[d] + atomicAdd(cur1 + d, 1)] = e;
  } else if (e - NE1 < NE2) {
    int e2 = e - NE1;
    int d = dst2[e2];
    eid2[rs2[d] + atomicAdd(cur2 + d, 1)] = e2;
  }
}

// ---------------- fused logit + online-softmax aggregate (one wave/node) ----------------
// logit_e = att . leakyrelu(xl[src] + xr[nid] + lerp(T, attr_e));  out = softmax-weighted
// sum of xl[src], computed in ONE pass over the node's edge list.
__global__ __launch_bounds__(256) void attagg_k(
    const float* __restrict__ attr1, const float* __restrict__ attr2,
    const ushort* __restrict__ T, int tcol1, int tcol2,
    const float* __restrict__ att1, const float* __restrict__ att2,
    const ushort* __restrict__ xlr,
    const int* __restrict__ src1, const int* __restrict__ src2,
    const int* __restrict__ rs1, const int* __restrict__ rs2,
    const int* __restrict__ eid1, const int* __restrict__ eid2,
    const float* __restrict__ bias1, const float* __restrict__ bias2,
    ushort* __restrict__ xnext) {
  __shared__ float att_s[2][256], bias_s[2][256];
  const int tid = threadIdx.x;
  att_s[0][tid] = att1[tid];
  att_s[1][tid] = att2[tid];
  bias_s[0][tid] = bias1[tid];
  bias_s[1][tid] = bias2[tid];
  __syncthreads();
  const int wave = tid >> 6, lane = tid & 63;
  const bool g1 = blockIdx.x < AGRID;
  const int nid = (g1 ? blockIdx.x : blockIdx.x - AGRID) * 4 + wave;
  if (nid >= NNODE) return;
  const int gi = g1 ? 0 : 1;
  const float* attr = g1 ? attr1 : attr2;
  const int* src = g1 ? src1 : src2;
  const int* rowstart = g1 ? rs1 : rs2;
  const int* eid = g1 ? eid1 : eid2;
  const int goff = g1 ? 0 : 512;
  const int colbase = g1 ? 0 : 256;
  const ushort* Tg = T + (g1 ? tcol1 : tcol2);
  const int c = lane * 4;
  ushort4 xr4 = *(const ushort4*)(xlr + (size_t)nid * 1024 + goff + 256 + c);
  const float xr0 = b2f(xr4.x), xr1 = b2f(xr4.y), xr2 = b2f(xr4.z), xr3 = b2f(xr4.w);
  const float a0 = att_s[gi][c], a1 = att_s[gi][c + 1];
  const float a2 = att_s[gi][c + 2], a3 = att_s[gi][c + 3];
  const int s0 = rowstart[nid], s1 = rowstart[nid + 1];
  float m = -__int_as_float(0x7f800000);
  float den = 0.f, ac0 = 0.f, ac1 = 0.f, ac2 = 0.f, ac3 = 0.f;
  for (int i = s0; i < s1; ++i) {
    int e = eid[i];
    int s = src[e];
    float f = attr[e] * 4096.f;
    int i0 = (int)f;
    i0 = i0 < 0 ? 0 : (i0 > 4095 ? 4095 : i0);
    float w = f - (float)i0;
    const ushort* t0 = Tg + (size_t)i0 * TLD + c;
    ushort4 lo = *(const ushort4*)t0;
    ushort4 hi = *(const ushort4*)(t0 + TLD);
    ushort4 xv = *(const ushort4*)(xlr + (size_t)s * 1024 + goff + c);
    float x0 = b2f(xv.x), x1 = b2f(xv.y), x2 = b2f(xv.z), x3 = b2f(xv.w);
    float l0 = b2f(lo.x), l1 = b2f(lo.y), l2 = b2f(lo.z), l3 = b2f(lo.w);
    float z0 = x0 + xr0 + l0 + w * (b2f(hi.x) - l0);
    float z1 = x1 + xr1 + l1 + w * (b2f(hi.y) - l1);
    float z2 = x2 + xr2 + l2 + w * (b2f(hi.z) - l2);
    float z3 = x3 + xr3 + l3 + w * (b2f(hi.w) - l3);
    z0 = z0 > 0.f ? z0 : 0.2f * z0;
    z1 = z1 > 0.f ? z1 : 0.2f * z1;
    z2 = z2 > 0.f ? z2 : 0.2f * z2;
    z3 = z3 > 0.f ? z3 : 0.2f * z3;
    float p = z0 * a0 + z1 * a1 + z2 * a2 + z3 * a3;
#pragma unroll
    for (int dd = 1; dd < 64; dd <<= 1) p += __shfl_xor(p, dd);
    float mn = fmaxf(m, p);
    float sc = __expf(m - mn);
    float ww = __expf(p - mn);
    den = den * sc + ww;
    ac0 = ac0 * sc + ww * x0;
    ac1 = ac1 * sc + ww * x1;
    ac2 = ac2 * sc + ww * x2;
    ac3 = ac3 * sc + ww * x3;
    m = mn;
  }
  float inv = 1.f / (den + 1e-16f);
  ushort4 o;
  o.x = f2b(ac0 * inv + bias_s[gi][c + 0]);
  o.y = f2b(ac1 * inv + bias_s[gi][c + 1]);
  o.z = f2b(ac2 * inv + bias_s[gi][c + 2]);
  o.w = f2b(ac3 * inv + bias_s[gi][c + 3]);
  *(ushort4*)(xnext + (size_t)nid * 512 + colbase + c) = o;
}

// ---------------- generic MFMA GEMM (A + B LDS-staged, 64-row tile) ----------------
template <bool RELU, bool OBF16>
__global__ __launch_bounds__(256, 2) void mgemm_k(
    const ushort* __restrict__ A, int lda, const ushort* __restrict__ WT, int K,
    const float* __restrict__ bias, void* __restrict__ C, int ldc, int M) {
  __shared__ ushort As[64][40];
  __shared__ ushort Bs[256][40];
  const int tid = threadIdx.x;
  const int wave = tid >> 6, lane = tid & 63;
  const int quad = lane >> 4, l15 = lane & 15;
  const int m0 = blockIdx.x * 64;
  const int ncol0 = blockIdx.y * 256;
  const ushort* WTb = WT + (size_t)ncol0 * K;
  const int arow = tid >> 2, akc = (tid & 3) << 3;
  int am = m0 + arow;
  if (am >= M) am = M - 1;
  f32x4 acc[4][4];
#pragma unroll
  for (int i = 0; i < 4; ++i)
#pragma unroll
    for (int j = 0; j < 4; ++j) acc[i][j] = (f32x4){0.f, 0.f, 0.f, 0.f};
  for (int k0 = 0; k0 < K; k0 += 32) {
    *(uint4*)&As[arow][akc] = *(const uint4*)(A + (size_t)am * lda + k0 + akc);
#pragma unroll
    for (int r = 0; r < 4; ++r) {
      int row = arow + r * 64;
      *(uint4*)&Bs[row][akc] = *(const uint4*)(WTb + (size_t)row * K + k0 + akc);
    }
    __syncthreads();
    bf16x8 bfr[4];
#pragma unroll
    for (int ni = 0; ni < 4; ++ni)
      bfr[ni] = *(const bf16x8*)&Bs[wave * 64 + ni * 16 + l15][quad * 8];
#pragma unroll
    for (int mi = 0; mi < 4; ++mi) {
      bf16x8 af = *(const bf16x8*)&As[mi * 16 + l15][quad * 8];
#pragma unroll
      for (int ni = 0; ni < 4; ++ni) acc[mi][ni] = MFMA16(af, bfr[ni], acc[mi][ni]);
    }
    __syncthreads();
  }
#pragma unroll
  for (int mi = 0; mi < 4; ++mi)
#pragma unroll
    for (int ni = 0; ni < 4; ++ni) {
      int c = ncol0 + wave * 64 + ni * 16 + l15;
      float bv = bias[c];
#pragma unroll
      for (int r = 0; r < 4; ++r) {
        int m = m0 + mi * 16 + quad * 4 + r;
        if (m < M) {
          float v = acc[mi][ni][r] + bv;
          if (RELU) v = fmaxf(v, 0.f);
          if (OBF16) ((ushort*)C)[(size_t)m * ldc + c] = f2b(v);
          else       ((float*)C)[(size_t)m * ldc + c] = v;
        }
      }
    }
}

// ---------------- decoder: dst-ordered tiles, h0 = relu(Za+Zb+lerp), MFMA + dot ----------------
__global__ __launch_bounds__(256, 2) void dec3_k(
    const float* __restrict__ attr1, const ushort* __restrict__ T,
    const float* __restrict__ Z, const int* __restrict__ eid,
    const ushort* __restrict__ W1T, const float* __restrict__ b1,
    const float* __restrict__ W2, const float* __restrict__ b2,
    const int* __restrict__ src, const int* __restrict__ dst,
    float* __restrict__ out) {
  __shared__ ushort Bs[256][40];
  __shared__ ushort h0[64][264];
  __shared__ float red[4][64];
  const int tid = threadIdx.x;
  const int wave = tid >> 6, lane = tid & 63;
  const int quad = lane >> 4, l15 = lane & 15;
  const int m0 = blockIdx.x * 64;
  const int arow = tid >> 2, akc = (tid & 3) << 3;
  {
    int e = eid[m0 + arow];           // dst-sorted order: Zb gathers are clustered
    int gs = src[e], gd = dst[e];
    float f = attr1[e] * 4096.f;
    int i0 = (int)f;
    i0 = i0 < 0 ? 0 : (i0 > 4095 ? 4095 : i0);
    float w = f - (float)i0;
    const ushort* tz0 = T + (size_t)i0 * TLD + 1536;
    const ushort* tz1 = tz0 + TLD;
    int c0 = (tid & 3) * 64;
    const float* za = Z + (size_t)gs * 512;
    const float* zb = Z + (size_t)gd * 512 + 256;
#pragma unroll
    for (int j = 0; j < 16; ++j) {
      int c = c0 + 4 * j;
      float4 a = *(const float4*)(za + c);
      float4 b = *(const float4*)(zb + c);
      ushort4 lo = *(const ushort4*)(tz0 + c);
      ushort4 hi = *(const ushort4*)(tz1 + c);
      float e0 = b2f(lo.x) + w * (b2f(hi.x) - b2f(lo.x));
      float e1 = b2f(lo.y) + w * (b2f(hi.y) - b2f(lo.y));
      float e2 = b2f(lo.z) + w * (b2f(hi.z) - b2f(lo.z));
      float e3 = b2f(lo.w) + w * (b2f(hi.w) - b2f(lo.w));
      ushort4 o;
      o.x = f2b(fmaxf(a.x + b.x + e0, 0.f));
      o.y = f2b(fmaxf(a.y + b.y + e1, 0.f));
      o.z = f2b(fmaxf(a.z + b.z + e2, 0.f));
      o.w = f2b(fmaxf(a.w + b.w + e3, 0.f));
      *(ushort4*)&h0[arow][c] = o;
    }
  }
  __syncthreads();
  f32x4 acc2[4][4];
#pragma unroll
  for (int i = 0; i < 4; ++i)
#pragma unroll
    for (int j = 0; j < 4; ++j) acc2[i][j] = (f32x4){0.f, 0.f, 0.f, 0.f};
  for (int k0 = 0; k0 < 256; k0 += 32) {
#pragma unroll
    for (int r = 0; r < 4; ++r) {
      int row = arow + r * 64;
      *(uint4*)&Bs[row][akc] = *(const uint4*)(W1T + (size_t)row * 256 + k0 + akc);
    }
    __syncthreads();
    bf16x8 bfr[4];
#pragma unroll
    for (int ni = 0; ni < 4; ++ni)
      bfr[ni] = *(const bf16x8*)&Bs[wave * 64 + ni * 16 + l15][quad * 8];
#pragma unroll
    for (int mi = 0; mi < 4; ++mi) {
      bf16x8 af = *(const bf16x8*)&h0[mi * 16 + l15][k0 + quad * 8];
#pragma unroll
      for (int ni = 0; ni < 4; ++ni) acc2[mi][ni] = MFMA16(af, bfr[ni], acc2[mi][ni]);
    }
    __syncthreads();
  }
  float part[4][4];
#pragma unroll
  for (int mi = 0; mi < 4; ++mi)
#pragma unroll
    for (int r = 0; r < 4; ++r) part[mi][r] = 0.f;
#pragma unroll
  for (int mi = 0; mi < 4; ++mi)
#pragma unroll
    for (int ni = 0; ni < 4; ++ni) {
      int c = wave * 64 + ni * 16 + l15;
      float bv = b1[c], wv = W2[c];
#pragma unroll
      for (int r = 0; r < 4; ++r) {
        float v = fmaxf(acc2[mi][ni][r] + bv, 0.f);
        part[mi][r] += v * wv;
      }
    }
#pragma unroll
  for (int d = 1; d < 16; d <<= 1)
#pragma unroll
    for (int mi = 0; mi < 4; ++mi)
#pragma unroll
      for (int r = 0; r < 4; ++r) part[mi][r] += __shfl_xor(part[mi][r], d);
  if (l15 == 0)
#pragma unroll
    for (int mi = 0; mi < 4; ++mi)
#pragma unroll
      for (int r = 0; r < 4; ++r) red[wave][mi * 16 + quad * 4 + r] = part[mi][r];
  __syncthreads();
  if (tid < 64) {
    float s = red[0][tid] + red[1][tid] + red[2][tid] + red[3][tid];
    out[eid[m0 + tid]] = s + b2[0];
  }
}

// ---------------- host ----------------

extern "C" void kernel_launch(void* const* d_in, const int* in_sizes, int n_in,
                              void* d_out, int out_size, void* d_ws, size_t ws_size,
                              hipStream_t stream) {
  const int*   eidx1  = (const int*)d_in[0];
  const float* eattr1 = (const float*)d_in[1];
  const int*   eidx2  = (const int*)d_in[2];
  const float* eattr2 = (const float*)d_in[3];
  const int*   batch  = (const int*)d_in[4];
  const float* tval   = (const float*)d_in[5];
  const float* te_W0 = (const float*)d_in[6];
  const float* te_b0 = (const float*)d_in[7];
  const float* te_W1 = (const float*)d_in[8];
  const float* te_b1 = (const float*)d_in[9];
  const float* te_W2 = (const float*)d_in[10];
  const float* te_b2 = (const float*)d_in[11];
  const float* ee_W0 = (const float*)d_in[12];
  const float* ee_b0 = (const float*)d_in[13];
  const float* ee_W1 = (const float*)d_in[14];
  const float* ee_b1 = (const float*)d_in[15];
  const float* ee_W2 = (const float*)d_in[16];
  const float* ee_b2 = (const float*)d_in[17];
  const float* dec_W0 = (const float*)d_in[18];
  const float* dec_b0 = (const float*)d_in[19];
  const float* dec_W1 = (const float*)d_in[20];
  const float* dec_b1 = (const float*)d_in[21];
  const float* dec_W2 = (const float*)d_in[22];
  const float* dec_b2 = (const float*)d_in[23];
  const float* gg_Wl  = (const float*)d_in[24];
  const float* gg_bl  = (const float*)d_in[25];
  const float* gg_Wr  = (const float*)d_in[26];
  const float* gg_br  = (const float*)d_in[27];
  const float* gg_We  = (const float*)d_in[28];
  const float* gg_att = (const float*)d_in[29];
  const float* gg_bias= (const float*)d_in[30];
  const float* gf_Wl  = (const float*)d_in[31];
  const float* gf_bl  = (const float*)d_in[32];
  const float* gf_Wr  = (const float*)d_in[33];
  const float* gf_br  = (const float*)d_in[34];
  const float* gf_We  = (const float*)d_in[35];
  const float* gf_att = (const float*)d_in[36];
  const float* gf_bias= (const float*)d_in[37];
  (void)in_sizes; (void)n_in; (void)out_size; (void)ws_size;

  const int* src1 = eidx1;
  const int* dst1 = eidx1 + NE1;
  const int* src2 = eidx2;
  const int* dst2 = eidx2 + NE2;

  char* base = (char*)d_ws;
  size_t off = 0;
  auto alloc = [&](size_t bytes) {
    void* p = base + off;
    off += (bytes + 255) & ~(size_t)255;
    return p;
  };
  ushort* x_a    = (ushort*)alloc((size_t)NNODE * 512 * 2);
  ushort* x_b    = (ushort*)alloc((size_t)NNODE * 512 * 2);
  ushort* xlr    = (ushort*)alloc((size_t)NNODE * 1024 * 2);
  float*  Z      = (float*)alloc((size_t)NNODE * 512 * 4);
  ushort* H1     = (ushort*)alloc((size_t)TROWS * 256 * 2);
  ushort* T      = (ushort*)alloc((size_t)TROWS * TLD * 2);   // 14.7 MB packed tables
  ushort* WcatT  = (ushort*)alloc((size_t)7 * 256 * 256 * 2);
  float*  bcat   = (float*)alloc((size_t)TLD * 4);
  float*  tenc   = (float*)alloc((size_t)16 * Hd * 4);
  ushort* decZT  = (ushort*)alloc((size_t)512 * 512 * 2);
  ushort* decW1T = (ushort*)alloc((size_t)256 * 256 * 2);
  ushort* wlrT   = (ushort*)alloc((size_t)6 * 512 * 512 * 2);  // [2*i+g]
  float*  biascat= (float*)alloc((size_t)6 * 1024 * 4);
  float*  zerob  = (float*)alloc((size_t)512 * 4);
  int* cnt1      = (int*)alloc((size_t)NNODE * 4);
  int* cur1      = (int*)alloc((size_t)NNODE * 4);
  int* rs1       = (int*)alloc((size_t)(NNODE + 1) * 4);
  int* eid1      = (int*)alloc((size_t)NE1 * 4);
  int* cnt2      = (int*)alloc((size_t)NNODE * 4);
  int* cur2      = (int*)alloc((size_t)NNODE * 4);
  int* rs2       = (int*)alloc((size_t)(NNODE + 1) * 4);
  int* eid2      = (int*)alloc((size_t)NE2 * 4);

  float* out = (float*)d_out;

  // ---- merged setup ----
  init_small_k<<<(NNODE + 512 + 6144 + 255) / 256, 256, 0, stream>>>(
      cnt1, cur1, cnt2, cur2, zerob, biascat, gg_bl, gg_br, gf_bl, gf_br);
  fold2_k<<<dim3(256, 7), 256, 0, stream>>>(gg_We, gf_We, dec_W0, dec_b0, ee_W2, ee_b2,
                                            WcatT, bcat);
  build_h1_k<<<TROWS, 256, 0, stream>>>(ee_W0, ee_b0, ee_W1, ee_b1, H1);

  TransArgs ta;
  int nt = 0, cum = 0;
  auto add = [&](const float* s, ushort* d, int K, int noff, int ld) {
    ta.t[nt].src = s; ta.t[nt].dst = d; ta.t[nt].K = K;
    ta.t[nt].n_off = noff; ta.t[nt].ld = ld; ta.t[nt].start = cum;
    cum += (K / 32) * 8; ++nt;
  };
  add(dec_W1, decW1T, 256, 0, 256);
  add(dec_W0, decZT, 512, 0, 512);
  add(dec_W0 + 512 * 256, decZT, 512, 256, 512);
  for (int i = 0; i < 3; ++i) {
    add(gg_Wl + (size_t)i * 512 * 256, wlrT + (size_t)(2 * i) * 512 * 512, 512, 0, 512);
    add(gg_Wr + (size_t)i * 512 * 256, wlrT + (size_t)(2 * i) * 512 * 512, 512, 256, 512);
    add(gf_Wl + (size_t)i * 512 * 256, wlrT + (size_t)(2 * i + 1) * 512 * 512, 512, 0, 512);
    add(gf_Wr + (size_t)i * 512 * 256, wlrT + (size_t)(2 * i + 1) * 512 * 512, 512, 256, 512);
  }
  for (int i = nt; i < 24; ++i) ta.t[i].start = 0x7fffffff;
  trans_all_k<<<cum, 256, 0, stream>>>(ta);

  // ---- table: T[4097][1792] = H1 @ WcatT^T + bcat (bf16) ----
  mgemm_k<false, true><<<dim3((TROWS + 63) / 64, 7), 256, 0, stream>>>(
      H1, 256, WcatT, 256, bcat, T, TLD, TROWS);

  // ---- CSR build ----
  deg_all_k<<<(NE1 + NE2) / 256, 256, 0, stream>>>(dst1, cnt1, dst2, cnt2);
  scan_k<<<2, 640, 0, stream>>>(cnt1, rs1, cnt2, rs2);
  fill_all_k<<<(NE1 + NE2) / 256, 256, 0, stream>>>(dst1, rs1, cur1, eid1, dst2, rs2, cur2, eid2);

  // ---- time encoding -> x0 (bf16) ----
  time_mlp_k<<<16, 256, 0, stream>>>(tval, te_W0, te_b0, te_W1, te_b1, te_W2, te_b2, tenc);
  build_x0_k<<<(NNODE * 512) / 256, 256, 0, stream>>>(batch, tenc, x_a);

  ushort* x_cur = x_a;
  ushort* x_nxt = x_b;
  const int ngrid = (NNODE + 63) / 64;
  for (int i = 0; i < 3; ++i) {
    mgemm_k<false, true><<<dim3(ngrid, 4), 256, 0, stream>>>(
        x_cur, 512, wlrT + (size_t)(2 * i) * 512 * 512, 512, biascat + (size_t)i * 1024, xlr, 1024, NNODE);
    attagg_k<<<2 * AGRID, 256, 0, stream>>>(
        eattr1, eattr2, T, (2 * i) * 256, (2 * i + 1) * 256,
        gg_att + i * Hd, gf_att + i * Hd, xlr,
        src1, src2, rs1, rs2, eid1, eid2,
        gg_bias + i * Hd, gf_bias + i * Hd, x_nxt);
    ushort* t = x_cur; x_cur = x_nxt; x_nxt = t;
  }

  // ---- decoder: Z per-node, then per-edge fused MLP (dst-ordered tiles) ----
  mgemm_k<false, false><<<dim3(ngrid, 2), 256, 0, stream>>>(
      x_cur, 512, decZT, 512, zerob, Z, 512, NNODE);
  dec3_k<<<NE1 / 64, 256, 0, stream>>>(eattr1, T, Z, eid1, decW1T, dec_b1, dec_W2, dec_b2,
                                       src1, dst1, out);
}

// Round 12
// 617.820 us; speedup vs baseline: 2.1259x; 1.0706x over previous
//
#include <hip/hip_runtime.h>

#define Hd 256
#define NNODE 10000
#define NE1 131072
#define NE2 65536
#define AGRID 2500   // ceil(NNODE/4)
#define TROWS 4097
#define TLD 1792     // 7 * 256 packed table columns

typedef __attribute__((ext_vector_type(8))) short bf16x8;
typedef __attribute__((ext_vector_type(4))) float f32x4;

#define MFMA16(a, b, c) __builtin_amdgcn_mfma_f32_16x16x32_bf16((a), (b), (c), 0, 0, 0)

__device__ __forceinline__ float b2f(ushort u) { return __uint_as_float(((unsigned)u) << 16); }
__device__ __forceinline__ ushort f2b(float f) {
  unsigned u = __float_as_uint(f);
  return (ushort)((u + 0x7fffu + ((u >> 16) & 1u)) >> 16);
}

// ---------------- small kernels ----------------

__global__ void time_mlp_k(const float* __restrict__ tval,
                           const float* __restrict__ W0, const float* __restrict__ b0,
                           const float* __restrict__ W1, const float* __restrict__ b1,
                           const float* __restrict__ W2, const float* __restrict__ b2,
                           float* __restrict__ tenc) {
  __shared__ float h0[Hd], h1[Hd];
  int b = blockIdx.x, j = threadIdx.x;
  float t = tval[b];
  h0[j] = fmaxf(t * W0[j] + b0[j], 0.f);
  __syncthreads();
  float a = b1[j];
  for (int k = 0; k < Hd; ++k) a += h0[k] * W1[k * Hd + j];
  h1[j] = fmaxf(a, 0.f);
  __syncthreads();
  float c = b2[j];
  for (int k = 0; k < Hd; ++k) c += h1[k] * W2[k * Hd + j];
  tenc[b * Hd + j] = c;
}

__global__ void build_x0_k(const int* __restrict__ batch, const float* __restrict__ tenc,
                           ushort* __restrict__ x0) {
  int idx = blockIdx.x * 256 + threadIdx.x;
  int n = idx >> 9;
  x0[idx] = f2b(tenc[batch[n] * Hd + (idx & 255)]);
}

__global__ void init_small_k(int* __restrict__ cnt1, int* __restrict__ cur1,
                             int* __restrict__ cnt2, int* __restrict__ cur2,
                             float* __restrict__ zerob, float* __restrict__ biascat,
                             const float* __restrict__ gg_bl, const float* __restrict__ gg_br,
                             const float* __restrict__ gf_bl, const float* __restrict__ gf_br) {
  int i = blockIdx.x * 256 + threadIdx.x;
  if (i < NNODE) { cnt1[i] = 0; cur1[i] = 0; cnt2[i] = 0; cur2[i] = 0; return; }
  i -= NNODE;
  if (i < 512) { zerob[i] = 0.f; return; }
  i -= 512;
  if (i < 6144) {
    int layer = i >> 10, c = i & 1023;
    float v;
    if (c < 256)      v = gg_bl[layer * 256 + c];
    else if (c < 512) v = gg_br[layer * 256 + c - 256];
    else if (c < 768) v = gf_bl[layer * 256 + c - 512];
    else              v = gf_br[layer * 256 + c - 768];
    biascat[layer * 1024 + c] = v;
  }
}

// Packed fold: WcatT[y][n][k] = sum_j W2[k][j] * Wy[j][n]  (y<6: We[2i+g]; y=6: dec_W0c)
__global__ void fold2_k(const float* __restrict__ gg_We, const float* __restrict__ gf_We,
                        const float* __restrict__ dec_W0, const float* __restrict__ dec_b0,
                        const float* __restrict__ eeW2, const float* __restrict__ eeb2,
                        ushort* __restrict__ WcatT, float* __restrict__ bcat) {
  __shared__ float col[256];
  int n = blockIdx.x, y = blockIdx.y, k = threadIdx.x;
  if (y < 6) {
    int i = y >> 1, g = y & 1;
    const float* src = (g == 0 ? gg_We : gf_We) + (size_t)i * 65536;
    col[k] = src[(size_t)k * 256 + n];
  } else {
    col[k] = dec_W0[(size_t)(1024 + k) * 256 + n];
  }
  __syncthreads();
  float acc = 0.f;
  const float* w2row = eeW2 + (size_t)k * 256;
  for (int j = 0; j < 256; ++j) acc += w2row[j] * col[j];
  WcatT[((size_t)y * 256 + n) * 256 + k] = f2b(acc);
  if (k == 0) {
    float bb = (y == 6) ? dec_b0[n] : 0.f;
    for (int j = 0; j < 256; ++j) bb += eeb2[j] * col[j];
    bcat[y * 256 + n] = bb;
  }
}

// H1[i][j] = relu( relu((i/4096)*W0 + b0) @ W1 + b1 )[j]   (bf16)
__global__ void build_h1_k(const float* __restrict__ W0, const float* __restrict__ b0,
                           const float* __restrict__ W1, const float* __restrict__ b1,
                           ushort* __restrict__ H1) {
  __shared__ float h0[256];
  int i = blockIdx.x, j = threadIdx.x;
  float a = (float)i / 4096.f;
  h0[j] = fmaxf(a * W0[j] + b0[j], 0.f);
  __syncthreads();
  float acc = b1[j];
  for (int k = 0; k < 256; ++k) acc += h0[k] * W1[k * 256 + j];
  H1[(size_t)i * 256 + j] = f2b(fmaxf(acc, 0.f));
}

// ---------------- merged weight transposes ----------------
struct TT { const float* src; ushort* dst; int K; int n_off; int ld; int start; };
struct TransArgs { TT t[24]; };

__global__ void trans_all_k(TransArgs a) {
  int b = blockIdx.x;
  int ti = 0;
  while (ti + 1 < 24 && a.t[ti + 1].start <= b) ++ti;
  TT tk = a.t[ti];
  int lb = b - tk.start;
  int gx = tk.K >> 5;
  int k0 = (lb % gx) * 32, n0 = (lb / gx) * 32;
  __shared__ float t[32][33];
  int tx = threadIdx.x & 31, ty = threadIdx.x >> 5;
#pragma unroll
  for (int p = 0; p < 4; ++p)
    t[ty + 8 * p][tx] = tk.src[(size_t)(k0 + ty + 8 * p) * 256 + n0 + tx];
  __syncthreads();
#pragma unroll
  for (int p = 0; p < 4; ++p)
    tk.dst[(size_t)(tk.n_off + n0 + ty + 8 * p) * tk.ld + k0 + tx] = f2b(t[tx][ty + 8 * p]);
}

// ---------------- CSR build (by dst) ----------------

__global__ void deg_all_k(const int* __restrict__ dst1, int* __restrict__ cnt1,
                          const int* __restrict__ dst2, int* __restrict__ cnt2) {
  int e = blockIdx.x * 256 + threadIdx.x;
  if (e < NE1) atomicAdd(cnt1 + dst1[e], 1);
  else if (e - NE1 < NE2) atomicAdd(cnt2 + dst2[e - NE1], 1);
}

__global__ void scan_k(const int* __restrict__ cnt1, int* __restrict__ rs1,
                       const int* __restrict__ cnt2, int* __restrict__ rs2) {
  const int g = blockIdx.x;
  const int* cnt = g ? cnt2 : cnt1;
  int* rowstart = g ? rs2 : rs1;
  const int E = g ? NE2 : NE1;
  __shared__ int part[626];
  int t = threadIdx.x;
  if (t < 625) {
    int s = 0;
#pragma unroll
    for (int i = 0; i < 16; ++i) s += cnt[t * 16 + i];
    part[t] = s;
  }
  __syncthreads();
  if (t == 0) {
    int run = 0;
    for (int i = 0; i < 625; ++i) { int v = part[i]; part[i] = run; run += v; }
  }
  __syncthreads();
  if (t < 625) {
    int off = part[t];
#pragma unroll
    for (int i = 0; i < 16; ++i) { rowstart[t * 16 + i] = off; off += cnt[t * 16 + i]; }
  }
  if (t == 0) rowstart[NNODE] = E;
}

// fill CSR + CSR-ordered side arrays (srcs/attrs[/dsts]) — sequential reads, scattered writes
__global__ void fill_all_k(const int* __restrict__ dst1, const int* __restrict__ rs1,
                           int* __restrict__ cur1, int* __restrict__ eid1,
                           const int* __restrict__ src1, const float* __restrict__ eattr1,
                           int* __restrict__ srcs1, float* __restrict__ attrs1,
                           int* __restrict__ dsts1,
                           const int* __restrict__ dst2, const int* __restrict__ rs2,
                           int* __restrict__ cur2, int* __restrict__ eid2,
                           const int* __restrict__ src2, const float* __restrict__ eattr2,
                           int* __restrict__ srcs2, float* __restrict__ attrs2) {
  int e = blockIdx.x * 256 + threadIdx.x;
  if (e < NE1) {
    int d = dst1[e];
    int idx = rs1[d] + atomicAdd(cur1 + d, 1);
    eid1[idx] = e;
    srcs1[idx] = src1[e];
    attrs1[idx] = eattr1[e];
    dsts1[idx] = d;
  } else if (e - NE1 < NE2) {
    int e2 = e - NE1;
    int d = dst2[e2];
    int idx = rs2[d] + atomicAdd(cur2 + d, 1);
    eid2[idx] = e2;
    srcs2[idx] = src2[e2];
    attrs2[idx] = eattr2[e2];
  }
}

// ---------------- fused logit + online-softmax aggregate (one wave/node) ----------------
// CSR-ordered srcs/attrs; software-pipelined gather.
__global__ __launch_bounds__(256) void attagg_k(
    const ushort* __restrict__ T, int tcol1, int tcol2,
    const float* __restrict__ att1, const float* __restrict__ att2,
    const ushort* __restrict__ xlr,
    const int* __restrict__ srcs1, const float* __restrict__ attrs1,
    const int* __restrict__ srcs2, const float* __restrict__ attrs2,
    const int* __restrict__ rs1, const int* __restrict__ rs2,
    const float* __restrict__ bias1, const float* __restrict__ bias2,
    ushort* __restrict__ xnext) {
  __shared__ float att_s[2][256], bias_s[2][256];
  const int tid = threadIdx.x;
  att_s[0][tid] = att1[tid];
  att_s[1][tid] = att2[tid];
  bias_s[0][tid] = bias1[tid];
  bias_s[1][tid] = bias2[tid];
  __syncthreads();
  const int wave = tid >> 6, lane = tid & 63;
  const bool g1 = blockIdx.x < AGRID;
  const int nid = (g1 ? blockIdx.x : blockIdx.x - AGRID) * 4 + wave;
  if (nid >= NNODE) return;
  const int gi = g1 ? 0 : 1;
  const int* srcs = g1 ? srcs1 : srcs2;
  const float* attrs = g1 ? attrs1 : attrs2;
  const int* rowstart = g1 ? rs1 : rs2;
  const int goff = g1 ? 0 : 512;
  const int colbase = g1 ? 0 : 256;
  const ushort* Tg = T + (g1 ? tcol1 : tcol2);
  const int c = lane * 4;
  ushort4 xr4 = *(const ushort4*)(xlr + (size_t)nid * 1024 + goff + 256 + c);
  const float xr0 = b2f(xr4.x), xr1 = b2f(xr4.y), xr2 = b2f(xr4.z), xr3 = b2f(xr4.w);
  const float a0 = att_s[gi][c], a1 = att_s[gi][c + 1];
  const float a2 = att_s[gi][c + 2], a3 = att_s[gi][c + 3];
  const int s0 = rowstart[nid], s1 = rowstart[nid + 1];
  float m = -__int_as_float(0x7f800000);
  float den = 0.f, ac0 = 0.f, ac1 = 0.f, ac2 = 0.f, ac3 = 0.f;
  if (s0 >= s1) goto done;
  {
    ushort4 xv, lo, hi;
    float w;
    {  // prologue: load edge s0
      int s = srcs[s0];
      float f = attrs[s0] * 4096.f;
      int i0 = (int)f;
      i0 = i0 < 0 ? 0 : (i0 > 4095 ? 4095 : i0);
      w = f - (float)i0;
      const ushort* t0 = Tg + (size_t)i0 * TLD + c;
      lo = *(const ushort4*)t0;
      hi = *(const ushort4*)(t0 + TLD);
      xv = *(const ushort4*)(xlr + (size_t)s * 1024 + goff + c);
    }
    for (int i = s0; i < s1; ++i) {
      ushort4 xv_c = xv, lo_c = lo, hi_c = hi;
      float w_c = w;
      if (i + 1 < s1) {  // prefetch next edge while reducing current
        int s = srcs[i + 1];
        float f = attrs[i + 1] * 4096.f;
        int i0 = (int)f;
        i0 = i0 < 0 ? 0 : (i0 > 4095 ? 4095 : i0);
        w = f - (float)i0;
        const ushort* t0 = Tg + (size_t)i0 * TLD + c;
        lo = *(const ushort4*)t0;
        hi = *(const ushort4*)(t0 + TLD);
        xv = *(const ushort4*)(xlr + (size_t)s * 1024 + goff + c);
      }
      float x0 = b2f(xv_c.x), x1 = b2f(xv_c.y), x2 = b2f(xv_c.z), x3 = b2f(xv_c.w);
      float l0 = b2f(lo_c.x), l1 = b2f(lo_c.y), l2 = b2f(lo_c.z), l3 = b2f(lo_c.w);
      float z0 = x0 + xr0 + l0 + w_c * (b2f(hi_c.x) - l0);
      float z1 = x1 + xr1 + l1 + w_c * (b2f(hi_c.y) - l1);
      float z2 = x2 + xr2 + l2 + w_c * (b2f(hi_c.z) - l2);
      float z3 = x3 + xr3 + l3 + w_c * (b2f(hi_c.w) - l3);
      z0 = z0 > 0.f ? z0 : 0.2f * z0;
      z1 = z1 > 0.f ? z1 : 0.2f * z1;
      z2 = z2 > 0.f ? z2 : 0.2f * z2;
      z3 = z3 > 0.f ? z3 : 0.2f * z3;
      float p = z0 * a0 + z1 * a1 + z2 * a2 + z3 * a3;
#pragma unroll
      for (int dd = 1; dd < 64; dd <<= 1) p += __shfl_xor(p, dd);
      float mn = fmaxf(m, p);
      float sc = __expf(m - mn);
      float ww = __expf(p - mn);
      den = den * sc + ww;
      ac0 = ac0 * sc + ww * x0;
      ac1 = ac1 * sc + ww * x1;
      ac2 = ac2 * sc + ww * x2;
      ac3 = ac3 * sc + ww * x3;
      m = mn;
    }
  }
done:
  float inv = 1.f / (den + 1e-16f);
  ushort4 o;
  o.x = f2b(ac0 * inv + bias_s[gi][c + 0]);
  o.y = f2b(ac1 * inv + bias_s[gi][c + 1]);
  o.z = f2b(ac2 * inv + bias_s[gi][c + 2]);
  o.w = f2b(ac3 * inv + bias_s[gi][c + 3]);
  *(ushort4*)(xnext + (size_t)nid * 512 + colbase + c) = o;
}

// ---------------- generic MFMA GEMM (A + B LDS-staged, 64-row tile) ----------------
template <bool RELU, bool OBF16>
__global__ __launch_bounds__(256, 2) void mgemm_k(
    const ushort* __restrict__ A, int lda, const ushort* __restrict__ WT, int K,
    const float* __restrict__ bias, void* __restrict__ C, int ldc, int M) {
  __shared__ ushort As[64][40];
  __shared__ ushort Bs[256][40];
  const int tid = threadIdx.x;
  const int wave = tid >> 6, lane = tid & 63;
  const int quad = lane >> 4, l15 = lane & 15;
  const int m0 = blockIdx.x * 64;
  const int ncol0 = blockIdx.y * 256;
  const ushort* WTb = WT + (size_t)ncol0 * K;
  const int arow = tid >> 2, akc = (tid & 3) << 3;
  int am = m0 + arow;
  if (am >= M) am = M - 1;
  f32x4 acc[4][4];
#pragma unroll
  for (int i = 0; i < 4; ++i)
#pragma unroll
    for (int j = 0; j < 4; ++j) acc[i][j] = (f32x4){0.f, 0.f, 0.f, 0.f};
  for (int k0 = 0; k0 < K; k0 += 32) {
    *(uint4*)&As[arow][akc] = *(const uint4*)(A + (size_t)am * lda + k0 + akc);
#pragma unroll
    for (int r = 0; r < 4; ++r) {
      int row = arow + r * 64;
      *(uint4*)&Bs[row][akc] = *(const uint4*)(WTb + (size_t)row * K + k0 + akc);
    }
    __syncthreads();
    bf16x8 bfr[4];
#pragma unroll
    for (int ni = 0; ni < 4; ++ni)
      bfr[ni] = *(const bf16x8*)&Bs[wave * 64 + ni * 16 + l15][quad * 8];
#pragma unroll
    for (int mi = 0; mi < 4; ++mi) {
      bf16x8 af = *(const bf16x8*)&As[mi * 16 + l15][quad * 8];
#pragma unroll
      for (int ni = 0; ni < 4; ++ni) acc[mi][ni] = MFMA16(af, bfr[ni], acc[mi][ni]);
    }
    __syncthreads();
  }
#pragma unroll
  for (int mi = 0; mi < 4; ++mi)
#pragma unroll
    for (int ni = 0; ni < 4; ++ni) {
      int c = ncol0 + wave * 64 + ni * 16 + l15;
      float bv = bias[c];
#pragma unroll
      for (int r = 0; r < 4; ++r) {
        int m = m0 + mi * 16 + quad * 4 + r;
        if (m < M) {
          float v = acc[mi][ni][r] + bv;
          if (RELU) v = fmaxf(v, 0.f);
          if (OBF16) ((ushort*)C)[(size_t)m * ldc + c] = f2b(v);
          else       ((float*)C)[(size_t)m * ldc + c] = v;
        }
      }
    }
}

// ---------------- decoder: dst-ordered tiles, bf16 Z, h0 = relu(Za+Zb+lerp) ----------------
__global__ __launch_bounds__(256, 2) void dec3_k(
    const float* __restrict__ attrs1, const ushort* __restrict__ T,
    const ushort* __restrict__ Z, const int* __restrict__ eid,
    const int* __restrict__ srcs1, const int* __restrict__ dsts1,
    const ushort* __restrict__ W1T, const float* __restrict__ b1,
    const float* __restrict__ W2, const float* __restrict__ b2,
    float* __restrict__ out) {
  __shared__ ushort Bs[256][40];
  __shared__ ushort h0[64][264];
  __shared__ float red[4][64];
  const int tid = threadIdx.x;
  const int wave = tid >> 6, lane = tid & 63;
  const int quad = lane >> 4, l15 = lane & 15;
  const int m0 = blockIdx.x * 64;
  const int arow = tid >> 2, akc = (tid & 3) << 3;
  {
    int gs = srcs1[m0 + arow], gd = dsts1[m0 + arow];
    float f = attrs1[m0 + arow] * 4096.f;
    int i0 = (int)f;
    i0 = i0 < 0 ? 0 : (i0 > 4095 ? 4095 : i0);
    float w = f - (float)i0;
    const ushort* tz0 = T + (size_t)i0 * TLD + 1536;
    const ushort* tz1 = tz0 + TLD;
    int c0 = (tid & 3) * 64;
    const ushort* za = Z + (size_t)gs * 512;
    const ushort* zb = Z + (size_t)gd * 512 + 256;
#pragma unroll
    for (int j = 0; j < 16; ++j) {
      int c = c0 + 4 * j;
      ushort4 a = *(const ushort4*)(za + c);
      ushort4 b = *(const ushort4*)(zb + c);
      ushort4 lo = *(const ushort4*)(tz0 + c);
      ushort4 hi = *(const ushort4*)(tz1 + c);
      float e0 = b2f(lo.x) + w * (b2f(hi.x) - b2f(lo.x));
      float e1 = b2f(lo.y) + w * (b2f(hi.y) - b2f(lo.y));
      float e2 = b2f(lo.z) + w * (b2f(hi.z) - b2f(lo.z));
      float e3 = b2f(lo.w) + w * (b2f(hi.w) - b2f(lo.w));
      ushort4 o;
      o.x = f2b(fmaxf(b2f(a.x) + b2f(b.x) + e0, 0.f));
      o.y = f2b(fmaxf(b2f(a.y) + b2f(b.y) + e1, 0.f));
      o.z = f2b(fmaxf(b2f(a.z) + b2f(b.z) + e2, 0.f));
      o.w = f2b(fmaxf(b2f(a.w) + b2f(b.w) + e3, 0.f));
      *(ushort4*)&h0[arow][c] = o;
    }
  }
  __syncthreads();
  f32x4 acc2[4][4];
#pragma unroll
  for (int i = 0; i < 4; ++i)
#pragma unroll
    for (int j = 0; j < 4; ++j) acc2[i][j] = (f32x4){0.f, 0.f, 0.f, 0.f};
  for (int k0 = 0; k0 < 256; k0 += 32) {
#pragma unroll
    for (int r = 0; r < 4; ++r) {
      int row = arow + r * 64;
      *(uint4*)&Bs[row][akc] = *(const uint4*)(W1T + (size_t)row * 256 + k0 + akc);
    }
    __syncthreads();
    bf16x8 bfr[4];
#pragma unroll
    for (int ni = 0; ni < 4; ++ni)
      bfr[ni] = *(const bf16x8*)&Bs[wave * 64 + ni * 16 + l15][quad * 8];
#pragma unroll
    for (int mi = 0; mi < 4; ++mi) {
      bf16x8 af = *(const bf16x8*)&h0[mi * 16 + l15][k0 + quad * 8];
#pragma unroll
      for (int ni = 0; ni < 4; ++ni) acc2[mi][ni] = MFMA16(af, bfr[ni], acc2[mi][ni]);
    }
    __syncthreads();
  }
  float part[4][4];
#pragma unroll
  for (int mi = 0; mi < 4; ++mi)
#pragma unroll
    for (int r = 0; r < 4; ++r) part[mi][r] = 0.f;
#pragma unroll
  for (int mi = 0; mi < 4; ++mi)
#pragma unroll
    for (int ni = 0; ni < 4; ++ni) {
      int c = wave * 64 + ni * 16 + l15;
      float bv = b1[c], wv = W2[c];
#pragma unroll
      for (int r = 0; r < 4; ++r) {
        float v = fmaxf(acc2[mi][ni][r] + bv, 0.f);
        part[mi][r] += v * wv;
      }
    }
#pragma unroll
  for (int d = 1; d < 16; d <<= 1)
#pragma unroll
    for (int mi = 0; mi < 4; ++mi)
#pragma unroll
      for (int r = 0; r < 4; ++r) part[mi][r] += __shfl_xor(part[mi][r], d);
  if (l15 == 0)
#pragma unroll
    for (int mi = 0; mi < 4; ++mi)
#pragma unroll
      for (int r = 0; r < 4; ++r) red[wave][mi * 16 + quad * 4 + r] = part[mi][r];
  __syncthreads();
  if (tid < 64) {
    float s = red[0][tid] + red[1][tid] + red[2][tid] + red[3][tid];
    out[eid[m0 + tid]] = s + b2[0];
  }
}

// ---------------- host ----------------

extern "C" void kernel_launch(void* const* d_in, const int* in_sizes, int n_in,
                              void* d_out, int out_size, void* d_ws, size_t ws_size,
                              hipStream_t stream) {
  const int*   eidx1  = (const int*)d_in[0];
  const float* eattr1 = (const float*)d_in[1];
  const int*   eidx2  = (const int*)d_in[2];
  const float* eattr2 = (const float*)d_in[3];
  const int*   batch  = (const int*)d_in[4];
  const float* tval   = (const float*)d_in[5];
  const float* te_W0 = (const float*)d_in[6];
  const float* te_b0 = (const float*)d_in[7];
  const float* te_W1 = (const float*)d_in[8];
  const float* te_b1 = (const float*)d_in[9];
  const float* te_W2 = (const float*)d_in[10];
  const float* te_b2 = (const float*)d_in[11];
  const float* ee_W0 = (const float*)d_in[12];
  const float* ee_b0 = (const float*)d_in[13];
  const float* ee_W1 = (const float*)d_in[14];
  const float* ee_b1 = (const float*)d_in[15];
  const float* ee_W2 = (const float*)d_in[16];
  const float* ee_b2 = (const float*)d_in[17];
  const float* dec_W0 = (const float*)d_in[18];
  const float* dec_b0 = (const float*)d_in[19];
  const float* dec_W1 = (const float*)d_in[20];
  const float* dec_b1 = (const float*)d_in[21];
  const float* dec_W2 = (const float*)d_in[22];
  const float* dec_b2 = (const float*)d_in[23];
  const float* gg_Wl  = (const float*)d_in[24];
  const float* gg_bl  = (const float*)d_in[25];
  const float* gg_Wr  = (const float*)d_in[26];
  const float* gg_br  = (const float*)d_in[27];
  const float* gg_We  = (const float*)d_in[28];
  const float* gg_att = (const float*)d_in[29];
  const float* gg_bias= (const float*)d_in[30];
  const float* gf_Wl  = (const float*)d_in[31];
  const float* gf_bl  = (const float*)d_in[32];
  const float* gf_Wr  = (const float*)d_in[33];
  const float* gf_br  = (const float*)d_in[34];
  const float* gf_We  = (const float*)d_in[35];
  const float* gf_att = (const float*)d_in[36];
  const float* gf_bias= (const float*)d_in[37];
  (void)in_sizes; (void)n_in; (void)out_size; (void)ws_size;

  const int* src1 = eidx1;
  const int* dst1 = eidx1 + NE1;
  const int* src2 = eidx2;
  const int* dst2 = eidx2 + NE2;

  char* base = (char*)d_ws;
  size_t off = 0;
  auto alloc = [&](size_t bytes) {
    void* p = base + off;
    off += (bytes + 255) & ~(size_t)255;
    return p;
  };
  ushort* x_a    = (ushort*)alloc((size_t)NNODE * 512 * 2);
  ushort* x_b    = (ushort*)alloc((size_t)NNODE * 512 * 2);
  ushort* xlr    = (ushort*)alloc((size_t)NNODE * 1024 * 2);
  ushort* Z      = (ushort*)alloc((size_t)NNODE * 512 * 2);
  ushort* H1     = (ushort*)alloc((size_t)TROWS * 256 * 2);
  ushort* T      = (ushort*)alloc((size_t)TROWS * TLD * 2);   // 14.7 MB packed tables
  ushort* WcatT  = (ushort*)alloc((size_t)7 * 256 * 256 * 2);
  float*  bcat   = (float*)alloc((size_t)TLD * 4);
  float*  tenc   = (float*)alloc((size_t)16 * Hd * 4);
  ushort* decZT  = (ushort*)alloc((size_t)512 * 512 * 2);
  ushort* decW1T = (ushort*)alloc((size_t)256 * 256 * 2);
  ushort* wlrT   = (ushort*)alloc((size_t)6 * 512 * 512 * 2);  // [2*i+g]
  float*  biascat= (float*)alloc((size_t)6 * 1024 * 4);
  float*  zerob  = (float*)alloc((size_t)512 * 4);
  int* cnt1      = (int*)alloc((size_t)NNODE * 4);
  int* cur1      = (int*)alloc((size_t)NNODE * 4);
  int* rs1       = (int*)alloc((size_t)(NNODE + 1) * 4);
  int* eid1      = (int*)alloc((size_t)NE1 * 4);
  int* srcs1     = (int*)alloc((size_t)NE1 * 4);
  float* attrs1  = (float*)alloc((size_t)NE1 * 4);
  int* dsts1     = (int*)alloc((size_t)NE1 * 4);
  int* cnt2      = (int*)alloc((size_t)NNODE * 4);
  int* cur2      = (int*)alloc((size_t)NNODE * 4);
  int* rs2       = (int*)alloc((size_t)(NNODE + 1) * 4);
  int* eid2      = (int*)alloc((size_t)NE2 * 4);
  int* srcs2     = (int*)alloc((size_t)NE2 * 4);
  float* attrs2  = (float*)alloc((size_t)NE2 * 4);

  float* out = (float*)d_out;

  // ---- merged setup ----
  init_small_k<<<(NNODE + 512 + 6144 + 255) / 256, 256, 0, stream>>>(
      cnt1, cur1, cnt2, cur2, zerob, biascat, gg_bl, gg_br, gf_bl, gf_br);
  fold2_k<<<dim3(256, 7), 256, 0, stream>>>(gg_We, gf_We, dec_W0, dec_b0, ee_W2, ee_b2,
                                            WcatT, bcat);
  build_h1_k<<<TROWS, 256, 0, stream>>>(ee_W0, ee_b0, ee_W1, ee_b1, H1);

  TransArgs ta;
  int nt = 0, cum = 0;
  auto add = [&](const float* s, ushort* d, int K, int noff, int ld) {
    ta.t[nt].src = s; ta.t[nt].dst = d; ta.t[nt].K = K;
    ta.t[nt].n_off = noff; ta.t[nt].ld = ld; ta.t[nt].start = cum;
    cum += (K / 32) * 8; ++nt;
  };
  add(dec_W1, decW1T, 256, 0, 256);
  add(dec_W0, decZT, 512, 0, 512);
  add(dec_W0 + 512 * 256, decZT, 512, 256, 512);
  for (int i = 0; i < 3; ++i) {
    add(gg_Wl + (size_t)i * 512 * 256, wlrT + (size_t)(2 * i) * 512 * 512, 512, 0, 512);
    add(gg_Wr + (size_t)i * 512 * 256, wlrT + (size_t)(2 * i) * 512 * 512, 512, 256, 512);
    add(gf_Wl + (size_t)i * 512 * 256, wlrT + (size_t)(2 * i + 1) * 512 * 512, 512, 0, 512);
    add(gf_Wr + (size_t)i * 512 * 256, wlrT + (size_t)(2 * i + 1) * 512 * 512, 512, 256, 512);
  }
  for (int i = nt; i < 24; ++i) ta.t[i].start = 0x7fffffff;
  trans_all_k<<<cum, 256, 0, stream>>>(ta);

  // ---- table: T[4097][1792] = H1 @ WcatT^T + bcat (bf16) ----
  mgemm_k<false, true><<<dim3((TROWS + 63) / 64, 7), 256, 0, stream>>>(
      H1, 256, WcatT, 256, bcat, T, TLD, TROWS);

  // ---- CSR build ----
  deg_all_k<<<(NE1 + NE2) / 256, 256, 0, stream>>>(dst1, cnt1, dst2, cnt2);
  scan_k<<<2, 640, 0, stream>>>(cnt1, rs1, cnt2, rs2);
  fill_all_k<<<(NE1 + NE2) / 256, 256, 0, stream>>>(
      dst1, rs1, cur1, eid1, src1, eattr1, srcs1, attrs1, dsts1,
      dst2, rs2, cur2, eid2, src2, eattr2, srcs2, attrs2);

  // ---- time encoding -> x0 (bf16) ----
  time_mlp_k<<<16, 256, 0, stream>>>(tval, te_W0, te_b0, te_W1, te_b1, te_W2, te_b2, tenc);
  build_x0_k<<<(NNODE * 512) / 256, 256, 0, stream>>>(batch, tenc, x_a);

  ushort* x_cur = x_a;
  ushort* x_nxt = x_b;
  const int ngrid = (NNODE + 63) / 64;
  for (int i = 0; i < 3; ++i) {
    mgemm_k<false, true><<<dim3(ngrid, 4), 256, 0, stream>>>(
        x_cur, 512, wlrT + (size_t)(2 * i) * 512 * 512, 512, biascat + (size_t)i * 1024, xlr, 1024, NNODE);
    attagg_k<<<2 * AGRID, 256, 0, stream>>>(
        T, (2 * i) * 256, (2 * i + 1) * 256,
        gg_att + i * Hd, gf_att + i * Hd, xlr,
        srcs1, attrs1, srcs2, attrs2, rs1, rs2,
        gg_bias + i * Hd, gf_bias + i * Hd, x_nxt);
    ushort* t = x_cur; x_cur = x_nxt; x_nxt = t;
  }

  // ---- decoder: Z (bf16) per-node, then per-edge fused MLP (dst-ordered tiles) ----
  mgemm_k<false, true><<<dim3(ngrid, 2), 256, 0, stream>>>(
      x_cur, 512, decZT, 512, zerob, Z, 512, NNODE);
  dec3_k<<<NE1 / 64, 256, 0, stream>>>(attrs1, T, Z, eid1, srcs1, dsts1,
                                       decW1T, dec_b1, dec_W2, dec_b2, out);
}